// Round 1
// baseline (7847.392 us; speedup 1.0000x reference)
//
#include <hip/hip_runtime.h>
#include <math.h>

// Sizes (fixed by problem): B=2 T=32 C=3 H=W=64 P=8 -> N=64, D=512, L=2048, M=B*T*N=4096
#define MTOK 4096
#define DMODEL 512

__device__ __forceinline__ float blockReduceSum(float v, float* red){
  #pragma unroll
  for (int off = 32; off; off >>= 1) v += __shfl_down(v, off, 64);
  int lane = threadIdx.x & 63, wid = threadIdx.x >> 6;
  __syncthreads();
  if (lane == 0) red[wid] = v;
  __syncthreads();
  float r = 0.f;
  int nw = blockDim.x >> 6;
  for (int i = 0; i < nw; i++) r += red[i];
  return r;
}

// ---------------- patch embed + LN + pos ----------------
__global__ __launch_bounds__(256) void patch_embed_kernel(
    const float* __restrict__ x, const float* __restrict__ pw, const float* __restrict__ pb,
    const float* __restrict__ g, const float* __restrict__ bta,
    const float* __restrict__ spos, const float* __restrict__ tpos, float* __restrict__ out)
{
  int m = blockIdx.x;                 // token id 0..4095  (b,t,n)
  int b = m >> 11, t = (m >> 6) & 31, n = m & 63;
  int hn = n >> 3, wn = n & 7;
  __shared__ float patch[192];
  __shared__ float red[4];
  int tid = threadIdx.x;
  if (tid < 192){
    int c = tid / 64, rem = tid & 63;
    int ph = rem >> 3, pwj = rem & 7;
    patch[tid] = x[(((size_t)(b*32 + t)*3 + c)*64 + hn*8 + ph)*64 + wn*8 + pwj];
  }
  __syncthreads();
  float e0 = pb[tid], e1 = pb[tid + 256];
  const float* r0 = pw + (size_t)tid*192;
  const float* r1 = pw + (size_t)(tid + 256)*192;
  for (int k = 0; k < 192; k++){ float p = patch[k]; e0 = fmaf(p, r0[k], e0); e1 = fmaf(p, r1[k], e1); }
  float s = blockReduceSum(e0 + e1, red);
  float mu = s * (1.f/512.f);
  float d0 = e0 - mu, d1 = e1 - mu;
  float vv = blockReduceSum(d0*d0 + d1*d1, red);
  float inv = rsqrtf(vv * (1.f/512.f) + 1e-5f);
  size_t o = (size_t)m * 512;
  out[o + tid]       = d0*inv*g[tid]       + bta[tid]       + spos[n*512 + tid]       + tpos[t*512 + tid];
  out[o + tid + 256] = d1*inv*g[tid + 256] + bta[tid + 256] + spos[n*512 + tid + 256] + tpos[t*512 + tid + 256];
}

// ---------------- LayerNorm (D=512), one block per row ----------------
__global__ __launch_bounds__(256) void ln_kernel(
    const float* __restrict__ in, float* __restrict__ out,
    const float* __restrict__ g, const float* __restrict__ b)
{
  int r = blockIdx.x, tid = threadIdx.x;
  const float* row = in + (size_t)r * 512;
  float2 v = *(const float2*)(row + tid*2);
  __shared__ float red[4];
  float s = blockReduceSum(v.x + v.y, red);
  float mu = s * (1.f/512.f);
  float dx = v.x - mu, dy = v.y - mu;
  float vv = blockReduceSum(dx*dx + dy*dy, red);
  float inv = rsqrtf(vv * (1.f/512.f) + 1e-5f);
  float2 gg = *(const float2*)(g + tid*2);
  float2 bb = *(const float2*)(b + tid*2);
  float2 o; o.x = dx*inv*gg.x + bb.x; o.y = dy*inv*gg.y + bb.y;
  *(float2*)(out + (size_t)r*512 + tid*2) = o;
}

// ---------------- GEMM: Y[M,N] = X[M,K] @ W[N,K]^T + bias (+res) (+gelu) ----------------
template<bool GELU>
__global__ __launch_bounds__(256) void gemm_kernel(
    const float* __restrict__ X, const float* __restrict__ W,
    const float* __restrict__ bias, const float* __restrict__ res,
    float* __restrict__ Y, int M, int Nn, int K)
{
  __shared__ float Xs[16][64];
  __shared__ float Ws[16][64];
  int bm = blockIdx.y * 64, bn = blockIdx.x * 64;
  int tid = threadIdx.x;
  int tx = tid & 15, ty = tid >> 4;
  int lr = tid >> 2;             // 0..63
  int lk = (tid & 3) * 4;        // 0,4,8,12
  float acc[4][4] = {};
  for (int k0 = 0; k0 < K; k0 += 16){
    float4 xa = *(const float4*)(X + (size_t)(bm + lr)*K + k0 + lk);
    float4 wa = *(const float4*)(W + (size_t)(bn + lr)*K + k0 + lk);
    Xs[lk+0][lr] = xa.x; Xs[lk+1][lr] = xa.y; Xs[lk+2][lr] = xa.z; Xs[lk+3][lr] = xa.w;
    Ws[lk+0][lr] = wa.x; Ws[lk+1][lr] = wa.y; Ws[lk+2][lr] = wa.z; Ws[lk+3][lr] = wa.w;
    __syncthreads();
    #pragma unroll
    for (int kk = 0; kk < 16; kk++){
      float4 a4 = *(const float4*)&Xs[kk][ty*4];
      float4 b4 = *(const float4*)&Ws[kk][tx*4];
      float av[4] = {a4.x, a4.y, a4.z, a4.w};
      float bv[4] = {b4.x, b4.y, b4.z, b4.w};
      #pragma unroll
      for (int i = 0; i < 4; i++)
        #pragma unroll
        for (int j = 0; j < 4; j++)
          acc[i][j] = fmaf(av[i], bv[j], acc[i][j]);
    }
    __syncthreads();
  }
  #pragma unroll
  for (int i = 0; i < 4; i++){
    int m = bm + ty*4 + i;
    #pragma unroll
    for (int j = 0; j < 4; j++){
      int n = bn + tx*4 + j;
      float v = acc[i][j] + bias[n];
      if (res) v += res[(size_t)m*Nn + n];
      if (GELU) v = 0.5f * v * (1.f + erff(v * 0.70710678118654752440f));
      Y[(size_t)m*Nn + n] = v;
    }
  }
}

// ---------------- spatial attention: per (frame, head), N=64, hd=128 ----------------
// qkv layout per row (1536): [q 0:512 | k 512:1024 | v 1024:1536], head slice h*128
__global__ __launch_bounds__(256) void spatial_attn_kernel(
    const float* __restrict__ qkv, float* __restrict__ y)
{
  __shared__ float bufA[8192];   // Q^T [d][i] -> then P [64][65]
  __shared__ float bufB[8192];   // K^T [d][j] -> then V [j][d]
  int bt = blockIdx.x, h = blockIdx.y;
  int tid = threadIdx.x, tx = tid & 15, ty = tid >> 4;
  const float scale = 0.08838834764831845f;  // 1/sqrt(128)
  size_t base = (size_t)bt * 64 * 1536 + (size_t)h * 128;
  for (int e = tid; e < 2048; e += 256){
    int i = e >> 5, dc = (e & 31) * 4;
    const float* qp = qkv + base + (size_t)i*1536 + dc;
    float4 q4 = *(const float4*)qp;
    float4 k4 = *(const float4*)(qp + 512);
    bufA[(dc+0)*64+i] = q4.x; bufA[(dc+1)*64+i] = q4.y; bufA[(dc+2)*64+i] = q4.z; bufA[(dc+3)*64+i] = q4.w;
    bufB[(dc+0)*64+i] = k4.x; bufB[(dc+1)*64+i] = k4.y; bufB[(dc+2)*64+i] = k4.z; bufB[(dc+3)*64+i] = k4.w;
  }
  __syncthreads();
  float acc[4][4] = {};
  for (int d = 0; d < 128; d++){
    float4 qa = *(const float4*)&bufA[d*64 + ty*4];
    float4 ka = *(const float4*)&bufB[d*64 + tx*4];
    float av[4] = {qa.x, qa.y, qa.z, qa.w};
    float bv[4] = {ka.x, ka.y, ka.z, ka.w};
    #pragma unroll
    for (int i = 0; i < 4; i++)
      #pragma unroll
      for (int j = 0; j < 4; j++)
        acc[i][j] = fmaf(av[i], bv[j], acc[i][j]);
  }
  __syncthreads();
  #pragma unroll
  for (int i = 0; i < 4; i++)
    #pragma unroll
    for (int j = 0; j < 4; j++)
      bufA[(ty*4+i)*65 + tx*4+j] = acc[i][j] * scale;
  __syncthreads();
  // load V (bufB free), then softmax rows in bufA
  for (int e = tid; e < 2048; e += 256){
    int j = e >> 5, dc = (e & 31) * 4;
    float4 v4 = *(const float4*)(qkv + base + (size_t)j*1536 + 1024 + dc);
    *(float4*)&bufB[j*128 + dc] = v4;
  }
  if (tid < 64){
    float mx = -1e30f;
    for (int j = 0; j < 64; j++) mx = fmaxf(mx, bufA[tid*65 + j]);
    float ssum = 0.f;
    for (int j = 0; j < 64; j++){ float p = __expf(bufA[tid*65 + j] - mx); bufA[tid*65 + j] = p; ssum += p; }
    float invs = 1.f / ssum;
    for (int j = 0; j < 64; j++) bufA[tid*65 + j] *= invs;
  }
  __syncthreads();
  float ao[4][8] = {};
  for (int j = 0; j < 64; j++){
    float p[4];
    #pragma unroll
    for (int i = 0; i < 4; i++) p[i] = bufA[(ty*4+i)*65 + j];
    float4 v0 = *(const float4*)&bufB[j*128 + tx*4];
    float4 v1 = *(const float4*)&bufB[j*128 + 64 + tx*4];
    #pragma unroll
    for (int i = 0; i < 4; i++){
      ao[i][0] = fmaf(p[i], v0.x, ao[i][0]); ao[i][1] = fmaf(p[i], v0.y, ao[i][1]);
      ao[i][2] = fmaf(p[i], v0.z, ao[i][2]); ao[i][3] = fmaf(p[i], v0.w, ao[i][3]);
      ao[i][4] = fmaf(p[i], v1.x, ao[i][4]); ao[i][5] = fmaf(p[i], v1.y, ao[i][5]);
      ao[i][6] = fmaf(p[i], v1.z, ao[i][6]); ao[i][7] = fmaf(p[i], v1.w, ao[i][7]);
    }
  }
  size_t ybase = (size_t)(bt*64) * 512 + (size_t)h * 128;
  #pragma unroll
  for (int i = 0; i < 4; i++){
    int row = ty*4 + i;
    float4 o0 = {ao[i][0], ao[i][1], ao[i][2], ao[i][3]};
    float4 o1 = {ao[i][4], ao[i][5], ao[i][6], ao[i][7]};
    *(float4*)(y + ybase + (size_t)row*512 + tx*4) = o0;
    *(float4*)(y + ybase + (size_t)row*512 + 64 + tx*4) = o1;
  }
}

// ---------------- temporal causal attention (flash tiles): per (b,h), hd=64 ----------------
// qkv layout per row (1536): [k 0:512 | q 512:1024 | v 1024:1536]  (torch split order k,q,v)
__global__ __launch_bounds__(256) void temporal_attn_kernel(
    const float* __restrict__ qkv, float* __restrict__ y)
{
  __shared__ float Qt[4096];     // [d][i], pre-scaled
  __shared__ float KV[4096];     // K^T [d][j], then V [j][d]
  __shared__ float S[64*65];
  int qt = blockIdx.x, bh = blockIdx.y;
  int b = bh >> 3, h = bh & 7;
  int tid = threadIdx.x, tx = tid & 15, ty = tid >> 4;
  size_t rowbase = (size_t)(b * 2048) * 1536 + (size_t)h * 64;
  for (int e = tid; e < 1024; e += 256){
    int i = e >> 4, dc = (e & 15) * 4;
    float4 q4 = *(const float4*)(qkv + rowbase + (size_t)(qt*64 + i)*1536 + 512 + dc);
    Qt[(dc+0)*64+i] = q4.x*0.125f; Qt[(dc+1)*64+i] = q4.y*0.125f;
    Qt[(dc+2)*64+i] = q4.z*0.125f; Qt[(dc+3)*64+i] = q4.w*0.125f;
  }
  float m_old[4], l_sum[4], ao[4][4] = {};
  #pragma unroll
  for (int i = 0; i < 4; i++){ m_old[i] = -1e30f; l_sum[i] = 0.f; }
  for (int kt = 0; kt <= qt; kt++){
    __syncthreads();
    for (int e = tid; e < 1024; e += 256){
      int j = e >> 4, dc = (e & 15) * 4;
      float4 k4 = *(const float4*)(qkv + rowbase + (size_t)(kt*64 + j)*1536 + dc);
      KV[(dc+0)*64+j] = k4.x; KV[(dc+1)*64+j] = k4.y; KV[(dc+2)*64+j] = k4.z; KV[(dc+3)*64+j] = k4.w;
    }
    __syncthreads();
    float sa[4][4] = {};
    for (int d = 0; d < 64; d++){
      float4 qa = *(const float4*)&Qt[d*64 + ty*4];
      float4 ka = *(const float4*)&KV[d*64 + tx*4];
      float av[4] = {qa.x, qa.y, qa.z, qa.w};
      float bv[4] = {ka.x, ka.y, ka.z, ka.w};
      #pragma unroll
      for (int i = 0; i < 4; i++)
        #pragma unroll
        for (int j = 0; j < 4; j++)
          sa[i][j] = fmaf(av[i], bv[j], sa[i][j]);
    }
    bool diag = (kt == qt);
    #pragma unroll
    for (int i = 0; i < 4; i++){
      int gi = ty*4 + i;
      #pragma unroll
      for (int j = 0; j < 4; j++){
        int gj = tx*4 + j;
        float v = sa[i][j];
        if (diag && gj > gi) v = -1e30f;
        S[gi*65 + gj] = v;
      }
    }
    __syncthreads();
    float mnew[4], corr[4];
    #pragma unroll
    for (int i = 0; i < 4; i++){
      int r = ty*4 + i;
      float mx = -1e30f;
      for (int j = 0; j < 64; j++) mx = fmaxf(mx, S[r*65 + j]);
      mnew[i] = fmaxf(m_old[i], mx);
      float ps = 0.f;
      for (int j = 0; j < 64; j++) ps += __expf(S[r*65 + j] - mnew[i]);
      corr[i] = __expf(m_old[i] - mnew[i]);
      l_sum[i] = l_sum[i]*corr[i] + ps;
      m_old[i] = mnew[i];
    }
    __syncthreads();
    #pragma unroll
    for (int i = 0; i < 4; i++){
      int r = ty*4 + i;
      #pragma unroll
      for (int j = 0; j < 4; j++){
        int c = tx*4 + j;
        S[r*65 + c] = __expf(S[r*65 + c] - mnew[i]);
        ao[i][j] *= corr[i];
      }
    }
    __syncthreads();
    for (int e = tid; e < 1024; e += 256){
      int j = e >> 4, dc = (e & 15) * 4;
      float4 v4 = *(const float4*)(qkv + rowbase + (size_t)(kt*64 + j)*1536 + 1024 + dc);
      *(float4*)&KV[j*64 + dc] = v4;
    }
    __syncthreads();
    for (int j = 0; j < 64; j++){
      float p[4];
      #pragma unroll
      for (int i = 0; i < 4; i++) p[i] = S[(ty*4+i)*65 + j];
      float4 vv = *(const float4*)&KV[j*64 + tx*4];
      #pragma unroll
      for (int i = 0; i < 4; i++){
        ao[i][0] = fmaf(p[i], vv.x, ao[i][0]); ao[i][1] = fmaf(p[i], vv.y, ao[i][1]);
        ao[i][2] = fmaf(p[i], vv.z, ao[i][2]); ao[i][3] = fmaf(p[i], vv.w, ao[i][3]);
      }
    }
  }
  #pragma unroll
  for (int i = 0; i < 4; i++){
    float invl = 1.f / l_sum[i];
    float4 o = {ao[i][0]*invl, ao[i][1]*invl, ao[i][2]*invl, ao[i][3]*invl};
    *(float4*)(y + (size_t)(b*2048 + qt*64 + ty*4 + i)*512 + h*64 + tx*4) = o;
  }
}

// ---------------- tf = mean over N of lnf(hid) ----------------
__global__ __launch_bounds__(256) void reduce_tf_kernel(const float* __restrict__ hid, float* __restrict__ tf){
  int bt = blockIdx.x, tid = threadIdx.x;
  for (int d = tid; d < 512; d += 256){
    float s = 0.f;
    for (int n = 0; n < 64; n++) s += hid[((size_t)bt*64 + n)*512 + d];
    tf[(size_t)bt*512 + d] = s * (1.f/64.f);
  }
}

// ---------------- heads: blocks 0..63 pf, 64..65 temporal, 66..67 spatial ----------------
__global__ __launch_bounds__(256) void head_kernel(
    const float* __restrict__ tf,
    const float* __restrict__ th_w1, const float* __restrict__ th_b1,
    const float* __restrict__ th_w2, const float* __restrict__ th_b2,
    const float* __restrict__ sh_w1, const float* __restrict__ sh_b1,
    const float* __restrict__ sh_w2, const float* __restrict__ sh_b2,
    const float* __restrict__ pf_w1, const float* __restrict__ pf_b1,
    const float* __restrict__ pf_w2, const float* __restrict__ pf_b2,
    float* __restrict__ out)
{
  __shared__ float z[512];
  __shared__ float red[4];
  int bi = blockIdx.x, tid = threadIdx.x;
  const float *w1, *b1, *w2, *b2;
  float* dst;
  if (bi < 64){
    w1 = pf_w1; b1 = pf_b1; w2 = pf_w2; b2 = pf_b2; dst = out + 4 + bi;
    z[tid]       = tf[(size_t)bi*512 + tid];
    z[tid + 256] = tf[(size_t)bi*512 + tid + 256];
  } else if (bi < 66){
    int b = bi - 64;
    w1 = th_w1; b1 = th_b1; w2 = th_w2; b2 = th_b2; dst = out + b;
    z[tid]       = tf[(size_t)(b*32 + 31)*512 + tid];
    z[tid + 256] = tf[(size_t)(b*32 + 31)*512 + tid + 256];
  } else {
    int b = bi - 66;
    w1 = sh_w1; b1 = sh_b1; w2 = sh_w2; b2 = sh_b2; dst = out + 2 + b;
    float s0 = 0.f, s1 = 0.f;
    for (int t = 0; t < 32; t++){
      s0 += tf[(size_t)(b*32 + t)*512 + tid];
      s1 += tf[(size_t)(b*32 + t)*512 + tid + 256];
    }
    z[tid] = s0 * (1.f/32.f); z[tid + 256] = s1 * (1.f/32.f);
  }
  __syncthreads();
  float a = b1[tid];
  const float* wrow = w1 + (size_t)tid * 512;
  for (int k = 0; k < 512; k++) a = fmaf(wrow[k], z[k], a);
  a = (a > 0.f) ? a : 0.2f * a;
  float s = blockReduceSum(a * w2[tid], red);
  if (tid == 0) *dst = s + b2[0];
}

__global__ __launch_bounds__(64) void final_kernel(float* __restrict__ out){
  int b = threadIdx.x;
  if (b < 2){
    float s = 0.f;
    for (int t = 0; t < 32; t++) s += out[4 + b*32 + t];
    out[68 + b] = out[b] + out[2 + b] + s * (1.f/32.f);
  }
}

extern "C" void kernel_launch(void* const* d_in, const int* in_sizes, int n_in,
                              void* d_out, int out_size, void* d_ws, size_t ws_size,
                              hipStream_t stream)
{
  const float* x          = (const float*)d_in[0];
  const float* patch_w    = (const float*)d_in[1];
  const float* patch_b    = (const float*)d_in[2];
  const float* tok_ln_g   = (const float*)d_in[3];
  const float* tok_ln_b   = (const float*)d_in[4];
  const float* spatial_pos= (const float*)d_in[5];
  const float* temporal_pos=(const float*)d_in[6];
  const float* snorm_g    = (const float*)d_in[7];
  const float* snorm_b    = (const float*)d_in[8];
  const float* sa_in_w    = (const float*)d_in[9];
  const float* sa_in_b    = (const float*)d_in[10];
  const float* sa_out_w   = (const float*)d_in[11];
  const float* sa_out_b   = (const float*)d_in[12];
  const float* ln1_g      = (const float*)d_in[13];
  const float* ln1_b      = (const float*)d_in[14];
  const float* kqv_w      = (const float*)d_in[15];
  const float* kqv_b      = (const float*)d_in[16];
  const float* proj_w     = (const float*)d_in[17];
  const float* proj_b     = (const float*)d_in[18];
  const float* ln2_g      = (const float*)d_in[19];
  const float* ln2_b      = (const float*)d_in[20];
  const float* fc_w       = (const float*)d_in[21];
  const float* fc_b       = (const float*)d_in[22];
  const float* cproj_w    = (const float*)d_in[23];
  const float* cproj_b    = (const float*)d_in[24];
  const float* lnf_g      = (const float*)d_in[25];
  const float* lnf_b      = (const float*)d_in[26];
  const float* th_w1 = (const float*)d_in[27];
  const float* th_b1 = (const float*)d_in[28];
  const float* th_w2 = (const float*)d_in[29];
  const float* th_b2 = (const float*)d_in[30];
  const float* sh_w1 = (const float*)d_in[31];
  const float* sh_b1 = (const float*)d_in[32];
  const float* sh_w2 = (const float*)d_in[33];
  const float* sh_b2 = (const float*)d_in[34];
  const float* pf_w1 = (const float*)d_in[35];
  const float* pf_b1 = (const float*)d_in[36];
  const float* pf_w2 = (const float*)d_in[37];
  const float* pf_b2 = (const float*)d_in[38];

  float* out = (float*)d_out;
  float* A  = (float*)d_ws;                   // hidden state, 4096x512
  float* Bf = A  + (size_t)MTOK*512;          // ln output,   4096x512
  float* Cf = Bf + (size_t)MTOK*512;          // qkv/fc,      4096x2048
  float* Ef = Cf + (size_t)MTOK*2048;         // attn y,      4096x512
  float* tf = Ef + (size_t)MTOK*512;          // 64x512

  // patch embed + tok LN + pos
  patch_embed_kernel<<<MTOK, 256, 0, stream>>>(x, patch_w, patch_b, tok_ln_g, tok_ln_b,
                                               spatial_pos, temporal_pos, A);
  // spatial layers
  for (int i = 0; i < 3; i++){
    ln_kernel<<<MTOK, 256, 0, stream>>>(A, Bf, snorm_g, snorm_b);
    gemm_kernel<false><<<dim3(1536/64, MTOK/64), 256, 0, stream>>>(
        Bf, sa_in_w + (size_t)i*1536*512, sa_in_b + (size_t)i*1536, nullptr, Cf, MTOK, 1536, 512);
    spatial_attn_kernel<<<dim3(64, 4), 256, 0, stream>>>(Cf, Ef);
    gemm_kernel<false><<<dim3(512/64, MTOK/64), 256, 0, stream>>>(
        Ef, sa_out_w + (size_t)i*512*512, sa_out_b + (size_t)i*512, A, A, MTOK, 512, 512);
  }
  // temporal layers
  for (int i = 0; i < 6; i++){
    ln_kernel<<<MTOK, 256, 0, stream>>>(A, Bf, ln1_g + (size_t)i*512, ln1_b + (size_t)i*512);
    gemm_kernel<false><<<dim3(1536/64, MTOK/64), 256, 0, stream>>>(
        Bf, kqv_w + (size_t)i*1536*512, kqv_b + (size_t)i*1536, nullptr, Cf, MTOK, 1536, 512);
    temporal_attn_kernel<<<dim3(32, 16), 256, 0, stream>>>(Cf, Ef);
    gemm_kernel<false><<<dim3(512/64, MTOK/64), 256, 0, stream>>>(
        Ef, proj_w + (size_t)i*512*512, proj_b + (size_t)i*512, A, A, MTOK, 512, 512);
    ln_kernel<<<MTOK, 256, 0, stream>>>(A, Bf, ln2_g + (size_t)i*512, ln2_b + (size_t)i*512);
    gemm_kernel<true><<<dim3(2048/64, MTOK/64), 256, 0, stream>>>(
        Bf, fc_w + (size_t)i*2048*512, fc_b + (size_t)i*2048, nullptr, Cf, MTOK, 2048, 512);
    gemm_kernel<false><<<dim3(512/64, MTOK/64), 256, 0, stream>>>(
        Cf, cproj_w + (size_t)i*512*2048, cproj_b + (size_t)i*512, A, A, MTOK, 512, 2048);
  }
  // final LN + heads
  ln_kernel<<<MTOK, 256, 0, stream>>>(A, Bf, lnf_g, lnf_b);
  reduce_tf_kernel<<<64, 256, 0, stream>>>(Bf, tf);
  head_kernel<<<68, 256, 0, stream>>>(tf, th_w1, th_b1, th_w2, th_b2,
                                      sh_w1, sh_b1, sh_w2, sh_b2,
                                      pf_w1, pf_b1, pf_w2, pf_b2, out);
  final_kernel<<<1, 64, 0, stream>>>(out);
}

// Round 2
// 5050.697 us; speedup vs baseline: 1.5537x; 1.5537x over previous
//
#include <hip/hip_runtime.h>
#include <math.h>

// Sizes (fixed by problem): B=2 T=32 C=3 H=W=64 P=8 -> N=64, D=512, L=2048, M=B*T*N=4096
#define MTOK 4096
#define DMODEL 512

__device__ __forceinline__ float blockReduceSum(float v, float* red){
  #pragma unroll
  for (int off = 32; off; off >>= 1) v += __shfl_down(v, off, 64);
  int lane = threadIdx.x & 63, wid = threadIdx.x >> 6;
  __syncthreads();
  if (lane == 0) red[wid] = v;
  __syncthreads();
  float r = 0.f;
  int nw = blockDim.x >> 6;
  for (int i = 0; i < nw; i++) r += red[i];
  return r;
}

// 16-lane-group (same-row) reductions via wave shuffles: lanes sharing a row
// are consecutive (tx = tid&15), masks 8,4,2,1 stay within the group.
__device__ __forceinline__ float rowMax16(float v){
  #pragma unroll
  for (int m = 8; m; m >>= 1) v = fmaxf(v, __shfl_xor(v, m, 64));
  return v;
}
__device__ __forceinline__ float rowSum16(float v){
  #pragma unroll
  for (int m = 8; m; m >>= 1) v += __shfl_xor(v, m, 64);
  return v;
}

// ---------------- patch embed + LN + pos ----------------
__global__ __launch_bounds__(256) void patch_embed_kernel(
    const float* __restrict__ x, const float* __restrict__ pw, const float* __restrict__ pb,
    const float* __restrict__ g, const float* __restrict__ bta,
    const float* __restrict__ spos, const float* __restrict__ tpos, float* __restrict__ out)
{
  int m = blockIdx.x;                 // token id 0..4095  (b,t,n)
  int b = m >> 11, t = (m >> 6) & 31, n = m & 63;
  int hn = n >> 3, wn = n & 7;
  __shared__ float patch[192];
  __shared__ float red[4];
  int tid = threadIdx.x;
  if (tid < 192){
    int c = tid / 64, rem = tid & 63;
    int ph = rem >> 3, pwj = rem & 7;
    patch[tid] = x[(((size_t)(b*32 + t)*3 + c)*64 + hn*8 + ph)*64 + wn*8 + pwj];
  }
  __syncthreads();
  float e0 = pb[tid], e1 = pb[tid + 256];
  const float* r0 = pw + (size_t)tid*192;
  const float* r1 = pw + (size_t)(tid + 256)*192;
  for (int k = 0; k < 192; k++){ float p = patch[k]; e0 = fmaf(p, r0[k], e0); e1 = fmaf(p, r1[k], e1); }
  float s = blockReduceSum(e0 + e1, red);
  float mu = s * (1.f/512.f);
  float d0 = e0 - mu, d1 = e1 - mu;
  float vv = blockReduceSum(d0*d0 + d1*d1, red);
  float inv = rsqrtf(vv * (1.f/512.f) + 1e-5f);
  size_t o = (size_t)m * 512;
  out[o + tid]       = d0*inv*g[tid]       + bta[tid]       + spos[n*512 + tid]       + tpos[t*512 + tid];
  out[o + tid + 256] = d1*inv*g[tid + 256] + bta[tid + 256] + spos[n*512 + tid + 256] + tpos[t*512 + tid + 256];
}

// ---------------- LayerNorm (D=512), one block per row ----------------
__global__ __launch_bounds__(256) void ln_kernel(
    const float* __restrict__ in, float* __restrict__ out,
    const float* __restrict__ g, const float* __restrict__ b)
{
  int r = blockIdx.x, tid = threadIdx.x;
  const float* row = in + (size_t)r * 512;
  float2 v = *(const float2*)(row + tid*2);
  __shared__ float red[4];
  float s = blockReduceSum(v.x + v.y, red);
  float mu = s * (1.f/512.f);
  float dx = v.x - mu, dy = v.y - mu;
  float vv = blockReduceSum(dx*dx + dy*dy, red);
  float inv = rsqrtf(vv * (1.f/512.f) + 1e-5f);
  float2 gg = *(const float2*)(g + tid*2);
  float2 bb = *(const float2*)(b + tid*2);
  float2 o; o.x = dx*inv*gg.x + bb.x; o.y = dy*inv*gg.y + bb.y;
  *(float2*)(out + (size_t)r*512 + tid*2) = o;
}

// ---------------- GEMM: Y[M,N] = X[M,K] @ W[N,K]^T + bias (+res) (+gelu) ----------------
template<bool GELU>
__global__ __launch_bounds__(256) void gemm_kernel(
    const float* __restrict__ X, const float* __restrict__ W,
    const float* __restrict__ bias, const float* __restrict__ res,
    float* __restrict__ Y, int M, int Nn, int K)
{
  __shared__ float Xs[16][64];
  __shared__ float Ws[16][64];
  int bm = blockIdx.y * 64, bn = blockIdx.x * 64;
  int tid = threadIdx.x;
  int tx = tid & 15, ty = tid >> 4;
  int lr = tid >> 2;             // 0..63
  int lk = (tid & 3) * 4;        // 0,4,8,12
  float acc[4][4] = {};
  for (int k0 = 0; k0 < K; k0 += 16){
    float4 xa = *(const float4*)(X + (size_t)(bm + lr)*K + k0 + lk);
    float4 wa = *(const float4*)(W + (size_t)(bn + lr)*K + k0 + lk);
    Xs[lk+0][lr] = xa.x; Xs[lk+1][lr] = xa.y; Xs[lk+2][lr] = xa.z; Xs[lk+3][lr] = xa.w;
    Ws[lk+0][lr] = wa.x; Ws[lk+1][lr] = wa.y; Ws[lk+2][lr] = wa.z; Ws[lk+3][lr] = wa.w;
    __syncthreads();
    #pragma unroll
    for (int kk = 0; kk < 16; kk++){
      float4 a4 = *(const float4*)&Xs[kk][ty*4];
      float4 b4 = *(const float4*)&Ws[kk][tx*4];
      float av[4] = {a4.x, a4.y, a4.z, a4.w};
      float bv[4] = {b4.x, b4.y, b4.z, b4.w};
      #pragma unroll
      for (int i = 0; i < 4; i++)
        #pragma unroll
        for (int j = 0; j < 4; j++)
          acc[i][j] = fmaf(av[i], bv[j], acc[i][j]);
    }
    __syncthreads();
  }
  #pragma unroll
  for (int i = 0; i < 4; i++){
    int m = bm + ty*4 + i;
    #pragma unroll
    for (int j = 0; j < 4; j++){
      int n = bn + tx*4 + j;
      float v = acc[i][j] + bias[n];
      if (res) v += res[(size_t)m*Nn + n];
      if (GELU) v = 0.5f * v * (1.f + erff(v * 0.70710678118654752440f));
      Y[(size_t)m*Nn + n] = v;
    }
  }
}

// ---------------- spatial attention: per (frame, head), N=64, hd=128 ----------------
// qkv layout per row (1536): [q 0:512 | k 512:1024 | v 1024:1536], head slice h*128
__global__ __launch_bounds__(256) void spatial_attn_kernel(
    const float* __restrict__ qkv, float* __restrict__ y)
{
  __shared__ float bufA[8192];   // Q^T [d][i] -> then P [64][65]
  __shared__ float bufB[8192];   // K^T [d][j] -> then V [j][d]
  int bt = blockIdx.x, h = blockIdx.y;
  int tid = threadIdx.x, tx = tid & 15, ty = tid >> 4;
  const float scale = 0.08838834764831845f;  // 1/sqrt(128)
  size_t base = (size_t)bt * 64 * 1536 + (size_t)h * 128;
  for (int e = tid; e < 2048; e += 256){
    int i = e >> 5, dc = (e & 31) * 4;
    const float* qp = qkv + base + (size_t)i*1536 + dc;
    float4 q4 = *(const float4*)qp;
    float4 k4 = *(const float4*)(qp + 512);
    bufA[(dc+0)*64+i] = q4.x; bufA[(dc+1)*64+i] = q4.y; bufA[(dc+2)*64+i] = q4.z; bufA[(dc+3)*64+i] = q4.w;
    bufB[(dc+0)*64+i] = k4.x; bufB[(dc+1)*64+i] = k4.y; bufB[(dc+2)*64+i] = k4.z; bufB[(dc+3)*64+i] = k4.w;
  }
  __syncthreads();
  float acc[4][4] = {};
  for (int d = 0; d < 128; d++){
    float4 qa = *(const float4*)&bufA[d*64 + ty*4];
    float4 ka = *(const float4*)&bufB[d*64 + tx*4];
    float av[4] = {qa.x, qa.y, qa.z, qa.w};
    float bv[4] = {ka.x, ka.y, ka.z, ka.w};
    #pragma unroll
    for (int i = 0; i < 4; i++)
      #pragma unroll
      for (int j = 0; j < 4; j++)
        acc[i][j] = fmaf(av[i], bv[j], acc[i][j]);
  }
  // in-register softmax over rows (16 lanes share a row)
  float pnorm[4];
  #pragma unroll
  for (int i = 0; i < 4; i++){
    float mx = fmaxf(fmaxf(acc[i][0], acc[i][1]), fmaxf(acc[i][2], acc[i][3]));
    mx = rowMax16(mx);
    float ps = 0.f;
    #pragma unroll
    for (int j = 0; j < 4; j++){ acc[i][j] = __expf(acc[i][j]*scale - mx*scale); ps += acc[i][j]; }
    ps = rowSum16(ps);
    pnorm[i] = 1.f / ps;
  }
  __syncthreads();   // all QK reads of bufA/bufB done
  #pragma unroll
  for (int i = 0; i < 4; i++)
    #pragma unroll
    for (int j = 0; j < 4; j++)
      bufA[(ty*4+i)*65 + tx*4+j] = acc[i][j] * pnorm[i];
  // load V into bufB
  for (int e = tid; e < 2048; e += 256){
    int j = e >> 5, dc = (e & 31) * 4;
    float4 v4 = *(const float4*)(qkv + base + (size_t)j*1536 + 1024 + dc);
    *(float4*)&bufB[j*128 + dc] = v4;
  }
  __syncthreads();
  float ao[4][8] = {};
  for (int j = 0; j < 64; j++){
    float p[4];
    #pragma unroll
    for (int i = 0; i < 4; i++) p[i] = bufA[(ty*4+i)*65 + j];
    float4 v0 = *(const float4*)&bufB[j*128 + tx*4];
    float4 v1 = *(const float4*)&bufB[j*128 + 64 + tx*4];
    #pragma unroll
    for (int i = 0; i < 4; i++){
      ao[i][0] = fmaf(p[i], v0.x, ao[i][0]); ao[i][1] = fmaf(p[i], v0.y, ao[i][1]);
      ao[i][2] = fmaf(p[i], v0.z, ao[i][2]); ao[i][3] = fmaf(p[i], v0.w, ao[i][3]);
      ao[i][4] = fmaf(p[i], v1.x, ao[i][4]); ao[i][5] = fmaf(p[i], v1.y, ao[i][5]);
      ao[i][6] = fmaf(p[i], v1.z, ao[i][6]); ao[i][7] = fmaf(p[i], v1.w, ao[i][7]);
    }
  }
  size_t ybase = (size_t)(bt*64) * 512 + (size_t)h * 128;
  #pragma unroll
  for (int i = 0; i < 4; i++){
    int row = ty*4 + i;
    float4 o0 = {ao[i][0], ao[i][1], ao[i][2], ao[i][3]};
    float4 o1 = {ao[i][4], ao[i][5], ao[i][6], ao[i][7]};
    *(float4*)(y + ybase + (size_t)row*512 + tx*4) = o0;
    *(float4*)(y + ybase + (size_t)row*512 + 64 + tx*4) = o1;
  }
}

// ---------------- temporal causal attention (flash tiles): per (b,h), hd=64 ----------------
// qkv layout per row (1536): [k 0:512 | q 512:1024 | v 1024:1536]  (torch split order k,q,v)
// In-register online softmax: each thread owns a 4x4 fragment; 16 lanes share a row.
__global__ __launch_bounds__(256) void temporal_attn_kernel(
    const float* __restrict__ qkv, float* __restrict__ y)
{
  __shared__ float Qt[4096];     // Q^T [d][i], pre-scaled
  __shared__ float KV[4096];     // K^T [d][j], then V [j][d]
  __shared__ float S[64*65];     // P tile for the PV product
  int bx = blockIdx.x;
  // pair heavy and light causal tiles: (0,31),(1,30),... for CU load balance
  int qt = (bx & 1) ? (31 - (bx >> 1)) : (bx >> 1);
  int bh = blockIdx.y;
  int b = bh >> 3, h = bh & 7;
  int tid = threadIdx.x, tx = tid & 15, ty = tid >> 4;
  size_t rowbase = (size_t)(b * 2048) * 1536 + (size_t)h * 64;
  for (int e = tid; e < 1024; e += 256){
    int i = e >> 4, dc = (e & 15) * 4;
    float4 q4 = *(const float4*)(qkv + rowbase + (size_t)(qt*64 + i)*1536 + 512 + dc);
    Qt[(dc+0)*64+i] = q4.x*0.125f; Qt[(dc+1)*64+i] = q4.y*0.125f;
    Qt[(dc+2)*64+i] = q4.z*0.125f; Qt[(dc+3)*64+i] = q4.w*0.125f;
  }
  float m_old[4], l_sum[4], ao[4][4] = {};
  #pragma unroll
  for (int i = 0; i < 4; i++){ m_old[i] = -1e30f; l_sum[i] = 0.f; }
  for (int kt = 0; kt <= qt; kt++){
    __syncthreads();  // (A) prev PV reads of KV/S done; Q staged (first iter)
    for (int e = tid; e < 1024; e += 256){
      int j = e >> 4, dc = (e & 15) * 4;
      float4 k4 = *(const float4*)(qkv + rowbase + (size_t)(kt*64 + j)*1536 + dc);
      KV[(dc+0)*64+j] = k4.x; KV[(dc+1)*64+j] = k4.y; KV[(dc+2)*64+j] = k4.z; KV[(dc+3)*64+j] = k4.w;
    }
    __syncthreads();  // (B) K ready
    float sa[4][4] = {};
    for (int d = 0; d < 64; d++){
      float4 qa = *(const float4*)&Qt[d*64 + ty*4];
      float4 ka = *(const float4*)&KV[d*64 + tx*4];
      float av[4] = {qa.x, qa.y, qa.z, qa.w};
      float bv[4] = {ka.x, ka.y, ka.z, ka.w};
      #pragma unroll
      for (int i = 0; i < 4; i++)
        #pragma unroll
        for (int j = 0; j < 4; j++)
          sa[i][j] = fmaf(av[i], bv[j], sa[i][j]);
    }
    if (kt == qt){
      #pragma unroll
      for (int i = 0; i < 4; i++)
        #pragma unroll
        for (int j = 0; j < 4; j++)
          if (tx*4 + j > ty*4 + i) sa[i][j] = -1e30f;
    }
    // in-register online softmax
    #pragma unroll
    for (int i = 0; i < 4; i++){
      float mx = fmaxf(fmaxf(sa[i][0], sa[i][1]), fmaxf(sa[i][2], sa[i][3]));
      mx = rowMax16(mx);
      float mnew = fmaxf(m_old[i], mx);
      float corr = __expf(m_old[i] - mnew);
      float ps = 0.f;
      #pragma unroll
      for (int j = 0; j < 4; j++){ sa[i][j] = __expf(sa[i][j] - mnew); ps += sa[i][j]; }
      ps = rowSum16(ps);
      l_sum[i] = l_sum[i]*corr + ps;
      m_old[i] = mnew;
      #pragma unroll
      for (int j = 0; j < 4; j++) ao[i][j] *= corr;
    }
    __syncthreads();  // (C) QK reads of KV done -> V may overwrite; S free
    #pragma unroll
    for (int i = 0; i < 4; i++)
      #pragma unroll
      for (int j = 0; j < 4; j++)
        S[(ty*4+i)*65 + tx*4+j] = sa[i][j];
    for (int e = tid; e < 1024; e += 256){
      int j = e >> 4, dc = (e & 15) * 4;
      float4 v4 = *(const float4*)(qkv + rowbase + (size_t)(kt*64 + j)*1536 + 1024 + dc);
      *(float4*)&KV[j*64 + dc] = v4;
    }
    __syncthreads();  // (D) P and V ready
    for (int j = 0; j < 64; j++){
      float p[4];
      #pragma unroll
      for (int i = 0; i < 4; i++) p[i] = S[(ty*4+i)*65 + j];
      float4 vv = *(const float4*)&KV[j*64 + tx*4];
      #pragma unroll
      for (int i = 0; i < 4; i++){
        ao[i][0] = fmaf(p[i], vv.x, ao[i][0]); ao[i][1] = fmaf(p[i], vv.y, ao[i][1]);
        ao[i][2] = fmaf(p[i], vv.z, ao[i][2]); ao[i][3] = fmaf(p[i], vv.w, ao[i][3]);
      }
    }
  }
  #pragma unroll
  for (int i = 0; i < 4; i++){
    float invl = 1.f / l_sum[i];
    float4 o = {ao[i][0]*invl, ao[i][1]*invl, ao[i][2]*invl, ao[i][3]*invl};
    *(float4*)(y + (size_t)(b*2048 + qt*64 + ty*4 + i)*512 + h*64 + tx*4) = o;
  }
}

// ---------------- tf = mean over N of lnf(hid) ----------------
__global__ __launch_bounds__(256) void reduce_tf_kernel(const float* __restrict__ hid, float* __restrict__ tf){
  int bt = blockIdx.x, tid = threadIdx.x;
  for (int d = tid; d < 512; d += 256){
    float s = 0.f;
    for (int n = 0; n < 64; n++) s += hid[((size_t)bt*64 + n)*512 + d];
    tf[(size_t)bt*512 + d] = s * (1.f/64.f);
  }
}

// ---------------- heads: blocks 0..63 pf, 64..65 temporal, 66..67 spatial ----------------
__global__ __launch_bounds__(256) void head_kernel(
    const float* __restrict__ tf,
    const float* __restrict__ th_w1, const float* __restrict__ th_b1,
    const float* __restrict__ th_w2, const float* __restrict__ th_b2,
    const float* __restrict__ sh_w1, const float* __restrict__ sh_b1,
    const float* __restrict__ sh_w2, const float* __restrict__ sh_b2,
    const float* __restrict__ pf_w1, const float* __restrict__ pf_b1,
    const float* __restrict__ pf_w2, const float* __restrict__ pf_b2,
    float* __restrict__ out)
{
  __shared__ float z[512];
  __shared__ float red[4];
  int bi = blockIdx.x, tid = threadIdx.x;
  const float *w1, *b1, *w2, *b2;
  float* dst;
  if (bi < 64){
    w1 = pf_w1; b1 = pf_b1; w2 = pf_w2; b2 = pf_b2; dst = out + 4 + bi;
    z[tid]       = tf[(size_t)bi*512 + tid];
    z[tid + 256] = tf[(size_t)bi*512 + tid + 256];
  } else if (bi < 66){
    int b = bi - 64;
    w1 = th_w1; b1 = th_b1; w2 = th_w2; b2 = th_b2; dst = out + b;
    z[tid]       = tf[(size_t)(b*32 + 31)*512 + tid];
    z[tid + 256] = tf[(size_t)(b*32 + 31)*512 + tid + 256];
  } else {
    int b = bi - 66;
    w1 = sh_w1; b1 = sh_b1; w2 = sh_w2; b2 = sh_b2; dst = out + 2 + b;
    float s0 = 0.f, s1 = 0.f;
    for (int t = 0; t < 32; t++){
      s0 += tf[(size_t)(b*32 + t)*512 + tid];
      s1 += tf[(size_t)(b*32 + t)*512 + tid + 256];
    }
    z[tid] = s0 * (1.f/32.f); z[tid + 256] = s1 * (1.f/32.f);
  }
  __syncthreads();
  float a = b1[tid];
  const float* wrow = w1 + (size_t)tid * 512;
  for (int k = 0; k < 512; k++) a = fmaf(wrow[k], z[k], a);
  a = (a > 0.f) ? a : 0.2f * a;
  float s = blockReduceSum(a * w2[tid], red);
  if (tid == 0) *dst = s + b2[0];
}

__global__ __launch_bounds__(64) void final_kernel(float* __restrict__ out){
  int b = threadIdx.x;
  if (b < 2){
    float s = 0.f;
    for (int t = 0; t < 32; t++) s += out[4 + b*32 + t];
    out[68 + b] = out[b] + out[2 + b] + s * (1.f/32.f);
  }
}

extern "C" void kernel_launch(void* const* d_in, const int* in_sizes, int n_in,
                              void* d_out, int out_size, void* d_ws, size_t ws_size,
                              hipStream_t stream)
{
  const float* x          = (const float*)d_in[0];
  const float* patch_w    = (const float*)d_in[1];
  const float* patch_b    = (const float*)d_in[2];
  const float* tok_ln_g   = (const float*)d_in[3];
  const float* tok_ln_b   = (const float*)d_in[4];
  const float* spatial_pos= (const float*)d_in[5];
  const float* temporal_pos=(const float*)d_in[6];
  const float* snorm_g    = (const float*)d_in[7];
  const float* snorm_b    = (const float*)d_in[8];
  const float* sa_in_w    = (const float*)d_in[9];
  const float* sa_in_b    = (const float*)d_in[10];
  const float* sa_out_w   = (const float*)d_in[11];
  const float* sa_out_b   = (const float*)d_in[12];
  const float* ln1_g      = (const float*)d_in[13];
  const float* ln1_b      = (const float*)d_in[14];
  const float* kqv_w      = (const float*)d_in[15];
  const float* kqv_b      = (const float*)d_in[16];
  const float* proj_w     = (const float*)d_in[17];
  const float* proj_b     = (const float*)d_in[18];
  const float* ln2_g      = (const float*)d_in[19];
  const float* ln2_b      = (const float*)d_in[20];
  const float* fc_w       = (const float*)d_in[21];
  const float* fc_b       = (const float*)d_in[22];
  const float* cproj_w    = (const float*)d_in[23];
  const float* cproj_b    = (const float*)d_in[24];
  const float* lnf_g      = (const float*)d_in[25];
  const float* lnf_b      = (const float*)d_in[26];
  const float* th_w1 = (const float*)d_in[27];
  const float* th_b1 = (const float*)d_in[28];
  const float* th_w2 = (const float*)d_in[29];
  const float* th_b2 = (const float*)d_in[30];
  const float* sh_w1 = (const float*)d_in[31];
  const float* sh_b1 = (const float*)d_in[32];
  const float* sh_w2 = (const float*)d_in[33];
  const float* sh_b2 = (const float*)d_in[34];
  const float* pf_w1 = (const float*)d_in[35];
  const float* pf_b1 = (const float*)d_in[36];
  const float* pf_w2 = (const float*)d_in[37];
  const float* pf_b2 = (const float*)d_in[38];

  float* out = (float*)d_out;
  float* A  = (float*)d_ws;                   // hidden state, 4096x512
  float* Bf = A  + (size_t)MTOK*512;          // ln output,   4096x512
  float* Cf = Bf + (size_t)MTOK*512;          // qkv/fc,      4096x2048
  float* Ef = Cf + (size_t)MTOK*2048;         // attn y,      4096x512
  float* tf = Ef + (size_t)MTOK*512;          // 64x512

  // patch embed + tok LN + pos
  patch_embed_kernel<<<MTOK, 256, 0, stream>>>(x, patch_w, patch_b, tok_ln_g, tok_ln_b,
                                               spatial_pos, temporal_pos, A);
  // spatial layers
  for (int i = 0; i < 3; i++){
    ln_kernel<<<MTOK, 256, 0, stream>>>(A, Bf, snorm_g, snorm_b);
    gemm_kernel<false><<<dim3(1536/64, MTOK/64), 256, 0, stream>>>(
        Bf, sa_in_w + (size_t)i*1536*512, sa_in_b + (size_t)i*1536, nullptr, Cf, MTOK, 1536, 512);
    spatial_attn_kernel<<<dim3(64, 4), 256, 0, stream>>>(Cf, Ef);
    gemm_kernel<false><<<dim3(512/64, MTOK/64), 256, 0, stream>>>(
        Ef, sa_out_w + (size_t)i*512*512, sa_out_b + (size_t)i*512, A, A, MTOK, 512, 512);
  }
  // temporal layers
  for (int i = 0; i < 6; i++){
    ln_kernel<<<MTOK, 256, 0, stream>>>(A, Bf, ln1_g + (size_t)i*512, ln1_b + (size_t)i*512);
    gemm_kernel<false><<<dim3(1536/64, MTOK/64), 256, 0, stream>>>(
        Bf, kqv_w + (size_t)i*1536*512, kqv_b + (size_t)i*1536, nullptr, Cf, MTOK, 1536, 512);
    temporal_attn_kernel<<<dim3(32, 16), 256, 0, stream>>>(Cf, Ef);
    gemm_kernel<false><<<dim3(512/64, MTOK/64), 256, 0, stream>>>(
        Ef, proj_w + (size_t)i*512*512, proj_b + (size_t)i*512, A, A, MTOK, 512, 512);
    ln_kernel<<<MTOK, 256, 0, stream>>>(A, Bf, ln2_g + (size_t)i*512, ln2_b + (size_t)i*512);
    gemm_kernel<true><<<dim3(2048/64, MTOK/64), 256, 0, stream>>>(
        Bf, fc_w + (size_t)i*2048*512, fc_b + (size_t)i*2048, nullptr, Cf, MTOK, 2048, 512);
    gemm_kernel<false><<<dim3(512/64, MTOK/64), 256, 0, stream>>>(
        Cf, cproj_w + (size_t)i*512*2048, cproj_b + (size_t)i*512, A, A, MTOK, 512, 2048);
  }
  // final LN + heads
  ln_kernel<<<MTOK, 256, 0, stream>>>(A, Bf, lnf_g, lnf_b);
  reduce_tf_kernel<<<64, 256, 0, stream>>>(Bf, tf);
  head_kernel<<<68, 256, 0, stream>>>(tf, th_w1, th_b1, th_w2, th_b2,
                                      sh_w1, sh_b1, sh_w2, sh_b2,
                                      pf_w1, pf_b1, pf_w2, pf_b2, out);
  final_kernel<<<1, 64, 0, stream>>>(out);
}

// Round 3
// 3995.573 us; speedup vs baseline: 1.9640x; 1.2641x over previous
//
#include <hip/hip_runtime.h>
#include <hip/hip_bf16.h>
#include <math.h>

// Sizes: B=2 T=32 C=3 H=W=64 P=8 -> N=64, D=512, L=2048, M=B*T*N=4096
#define MTOK 4096

typedef __bf16 bf16x8 __attribute__((ext_vector_type(8)));
typedef float f32x4 __attribute__((ext_vector_type(4)));

__device__ __forceinline__ ushort f2bf(float f){
  __hip_bfloat16 h = __float2bfloat16(f);
  return *reinterpret_cast<ushort*>(&h);
}
__device__ __forceinline__ float bf2f(ushort u){
  return __uint_as_float(((uint)u) << 16);
}
__device__ __forceinline__ void gload_lds16(const void* g, void* l){
  __builtin_amdgcn_global_load_lds((__attribute__((address_space(1))) void*)(void*)g,
                                   (__attribute__((address_space(3))) void*)l, 16, 0, 0);
}

__device__ __forceinline__ float blockReduceSum(float v, float* red){
  #pragma unroll
  for (int off = 32; off; off >>= 1) v += __shfl_down(v, off, 64);
  int lane = threadIdx.x & 63, wid = threadIdx.x >> 6;
  __syncthreads();
  if (lane == 0) red[wid] = v;
  __syncthreads();
  float r = 0.f;
  int nw = blockDim.x >> 6;
  for (int i = 0; i < nw; i++) r += red[i];
  return r;
}
__device__ __forceinline__ float rowMax16(float v){
  #pragma unroll
  for (int m = 8; m; m >>= 1) v = fmaxf(v, __shfl_xor(v, m, 64));
  return v;
}
__device__ __forceinline__ float rowSum16(float v){
  #pragma unroll
  for (int m = 8; m; m >>= 1) v += __shfl_xor(v, m, 64);
  return v;
}

// ---------------- patch embed + LN + pos (fp32, writes A) ----------------
__global__ __launch_bounds__(256) void patch_embed_kernel(
    const float* __restrict__ x, const float* __restrict__ pw, const float* __restrict__ pb,
    const float* __restrict__ g, const float* __restrict__ bta,
    const float* __restrict__ spos, const float* __restrict__ tpos, float* __restrict__ out)
{
  int m = blockIdx.x;
  int b = m >> 11, t = (m >> 6) & 31, n = m & 63;
  int hn = n >> 3, wn = n & 7;
  __shared__ float patch[192];
  __shared__ float red[4];
  int tid = threadIdx.x;
  if (tid < 192){
    int c = tid / 64, rem = tid & 63;
    int ph = rem >> 3, pwj = rem & 7;
    patch[tid] = x[(((size_t)(b*32 + t)*3 + c)*64 + hn*8 + ph)*64 + wn*8 + pwj];
  }
  __syncthreads();
  float e0 = pb[tid], e1 = pb[tid + 256];
  const float* r0 = pw + (size_t)tid*192;
  const float* r1 = pw + (size_t)(tid + 256)*192;
  for (int k = 0; k < 192; k++){ float p = patch[k]; e0 = fmaf(p, r0[k], e0); e1 = fmaf(p, r1[k], e1); }
  float s = blockReduceSum(e0 + e1, red);
  float mu = s * (1.f/512.f);
  float d0 = e0 - mu, d1 = e1 - mu;
  float vv = blockReduceSum(d0*d0 + d1*d1, red);
  float inv = rsqrtf(vv * (1.f/512.f) + 1e-5f);
  size_t o = (size_t)m * 512;
  out[o + tid]       = d0*inv*g[tid]       + bta[tid]       + spos[n*512 + tid]       + tpos[t*512 + tid];
  out[o + tid + 256] = d1*inv*g[tid + 256] + bta[tid + 256] + spos[n*512 + tid + 256] + tpos[t*512 + tid + 256];
}

// ---------------- LayerNorm (D=512) fp32 in -> bf16 out ----------------
__global__ __launch_bounds__(256) void ln_bf16_kernel(
    const float* __restrict__ in, ushort* __restrict__ out,
    const float* __restrict__ g, const float* __restrict__ b)
{
  int r = blockIdx.x, tid = threadIdx.x;
  const float* row = in + (size_t)r * 512;
  float2 v = *(const float2*)(row + tid*2);
  __shared__ float red[4];
  float s = blockReduceSum(v.x + v.y, red);
  float mu = s * (1.f/512.f);
  float dx = v.x - mu, dy = v.y - mu;
  float vv = blockReduceSum(dx*dx + dy*dy, red);
  float inv = rsqrtf(vv * (1.f/512.f) + 1e-5f);
  float2 gg = *(const float2*)(g + tid*2);
  float2 bb = *(const float2*)(b + tid*2);
  ushort2 o2; o2.x = f2bf(dx*inv*gg.x + bb.x); o2.y = f2bf(dy*inv*gg.y + bb.y);
  *(ushort2*)(out + (size_t)r*512 + tid*2) = o2;
}

// ---------------- MFMA GEMM: Y[M,N] = X[M,K](bf16) @ W[N,K](f32->bf16)^T + bias (+res)(+gelu) ----------------
// 128x128 tile, BK=64, 4 waves (2x2), each wave 64x64 = 4x4 fragments of 16x16x32.
// X staged via global_load_lds (linear LDS dest, pre-swizzled global src);
// W reg-staged with inline f32->bf16 cvt and swizzled ds_write.
// Swizzle: byte_in_row ^= (row&7)<<4   (row stride = 128B)
template<bool GELU, bool BF16OUT>
__global__ __launch_bounds__(256) void gemm_bf16_kernel(
    const ushort* __restrict__ X, const float* __restrict__ W,
    const float* __restrict__ bias, const float* __restrict__ res,
    void* __restrict__ Yv, int M, int Nn, int K)
{
  __shared__ char smem[32768];
  char* Xs = smem;
  char* Ws = smem + 16384;
  int tid = threadIdx.x, lane = tid & 63, wv = tid >> 6;
  int bm = blockIdx.y * 128, bn = blockIdx.x * 128;
  int wm = (wv >> 1) * 64, wn = (wv & 1) * 64;

  f32x4 zero4 = {0.f, 0.f, 0.f, 0.f};
  f32x4 acc[4][4];
  #pragma unroll
  for (int i = 0; i < 4; i++)
    #pragma unroll
    for (int j = 0; j < 4; j++) acc[i][j] = zero4;

  int xrow_off = wv*8 + (lane >> 3);                     // row within 32-row chunk
  int xcolsrc  = (((lane & 7) ^ (lane >> 3)) * 16);      // pre-swizzled source byte col
  int wrow0 = tid >> 2;                                  // 0..63
  int wkseg = (tid & 3) * 16;                            // k offset in elems

  for (int k0 = 0; k0 < K; k0 += 64){
    __syncthreads();   // previous compute's ds_reads done
    // stage X (4 x global_load_lds per wave)
    #pragma unroll
    for (int i = 0; i < 4; i++){
      int row = i*32 + xrow_off;
      const char* src = (const char*)(X + (size_t)(bm + row)*K + k0) + xcolsrc;
      char* dst = Xs + (i*32 + wv*8)*128;
      gload_lds16(src, dst);
    }
    // stage W (2 rows x 16 k per thread), inline cvt + swizzled ds_write_b128
    #pragma unroll
    for (int i = 0; i < 2; i++){
      int row = wrow0 + i*64;
      const float* src = W + (size_t)(bn + row)*K + k0 + wkseg;
      float4 v0 = *(const float4*)(src);
      float4 v1 = *(const float4*)(src + 4);
      float4 v2 = *(const float4*)(src + 8);
      float4 v3 = *(const float4*)(src + 12);
      uint4 w0, w1;
      w0.x = (uint)f2bf(v0.x) | ((uint)f2bf(v0.y) << 16);
      w0.y = (uint)f2bf(v0.z) | ((uint)f2bf(v0.w) << 16);
      w0.z = (uint)f2bf(v1.x) | ((uint)f2bf(v1.y) << 16);
      w0.w = (uint)f2bf(v1.z) | ((uint)f2bf(v1.w) << 16);
      w1.x = (uint)f2bf(v2.x) | ((uint)f2bf(v2.y) << 16);
      w1.y = (uint)f2bf(v2.z) | ((uint)f2bf(v2.w) << 16);
      w1.z = (uint)f2bf(v3.x) | ((uint)f2bf(v3.y) << 16);
      w1.w = (uint)f2bf(v3.z) | ((uint)f2bf(v3.w) << 16);
      int swz = (row & 7) << 4;
      char* base = Ws + row*128;
      *(uint4*)(base + ((wkseg*2)      ^ swz)) = w0;
      *(uint4*)(base + ((wkseg*2 + 16) ^ swz)) = w1;
    }
    __syncthreads();   // drains vmcnt+lgkm: tiles ready
    #pragma unroll
    for (int kc = 0; kc < 2; kc++){
      bf16x8 a[4], b[4];
      #pragma unroll
      for (int f = 0; f < 4; f++){
        int ra = wm + f*16 + (lane & 15);
        a[f] = *(const bf16x8*)(Xs + ra*128 + ((kc*64 + (lane>>4)*16) ^ ((ra & 7) << 4)));
        int rb = wn + f*16 + (lane & 15);
        b[f] = *(const bf16x8*)(Ws + rb*128 + ((kc*64 + (lane>>4)*16) ^ ((rb & 7) << 4)));
      }
      #pragma unroll
      for (int i = 0; i < 4; i++)
        #pragma unroll
        for (int j = 0; j < 4; j++)
          acc[i][j] = __builtin_amdgcn_mfma_f32_16x16x32_bf16(a[i], b[j], acc[i][j], 0, 0, 0);
    }
  }
  // epilogue: C/D layout col = lane&15, row = (lane>>4)*4 + reg
  int col0 = lane & 15;
  float bv[4];
  #pragma unroll
  for (int fn = 0; fn < 4; fn++) bv[fn] = bias[bn + wn + fn*16 + col0];
  #pragma unroll
  for (int fm = 0; fm < 4; fm++){
    #pragma unroll
    for (int r = 0; r < 4; r++){
      int m = bm + wm + fm*16 + (lane >> 4)*4 + r;
      #pragma unroll
      for (int fn = 0; fn < 4; fn++){
        int n = bn + wn + fn*16 + col0;
        float v = acc[fm][fn][r] + bv[fn];
        if (res) v += res[(size_t)m*Nn + n];
        if (GELU) v = 0.5f * v * (1.f + erff(v * 0.70710678118654752440f));
        if (BF16OUT) ((ushort*)Yv)[(size_t)m*Nn + n] = f2bf(v);
        else         ((float*) Yv)[(size_t)m*Nn + n] = v;
      }
    }
  }
}

// ---------------- spatial attention: per (frame, head), N=64, hd=128, fp32 math, bf16 out ----------------
// qkv row (1536): [q 0:512 | k 512:1024 | v 1024:1536]
__global__ __launch_bounds__(256) void spatial_attn_kernel(
    const float* __restrict__ qkv, ushort* __restrict__ y)
{
  __shared__ float bufA[8192];
  __shared__ float bufB[8192];
  int bt = blockIdx.x, h = blockIdx.y;
  int tid = threadIdx.x, tx = tid & 15, ty = tid >> 4;
  const float scale = 0.08838834764831845f;  // 1/sqrt(128)
  size_t base = (size_t)bt * 64 * 1536 + (size_t)h * 128;
  for (int e = tid; e < 2048; e += 256){
    int i = e >> 5, dc = (e & 31) * 4;
    const float* qp = qkv + base + (size_t)i*1536 + dc;
    float4 q4 = *(const float4*)qp;
    float4 k4 = *(const float4*)(qp + 512);
    bufA[(dc+0)*64+i] = q4.x; bufA[(dc+1)*64+i] = q4.y; bufA[(dc+2)*64+i] = q4.z; bufA[(dc+3)*64+i] = q4.w;
    bufB[(dc+0)*64+i] = k4.x; bufB[(dc+1)*64+i] = k4.y; bufB[(dc+2)*64+i] = k4.z; bufB[(dc+3)*64+i] = k4.w;
  }
  __syncthreads();
  float acc[4][4] = {};
  for (int d = 0; d < 128; d++){
    float4 qa = *(const float4*)&bufA[d*64 + ty*4];
    float4 ka = *(const float4*)&bufB[d*64 + tx*4];
    float av[4] = {qa.x, qa.y, qa.z, qa.w};
    float bvv[4] = {ka.x, ka.y, ka.z, ka.w};
    #pragma unroll
    for (int i = 0; i < 4; i++)
      #pragma unroll
      for (int j = 0; j < 4; j++)
        acc[i][j] = fmaf(av[i], bvv[j], acc[i][j]);
  }
  float pnorm[4];
  #pragma unroll
  for (int i = 0; i < 4; i++){
    float mx = fmaxf(fmaxf(acc[i][0], acc[i][1]), fmaxf(acc[i][2], acc[i][3]));
    mx = rowMax16(mx);
    float ps = 0.f;
    #pragma unroll
    for (int j = 0; j < 4; j++){ acc[i][j] = __expf(acc[i][j]*scale - mx*scale); ps += acc[i][j]; }
    ps = rowSum16(ps);
    pnorm[i] = 1.f / ps;
  }
  __syncthreads();
  #pragma unroll
  for (int i = 0; i < 4; i++)
    #pragma unroll
    for (int j = 0; j < 4; j++)
      bufA[(ty*4+i)*65 + tx*4+j] = acc[i][j] * pnorm[i];
  for (int e = tid; e < 2048; e += 256){
    int j = e >> 5, dc = (e & 31) * 4;
    float4 v4 = *(const float4*)(qkv + base + (size_t)j*1536 + 1024 + dc);
    *(float4*)&bufB[j*128 + dc] = v4;
  }
  __syncthreads();
  float ao[4][8] = {};
  for (int j = 0; j < 64; j++){
    float p[4];
    #pragma unroll
    for (int i = 0; i < 4; i++) p[i] = bufA[(ty*4+i)*65 + j];
    float4 v0 = *(const float4*)&bufB[j*128 + tx*4];
    float4 v1 = *(const float4*)&bufB[j*128 + 64 + tx*4];
    #pragma unroll
    for (int i = 0; i < 4; i++){
      ao[i][0] = fmaf(p[i], v0.x, ao[i][0]); ao[i][1] = fmaf(p[i], v0.y, ao[i][1]);
      ao[i][2] = fmaf(p[i], v0.z, ao[i][2]); ao[i][3] = fmaf(p[i], v0.w, ao[i][3]);
      ao[i][4] = fmaf(p[i], v1.x, ao[i][4]); ao[i][5] = fmaf(p[i], v1.y, ao[i][5]);
      ao[i][6] = fmaf(p[i], v1.z, ao[i][6]); ao[i][7] = fmaf(p[i], v1.w, ao[i][7]);
    }
  }
  size_t ybase = (size_t)(bt*64) * 512 + (size_t)h * 128;
  #pragma unroll
  for (int i = 0; i < 4; i++){
    int row = ty*4 + i;
    ushort4 o0; o0.x=f2bf(ao[i][0]); o0.y=f2bf(ao[i][1]); o0.z=f2bf(ao[i][2]); o0.w=f2bf(ao[i][3]);
    ushort4 o1; o1.x=f2bf(ao[i][4]); o1.y=f2bf(ao[i][5]); o1.z=f2bf(ao[i][6]); o1.w=f2bf(ao[i][7]);
    *(ushort4*)(y + ybase + (size_t)row*512 + tx*4) = o0;
    *(ushort4*)(y + ybase + (size_t)row*512 + 64 + tx*4) = o1;
  }
}

// ---------------- temporal causal attention: QBLK=32, KBLK=64, fp32 math, bf16 out ----------------
// qkv row (1536): [k 0:512 | q 512:1024 | v 1024:1536]  (torch split order k,q,v)
__global__ __launch_bounds__(256) void temporal_attn_kernel(
    const float* __restrict__ qkv, ushort* __restrict__ y)
{
  __shared__ float Qt[64*32];     // Q^T [d][i], pre-scaled
  __shared__ float KV[64*64];     // K^T [d][j], then V [j][d]
  __shared__ float S[32*65];
  int bx = blockIdx.x;            // 0..63
  int qt = (bx & 1) ? (63 - (bx >> 1)) : (bx >> 1);
  int bh = blockIdx.y;
  int b = bh >> 3, h = bh & 7;
  int tid = threadIdx.x, tx = tid & 15, ty = tid >> 4;
  size_t rowbase = (size_t)(b * 2048) * 1536 + (size_t)h * 64;
  for (int e = tid; e < 512; e += 256){
    int i = e >> 4, dc = (e & 15) * 4;
    float4 q4 = *(const float4*)(qkv + rowbase + (size_t)(qt*32 + i)*1536 + 512 + dc);
    Qt[(dc+0)*32+i] = q4.x*0.125f; Qt[(dc+1)*32+i] = q4.y*0.125f;
    Qt[(dc+2)*32+i] = q4.z*0.125f; Qt[(dc+3)*32+i] = q4.w*0.125f;
  }
  float m_old[2] = {-1e30f, -1e30f}, l_sum[2] = {0.f, 0.f}, ao[2][4] = {};
  int ktmax = qt >> 1;
  for (int kt = 0; kt <= ktmax; kt++){
    __syncthreads();   // prev PV reads done; Q staged on first iter
    for (int e = tid; e < 1024; e += 256){
      int j = e >> 4, dc = (e & 15) * 4;
      float4 k4 = *(const float4*)(qkv + rowbase + (size_t)(kt*64 + j)*1536 + dc);
      KV[(dc+0)*64+j] = k4.x; KV[(dc+1)*64+j] = k4.y; KV[(dc+2)*64+j] = k4.z; KV[(dc+3)*64+j] = k4.w;
    }
    __syncthreads();   // K ready
    float sa[2][4] = {};
    for (int d = 0; d < 64; d++){
      float2 qa = *(const float2*)&Qt[d*32 + ty*2];
      float4 ka = *(const float4*)&KV[d*64 + tx*4];
      sa[0][0] = fmaf(qa.x, ka.x, sa[0][0]); sa[0][1] = fmaf(qa.x, ka.y, sa[0][1]);
      sa[0][2] = fmaf(qa.x, ka.z, sa[0][2]); sa[0][3] = fmaf(qa.x, ka.w, sa[0][3]);
      sa[1][0] = fmaf(qa.y, ka.x, sa[1][0]); sa[1][1] = fmaf(qa.y, ka.y, sa[1][1]);
      sa[1][2] = fmaf(qa.y, ka.z, sa[1][2]); sa[1][3] = fmaf(qa.y, ka.w, sa[1][3]);
    }
    if (kt == ktmax){
      int gi0 = qt*32 + ty*2, gj0 = kt*64 + tx*4;
      #pragma unroll
      for (int i = 0; i < 2; i++)
        #pragma unroll
        for (int j = 0; j < 4; j++)
          if (gj0 + j > gi0 + i) sa[i][j] = -1e30f;
    }
    #pragma unroll
    for (int i = 0; i < 2; i++){
      float mx = fmaxf(fmaxf(sa[i][0], sa[i][1]), fmaxf(sa[i][2], sa[i][3]));
      mx = rowMax16(mx);
      float mnew = fmaxf(m_old[i], mx);
      float corr = __expf(m_old[i] - mnew);
      float ps = 0.f;
      #pragma unroll
      for (int j = 0; j < 4; j++){ sa[i][j] = __expf(sa[i][j] - mnew); ps += sa[i][j]; }
      ps = rowSum16(ps);
      l_sum[i] = l_sum[i]*corr + ps;
      m_old[i] = mnew;
      #pragma unroll
      for (int j = 0; j < 4; j++) ao[i][j] *= corr;
    }
    __syncthreads();   // QK reads of KV done -> V may overwrite; S free
    #pragma unroll
    for (int i = 0; i < 2; i++)
      #pragma unroll
      for (int j = 0; j < 4; j++)
        S[(ty*2+i)*65 + tx*4+j] = sa[i][j];
    for (int e = tid; e < 1024; e += 256){
      int j = e >> 4, dc = (e & 15) * 4;
      float4 v4 = *(const float4*)(qkv + rowbase + (size_t)(kt*64 + j)*1536 + 1024 + dc);
      *(float4*)&KV[j*64 + dc] = v4;
    }
    __syncthreads();   // P and V ready
    for (int j = 0; j < 64; j++){
      float p0 = S[(ty*2)*65 + j];
      float p1 = S[(ty*2+1)*65 + j];
      float4 vv = *(const float4*)&KV[j*64 + tx*4];
      ao[0][0] = fmaf(p0, vv.x, ao[0][0]); ao[0][1] = fmaf(p0, vv.y, ao[0][1]);
      ao[0][2] = fmaf(p0, vv.z, ao[0][2]); ao[0][3] = fmaf(p0, vv.w, ao[0][3]);
      ao[1][0] = fmaf(p1, vv.x, ao[1][0]); ao[1][1] = fmaf(p1, vv.y, ao[1][1]);
      ao[1][2] = fmaf(p1, vv.z, ao[1][2]); ao[1][3] = fmaf(p1, vv.w, ao[1][3]);
    }
  }
  #pragma unroll
  for (int i = 0; i < 2; i++){
    float invl = 1.f / l_sum[i];
    ushort4 o; o.x = f2bf(ao[i][0]*invl); o.y = f2bf(ao[i][1]*invl);
    o.z = f2bf(ao[i][2]*invl); o.w = f2bf(ao[i][3]*invl);
    *(ushort4*)(y + (size_t)(b*2048 + qt*32 + ty*2 + i)*512 + h*64 + tx*4) = o;
  }
}

// ---------------- tf = mean over N of lnf(hid) (bf16 in, f32 out) ----------------
__global__ __launch_bounds__(256) void reduce_tf_kernel(const ushort* __restrict__ hid, float* __restrict__ tf){
  int bt = blockIdx.x, tid = threadIdx.x;
  for (int d = tid; d < 512; d += 256){
    float s = 0.f;
    for (int n = 0; n < 64; n++) s += bf2f(hid[((size_t)bt*64 + n)*512 + d]);
    tf[(size_t)bt*512 + d] = s * (1.f/64.f);
  }
}

// ---------------- heads ----------------
__global__ __launch_bounds__(256) void head_kernel(
    const float* __restrict__ tf,
    const float* __restrict__ th_w1, const float* __restrict__ th_b1,
    const float* __restrict__ th_w2, const float* __restrict__ th_b2,
    const float* __restrict__ sh_w1, const float* __restrict__ sh_b1,
    const float* __restrict__ sh_w2, const float* __restrict__ sh_b2,
    const float* __restrict__ pf_w1, const float* __restrict__ pf_b1,
    const float* __restrict__ pf_w2, const float* __restrict__ pf_b2,
    float* __restrict__ out)
{
  __shared__ float z[512];
  __shared__ float red[4];
  int bi = blockIdx.x, tid = threadIdx.x;
  const float *w1, *b1, *w2, *b2;
  float* dst;
  if (bi < 64){
    w1 = pf_w1; b1 = pf_b1; w2 = pf_w2; b2 = pf_b2; dst = out + 4 + bi;
    z[tid]       = tf[(size_t)bi*512 + tid];
    z[tid + 256] = tf[(size_t)bi*512 + tid + 256];
  } else if (bi < 66){
    int b = bi - 64;
    w1 = th_w1; b1 = th_b1; w2 = th_w2; b2 = th_b2; dst = out + b;
    z[tid]       = tf[(size_t)(b*32 + 31)*512 + tid];
    z[tid + 256] = tf[(size_t)(b*32 + 31)*512 + tid + 256];
  } else {
    int b = bi - 66;
    w1 = sh_w1; b1 = sh_b1; w2 = sh_w2; b2 = sh_b2; dst = out + 2 + b;
    float s0 = 0.f, s1 = 0.f;
    for (int t = 0; t < 32; t++){
      s0 += tf[(size_t)(b*32 + t)*512 + tid];
      s1 += tf[(size_t)(b*32 + t)*512 + tid + 256];
    }
    z[tid] = s0 * (1.f/32.f); z[tid + 256] = s1 * (1.f/32.f);
  }
  __syncthreads();
  float a = b1[tid];
  const float* wrow = w1 + (size_t)tid * 512;
  for (int k = 0; k < 512; k++) a = fmaf(wrow[k], z[k], a);
  a = (a > 0.f) ? a : 0.2f * a;
  float s = blockReduceSum(a * w2[tid], red);
  if (tid == 0) *dst = s + b2[0];
}

__global__ __launch_bounds__(64) void final_kernel(float* __restrict__ out){
  int b = threadIdx.x;
  if (b < 2){
    float s = 0.f;
    for (int t = 0; t < 32; t++) s += out[4 + b*32 + t];
    out[68 + b] = out[b] + out[2 + b] + s * (1.f/32.f);
  }
}

extern "C" void kernel_launch(void* const* d_in, const int* in_sizes, int n_in,
                              void* d_out, int out_size, void* d_ws, size_t ws_size,
                              hipStream_t stream)
{
  const float* x          = (const float*)d_in[0];
  const float* patch_w    = (const float*)d_in[1];
  const float* patch_b    = (const float*)d_in[2];
  const float* tok_ln_g   = (const float*)d_in[3];
  const float* tok_ln_b   = (const float*)d_in[4];
  const float* spatial_pos= (const float*)d_in[5];
  const float* temporal_pos=(const float*)d_in[6];
  const float* snorm_g    = (const float*)d_in[7];
  const float* snorm_b    = (const float*)d_in[8];
  const float* sa_in_w    = (const float*)d_in[9];
  const float* sa_in_b    = (const float*)d_in[10];
  const float* sa_out_w   = (const float*)d_in[11];
  const float* sa_out_b   = (const float*)d_in[12];
  const float* ln1_g      = (const float*)d_in[13];
  const float* ln1_b      = (const float*)d_in[14];
  const float* kqv_w      = (const float*)d_in[15];
  const float* kqv_b      = (const float*)d_in[16];
  const float* proj_w     = (const float*)d_in[17];
  const float* proj_b     = (const float*)d_in[18];
  const float* ln2_g      = (const float*)d_in[19];
  const float* ln2_b      = (const float*)d_in[20];
  const float* fc_w       = (const float*)d_in[21];
  const float* fc_b       = (const float*)d_in[22];
  const float* cproj_w    = (const float*)d_in[23];
  const float* cproj_b    = (const float*)d_in[24];
  const float* lnf_g      = (const float*)d_in[25];
  const float* lnf_b      = (const float*)d_in[26];
  const float* th_w1 = (const float*)d_in[27];
  const float* th_b1 = (const float*)d_in[28];
  const float* th_w2 = (const float*)d_in[29];
  const float* th_b2 = (const float*)d_in[30];
  const float* sh_w1 = (const float*)d_in[31];
  const float* sh_b1 = (const float*)d_in[32];
  const float* sh_w2 = (const float*)d_in[33];
  const float* sh_b2 = (const float*)d_in[34];
  const float* pf_w1 = (const float*)d_in[35];
  const float* pf_b1 = (const float*)d_in[36];
  const float* pf_w2 = (const float*)d_in[37];
  const float* pf_b2 = (const float*)d_in[38];

  float* out = (float*)d_out;
  // workspace layout (f32 slots)
  float*  A  = (float*)d_ws;                         // 4096x512 f32 hidden
  float*  Cf = A + (size_t)MTOK*512;                 // 4096x1536 f32 qkv (aliased: gelu bf16 4096x2048)
  ushort* Bf = (ushort*)(Cf + (size_t)MTOK*1536);    // 4096x512 bf16 (ln out)
  ushort* Ef = Bf + (size_t)MTOK*512;                // 4096x512 bf16 (attn out)
  float*  tf = (float*)(Ef + (size_t)MTOK*512);      // 64x512 f32
  ushort* Gf = (ushort*)Cf;                          // gelu bf16 4096x2048 (alias, stream-ordered safe)

  patch_embed_kernel<<<MTOK, 256, 0, stream>>>(x, patch_w, patch_b, tok_ln_g, tok_ln_b,
                                               spatial_pos, temporal_pos, A);
  // spatial layers
  for (int i = 0; i < 3; i++){
    ln_bf16_kernel<<<MTOK, 256, 0, stream>>>(A, Bf, snorm_g, snorm_b);
    gemm_bf16_kernel<false,false><<<dim3(1536/128, MTOK/128), 256, 0, stream>>>(
        Bf, sa_in_w + (size_t)i*1536*512, sa_in_b + (size_t)i*1536, nullptr, Cf, MTOK, 1536, 512);
    spatial_attn_kernel<<<dim3(64, 4), 256, 0, stream>>>(Cf, Ef);
    gemm_bf16_kernel<false,false><<<dim3(512/128, MTOK/128), 256, 0, stream>>>(
        Ef, sa_out_w + (size_t)i*512*512, sa_out_b + (size_t)i*512, A, A, MTOK, 512, 512);
  }
  // temporal layers
  for (int i = 0; i < 6; i++){
    ln_bf16_kernel<<<MTOK, 256, 0, stream>>>(A, Bf, ln1_g + (size_t)i*512, ln1_b + (size_t)i*512);
    gemm_bf16_kernel<false,false><<<dim3(1536/128, MTOK/128), 256, 0, stream>>>(
        Bf, kqv_w + (size_t)i*1536*512, kqv_b + (size_t)i*1536, nullptr, Cf, MTOK, 1536, 512);
    temporal_attn_kernel<<<dim3(64, 16), 256, 0, stream>>>(Cf, Ef);
    gemm_bf16_kernel<false,false><<<dim3(512/128, MTOK/128), 256, 0, stream>>>(
        Ef, proj_w + (size_t)i*512*512, proj_b + (size_t)i*512, A, A, MTOK, 512, 512);
    ln_bf16_kernel<<<MTOK, 256, 0, stream>>>(A, Bf, ln2_g + (size_t)i*512, ln2_b + (size_t)i*512);
    gemm_bf16_kernel<true,true><<<dim3(2048/128, MTOK/128), 256, 0, stream>>>(
        Bf, fc_w + (size_t)i*2048*512, fc_b + (size_t)i*2048, nullptr, Gf, MTOK, 2048, 512);
    gemm_bf16_kernel<false,false><<<dim3(512/128, MTOK/128), 256, 0, stream>>>(
        Gf, cproj_w + (size_t)i*512*2048, cproj_b + (size_t)i*512, A, A, MTOK, 512, 2048);
  }
  // final LN + heads
  ln_bf16_kernel<<<MTOK, 256, 0, stream>>>(A, Bf, lnf_g, lnf_b);
  reduce_tf_kernel<<<64, 256, 0, stream>>>(Bf, tf);
  head_kernel<<<68, 256, 0, stream>>>(tf, th_w1, th_b1, th_w2, th_b2,
                                      sh_w1, sh_b1, sh_w2, sh_b2,
                                      pf_w1, pf_b1, pf_w2, pf_b2, out);
  final_kernel<<<1, 64, 0, stream>>>(out);
}

// Round 4
// 1690.143 us; speedup vs baseline: 4.6430x; 2.3640x over previous
//
#include <hip/hip_runtime.h>
#include <hip/hip_bf16.h>
#include <math.h>

// Sizes: B=2 T=32 C=3 H=W=64 P=8 -> N=64, D=512, L=2048, M=B*T*N=4096
#define MTOK 4096

typedef __bf16 bf16x8 __attribute__((ext_vector_type(8)));
typedef float f32x4 __attribute__((ext_vector_type(4)));

__device__ __forceinline__ ushort f2bf(float f){
  __hip_bfloat16 h = __float2bfloat16(f);
  return *reinterpret_cast<ushort*>(&h);
}
__device__ __forceinline__ float bf2f(ushort u){
  return __uint_as_float(((uint)u) << 16);
}
__device__ __forceinline__ void gload_lds16(const void* g, void* l){
  __builtin_amdgcn_global_load_lds((__attribute__((address_space(1))) void*)(void*)g,
                                   (__attribute__((address_space(3))) void*)l, 16, 0, 0);
}

__device__ __forceinline__ float blockReduceSum(float v, float* red){
  #pragma unroll
  for (int off = 32; off; off >>= 1) v += __shfl_down(v, off, 64);
  int lane = threadIdx.x & 63, wid = threadIdx.x >> 6;
  __syncthreads();
  if (lane == 0) red[wid] = v;
  __syncthreads();
  float r = 0.f;
  int nw = blockDim.x >> 6;
  for (int i = 0; i < nw; i++) r += red[i];
  return r;
}
__device__ __forceinline__ float rowMax16(float v){
  #pragma unroll
  for (int m = 8; m; m >>= 1) v = fmaxf(v, __shfl_xor(v, m, 64));
  return v;
}
__device__ __forceinline__ float rowSum16(float v){
  #pragma unroll
  for (int m = 8; m; m >>= 1) v += __shfl_xor(v, m, 64);
  return v;
}

// ---------------- patch embed + LN + pos (fp32, writes A) ----------------
__global__ __launch_bounds__(256) void patch_embed_kernel(
    const float* __restrict__ x, const float* __restrict__ pw, const float* __restrict__ pb,
    const float* __restrict__ g, const float* __restrict__ bta,
    const float* __restrict__ spos, const float* __restrict__ tpos, float* __restrict__ out)
{
  int m = blockIdx.x;
  int b = m >> 11, t = (m >> 6) & 31, n = m & 63;
  int hn = n >> 3, wn = n & 7;
  __shared__ float patch[192];
  __shared__ float red[4];
  int tid = threadIdx.x;
  if (tid < 192){
    int c = tid / 64, rem = tid & 63;
    int ph = rem >> 3, pwj = rem & 7;
    patch[tid] = x[(((size_t)(b*32 + t)*3 + c)*64 + hn*8 + ph)*64 + wn*8 + pwj];
  }
  __syncthreads();
  float e0 = pb[tid], e1 = pb[tid + 256];
  const float* r0 = pw + (size_t)tid*192;
  const float* r1 = pw + (size_t)(tid + 256)*192;
  for (int k = 0; k < 192; k++){ float p = patch[k]; e0 = fmaf(p, r0[k], e0); e1 = fmaf(p, r1[k], e1); }
  float s = blockReduceSum(e0 + e1, red);
  float mu = s * (1.f/512.f);
  float d0 = e0 - mu, d1 = e1 - mu;
  float vv = blockReduceSum(d0*d0 + d1*d1, red);
  float inv = rsqrtf(vv * (1.f/512.f) + 1e-5f);
  size_t o = (size_t)m * 512;
  out[o + tid]       = d0*inv*g[tid]       + bta[tid]       + spos[n*512 + tid]       + tpos[t*512 + tid];
  out[o + tid + 256] = d1*inv*g[tid + 256] + bta[tid + 256] + spos[n*512 + tid + 256] + tpos[t*512 + tid + 256];
}

// ---------------- LayerNorm (D=512) fp32 in -> bf16 out ----------------
__global__ __launch_bounds__(256) void ln_bf16_kernel(
    const float* __restrict__ in, ushort* __restrict__ out,
    const float* __restrict__ g, const float* __restrict__ b)
{
  int r = blockIdx.x, tid = threadIdx.x;
  const float* row = in + (size_t)r * 512;
  float2 v = *(const float2*)(row + tid*2);
  __shared__ float red[4];
  float s = blockReduceSum(v.x + v.y, red);
  float mu = s * (1.f/512.f);
  float dx = v.x - mu, dy = v.y - mu;
  float vv = blockReduceSum(dx*dx + dy*dy, red);
  float inv = rsqrtf(vv * (1.f/512.f) + 1e-5f);
  float2 gg = *(const float2*)(g + tid*2);
  float2 bb = *(const float2*)(b + tid*2);
  ushort2 o2; o2.x = f2bf(dx*inv*gg.x + bb.x); o2.y = f2bf(dy*inv*gg.y + bb.y);
  *(ushort2*)(out + (size_t)r*512 + tid*2) = o2;
}

// ---------------- MFMA GEMM: Y[M,N] = X[M,K](bf16) @ W[N,K](f32->bf16)^T + bias (+res)(+gelu) ----------------
template<bool GELU, bool BF16OUT>
__global__ __launch_bounds__(256) void gemm_bf16_kernel(
    const ushort* __restrict__ X, const float* __restrict__ W,
    const float* __restrict__ bias, const float* __restrict__ res,
    void* __restrict__ Yv, int M, int Nn, int K)
{
  __shared__ char smem[32768];
  char* Xs = smem;
  char* Ws = smem + 16384;
  int tid = threadIdx.x, lane = tid & 63, wv = tid >> 6;
  int bm = blockIdx.y * 128, bn = blockIdx.x * 128;
  int wm = (wv >> 1) * 64, wn = (wv & 1) * 64;

  f32x4 zero4 = {0.f, 0.f, 0.f, 0.f};
  f32x4 acc[4][4];
  #pragma unroll
  for (int i = 0; i < 4; i++)
    #pragma unroll
    for (int j = 0; j < 4; j++) acc[i][j] = zero4;

  int xrow_off = wv*8 + (lane >> 3);
  int xcolsrc  = (((lane & 7) ^ (lane >> 3)) * 16);
  int wrow0 = tid >> 2;
  int wkseg = (tid & 3) * 16;

  for (int k0 = 0; k0 < K; k0 += 64){
    __syncthreads();
    #pragma unroll
    for (int i = 0; i < 4; i++){
      int row = i*32 + xrow_off;
      const char* src = (const char*)(X + (size_t)(bm + row)*K + k0) + xcolsrc;
      char* dst = Xs + (i*32 + wv*8)*128;
      gload_lds16(src, dst);
    }
    #pragma unroll
    for (int i = 0; i < 2; i++){
      int row = wrow0 + i*64;
      const float* src = W + (size_t)(bn + row)*K + k0 + wkseg;
      float4 v0 = *(const float4*)(src);
      float4 v1 = *(const float4*)(src + 4);
      float4 v2 = *(const float4*)(src + 8);
      float4 v3 = *(const float4*)(src + 12);
      uint4 w0, w1;
      w0.x = (uint)f2bf(v0.x) | ((uint)f2bf(v0.y) << 16);
      w0.y = (uint)f2bf(v0.z) | ((uint)f2bf(v0.w) << 16);
      w0.z = (uint)f2bf(v1.x) | ((uint)f2bf(v1.y) << 16);
      w0.w = (uint)f2bf(v1.z) | ((uint)f2bf(v1.w) << 16);
      w1.x = (uint)f2bf(v2.x) | ((uint)f2bf(v2.y) << 16);
      w1.y = (uint)f2bf(v2.z) | ((uint)f2bf(v2.w) << 16);
      w1.z = (uint)f2bf(v3.x) | ((uint)f2bf(v3.y) << 16);
      w1.w = (uint)f2bf(v3.z) | ((uint)f2bf(v3.w) << 16);
      int swz = (row & 7) << 4;
      char* base = Ws + row*128;
      *(uint4*)(base + ((wkseg*2)      ^ swz)) = w0;
      *(uint4*)(base + ((wkseg*2 + 16) ^ swz)) = w1;
    }
    __syncthreads();
    #pragma unroll
    for (int kc = 0; kc < 2; kc++){
      bf16x8 a[4], b[4];
      #pragma unroll
      for (int f = 0; f < 4; f++){
        int ra = wm + f*16 + (lane & 15);
        a[f] = *(const bf16x8*)(Xs + ra*128 + ((kc*64 + (lane>>4)*16) ^ ((ra & 7) << 4)));
        int rb = wn + f*16 + (lane & 15);
        b[f] = *(const bf16x8*)(Ws + rb*128 + ((kc*64 + (lane>>4)*16) ^ ((rb & 7) << 4)));
      }
      #pragma unroll
      for (int i = 0; i < 4; i++)
        #pragma unroll
        for (int j = 0; j < 4; j++)
          acc[i][j] = __builtin_amdgcn_mfma_f32_16x16x32_bf16(a[i], b[j], acc[i][j], 0, 0, 0);
    }
  }
  int col0 = lane & 15;
  float bv[4];
  #pragma unroll
  for (int fn = 0; fn < 4; fn++) bv[fn] = bias[bn + wn + fn*16 + col0];
  #pragma unroll
  for (int fm = 0; fm < 4; fm++){
    #pragma unroll
    for (int r = 0; r < 4; r++){
      int m = bm + wm + fm*16 + (lane >> 4)*4 + r;
      #pragma unroll
      for (int fn = 0; fn < 4; fn++){
        int n = bn + wn + fn*16 + col0;
        float v = acc[fm][fn][r] + bv[fn];
        if (res) v += res[(size_t)m*Nn + n];
        if (GELU) v = 0.5f * v * (1.f + erff(v * 0.70710678118654752440f));
        if (BF16OUT) ((ushort*)Yv)[(size_t)m*Nn + n] = f2bf(v);
        else         ((float*) Yv)[(size_t)m*Nn + n] = v;
      }
    }
  }
}

// ---------------- spatial attention: per (frame, head), N=64, hd=128, fp32 math, bf16 out ----------------
// qkv row (1536): [q 0:512 | k 512:1024 | v 1024:1536]
__global__ __launch_bounds__(256) void spatial_attn_kernel(
    const float* __restrict__ qkv, ushort* __restrict__ y)
{
  __shared__ float bufA[8192];
  __shared__ float bufB[8192];
  int bt = blockIdx.x, h = blockIdx.y;
  int tid = threadIdx.x, tx = tid & 15, ty = tid >> 4;
  const float scale = 0.08838834764831845f;  // 1/sqrt(128)
  size_t base = (size_t)bt * 64 * 1536 + (size_t)h * 128;
  for (int e = tid; e < 2048; e += 256){
    int i = e >> 5, dc = (e & 31) * 4;
    const float* qp = qkv + base + (size_t)i*1536 + dc;
    float4 q4 = *(const float4*)qp;
    float4 k4 = *(const float4*)(qp + 512);
    bufA[(dc+0)*64+i] = q4.x; bufA[(dc+1)*64+i] = q4.y; bufA[(dc+2)*64+i] = q4.z; bufA[(dc+3)*64+i] = q4.w;
    bufB[(dc+0)*64+i] = k4.x; bufB[(dc+1)*64+i] = k4.y; bufB[(dc+2)*64+i] = k4.z; bufB[(dc+3)*64+i] = k4.w;
  }
  __syncthreads();
  float acc[4][4] = {};
  for (int d = 0; d < 128; d++){
    float4 qa = *(const float4*)&bufA[d*64 + ty*4];
    float4 ka = *(const float4*)&bufB[d*64 + tx*4];
    float av[4] = {qa.x, qa.y, qa.z, qa.w};
    float bvv[4] = {ka.x, ka.y, ka.z, ka.w};
    #pragma unroll
    for (int i = 0; i < 4; i++)
      #pragma unroll
      for (int j = 0; j < 4; j++)
        acc[i][j] = fmaf(av[i], bvv[j], acc[i][j]);
  }
  float pnorm[4];
  #pragma unroll
  for (int i = 0; i < 4; i++){
    float mx = fmaxf(fmaxf(acc[i][0], acc[i][1]), fmaxf(acc[i][2], acc[i][3]));
    mx = rowMax16(mx);
    float ps = 0.f;
    #pragma unroll
    for (int j = 0; j < 4; j++){ acc[i][j] = __expf(acc[i][j]*scale - mx*scale); ps += acc[i][j]; }
    ps = rowSum16(ps);
    pnorm[i] = 1.f / ps;
  }
  __syncthreads();
  #pragma unroll
  for (int i = 0; i < 4; i++)
    #pragma unroll
    for (int j = 0; j < 4; j++)
      bufA[(ty*4+i)*65 + tx*4+j] = acc[i][j] * pnorm[i];
  for (int e = tid; e < 2048; e += 256){
    int j = e >> 5, dc = (e & 31) * 4;
    float4 v4 = *(const float4*)(qkv + base + (size_t)j*1536 + 1024 + dc);
    *(float4*)&bufB[j*128 + dc] = v4;
  }
  __syncthreads();
  float ao[4][8] = {};
  for (int j = 0; j < 64; j++){
    float p[4];
    #pragma unroll
    for (int i = 0; i < 4; i++) p[i] = bufA[(ty*4+i)*65 + j];
    float4 v0 = *(const float4*)&bufB[j*128 + tx*4];
    float4 v1 = *(const float4*)&bufB[j*128 + 64 + tx*4];
    #pragma unroll
    for (int i = 0; i < 4; i++){
      ao[i][0] = fmaf(p[i], v0.x, ao[i][0]); ao[i][1] = fmaf(p[i], v0.y, ao[i][1]);
      ao[i][2] = fmaf(p[i], v0.z, ao[i][2]); ao[i][3] = fmaf(p[i], v0.w, ao[i][3]);
      ao[i][4] = fmaf(p[i], v1.x, ao[i][4]); ao[i][5] = fmaf(p[i], v1.y, ao[i][5]);
      ao[i][6] = fmaf(p[i], v1.z, ao[i][6]); ao[i][7] = fmaf(p[i], v1.w, ao[i][7]);
    }
  }
  size_t ybase = (size_t)(bt*64) * 512 + (size_t)h * 128;
  #pragma unroll
  for (int i = 0; i < 4; i++){
    int row = ty*4 + i;
    ushort4 o0; o0.x=f2bf(ao[i][0]); o0.y=f2bf(ao[i][1]); o0.z=f2bf(ao[i][2]); o0.w=f2bf(ao[i][3]);
    ushort4 o1; o1.x=f2bf(ao[i][4]); o1.y=f2bf(ao[i][5]); o1.z=f2bf(ao[i][6]); o1.w=f2bf(ao[i][7]);
    *(ushort4*)(y + ybase + (size_t)row*512 + tx*4) = o0;
    *(ushort4*)(y + ybase + (size_t)row*512 + 64 + tx*4) = o1;
  }
}

// ---------------- temporal causal attention, bf16 MFMA flash ----------------
// qkv row (1536 bf16): [k 0:512 | q 512:1024 | v 1024:1536], head slice h*64.
// QBLK=64 (4 waves x 16 q-rows), KBLK=64. grid: 512 blocks 1-D.
// A-frag layout: row=l&15, k=(l>>4)*8..+8 ; C/D: col=l&15, row=(l>>4)*4+reg.
__global__ __launch_bounds__(256) void temporal_attn_mfma_kernel(
    const ushort* __restrict__ qkv, ushort* __restrict__ y)
{
  __shared__ char Ks[64*128];   // K [key][d] bf16, swizzled
  __shared__ char Vt[64*128];   // V^T [d][key] bf16, swizzled
  __shared__ char Ps[64*128];   // P [q][key] bf16, swizzled (wave-private rows)
  int id = blockIdx.x;
  int bh = id & 15;
  int idx = id >> 4;                       // 0..31
  int qt = (idx < 16) ? idx : 47 - idx;    // co-resident pair sums to 31
  int b = bh >> 3, h = bh & 7;
  int tid = threadIdx.x, lane = tid & 63, w = tid >> 6;
  const ushort* base = qkv + (size_t)(b*2048)*1536 + h*64;

  // Q fragments (held in registers for the whole block)
  int qrow = qt*64 + w*16 + (lane & 15);
  bf16x8 qa[2];
  #pragma unroll
  for (int kc = 0; kc < 2; kc++)
    qa[kc] = *(const bf16x8*)(base + (size_t)qrow*1536 + 512 + kc*32 + (lane>>4)*8);

  f32x4 zero4 = {0.f,0.f,0.f,0.f};
  f32x4 o[4];
  float m_old[4], l_sum[4];
  #pragma unroll
  for (int dt = 0; dt < 4; dt++) o[dt] = zero4;
  #pragma unroll
  for (int r = 0; r < 4; r++){ m_old[r] = -1e30f; l_sum[r] = 0.f; }

  // staging index precompute
  int kcolsrc = ((lane & 7) ^ (lane >> 3)) * 16;        // pre-swizzled source byte col
  int vj = tid & 63;                                    // key j for V staging
  int vd0 = (tid >> 6) * 16;                            // d segment (one per wave)

  for (int kt = 0; kt <= qt; kt++){
    __syncthreads();   // prev tile's LDS reads complete
    // ---- stage K via global_load_lds (linear dest, pre-swizzled src) ----
    #pragma unroll
    for (int i = 0; i < 2; i++){
      int row = w*16 + i*8 + (lane >> 3);
      const char* src = (const char*)(base + (size_t)(kt*64 + row)*1536) + kcolsrc;
      char* dst = Ks + (w*16 + i*8)*128;
      gload_lds16(src, dst);
    }
    // ---- stage V transposed: Vt[d][key], swizzled ----
    {
      const ushort* vrow = base + (size_t)(kt*64 + vj)*1536 + 1024 + vd0;
      uint4 p0 = *(const uint4*)(vrow);
      uint4 p1 = *(const uint4*)(vrow + 8);
      uint vals[8] = {p0.x, p0.y, p0.z, p0.w, p1.x, p1.y, p1.z, p1.w};
      #pragma unroll
      for (int e = 0; e < 8; e++){
        int d0 = vd0 + e*2;
        *(ushort*)(Vt + d0*128     + ((2*vj) ^ (( d0    & 7) << 4))) = (ushort)(vals[e] & 0xffff);
        *(ushort*)(Vt + (d0+1)*128 + ((2*vj) ^ (((d0+1) & 7) << 4))) = (ushort)(vals[e] >> 16);
      }
    }
    __syncthreads();   // K, V staged (drains vmcnt + lgkm)

    // ---- QK^T: S[16q x 64key] per wave ----
    f32x4 accS[4];
    #pragma unroll
    for (int jt = 0; jt < 4; jt++){
      accS[jt] = zero4;
      #pragma unroll
      for (int kc = 0; kc < 2; kc++){
        int krow = jt*16 + (lane & 15);
        bf16x8 kb = *(const bf16x8*)(Ks + krow*128 + ((kc*64 + (lane>>4)*16) ^ ((krow & 7) << 4)));
        accS[jt] = __builtin_amdgcn_mfma_f32_16x16x32_bf16(qa[kc], kb, accS[jt], 0, 0, 0);
      }
    }
    // causal mask on diagonal tile
    if (kt == qt){
      #pragma unroll
      for (int jt = 0; jt < 4; jt++){
        int gj = kt*64 + jt*16 + (lane & 15);
        #pragma unroll
        for (int r = 0; r < 4; r++){
          int gi = qt*64 + w*16 + (lane>>4)*4 + r;
          if (gj > gi) accS[jt][r] = -1e30f;
        }
      }
    }
    // ---- online softmax (in-register) + P -> LDS (bf16, wave-private rows) ----
    #pragma unroll
    for (int r = 0; r < 4; r++){
      float mloc = fmaxf(fmaxf(accS[0][r], accS[1][r]), fmaxf(accS[2][r], accS[3][r])) * 0.125f;
      mloc = rowMax16(mloc);
      float mnew = fmaxf(m_old[r], mloc);
      float corr = __expf(m_old[r] - mnew);
      int prow = w*16 + (lane>>4)*4 + r;
      int swz = (prow & 7) << 4;
      char* pbase = Ps + prow*128;
      float ps = 0.f;
      #pragma unroll
      for (int jt = 0; jt < 4; jt++){
        float p = __expf(accS[jt][r]*0.125f - mnew);
        ushort pb = f2bf(p);
        *(ushort*)(pbase + ((2*(jt*16 + (lane & 15))) ^ swz)) = pb;
        ps += bf2f(pb);
      }
      ps = rowSum16(ps);
      l_sum[r] = l_sum[r]*corr + ps;
      m_old[r] = mnew;
      #pragma unroll
      for (int dt = 0; dt < 4; dt++) o[dt][r] *= corr;
    }
    // ---- PV: O += P @ V  (P rows are wave-private; in-wave lgkm ordering suffices) ----
    bf16x8 pa[2];
    #pragma unroll
    for (int kc2 = 0; kc2 < 2; kc2++){
      int prow = w*16 + (lane & 15);
      pa[kc2] = *(const bf16x8*)(Ps + prow*128 + ((kc2*64 + (lane>>4)*16) ^ ((prow & 7) << 4)));
    }
    #pragma unroll
    for (int dt = 0; dt < 4; dt++){
      #pragma unroll
      for (int kc2 = 0; kc2 < 2; kc2++){
        int vrow = dt*16 + (lane & 15);
        bf16x8 vb = *(const bf16x8*)(Vt + vrow*128 + ((kc2*64 + (lane>>4)*16) ^ ((vrow & 7) << 4)));
        o[dt] = __builtin_amdgcn_mfma_f32_16x16x32_bf16(pa[kc2], vb, o[dt], 0, 0, 0);
      }
    }
  }
  // ---- epilogue ----
  #pragma unroll
  for (int r = 0; r < 4; r++){
    float invl = 1.f / l_sum[r];
    int token = qt*64 + w*16 + (lane>>4)*4 + r;
    ushort* yrow = y + (size_t)(b*2048 + token)*512 + h*64;
    #pragma unroll
    for (int dt = 0; dt < 4; dt++)
      yrow[dt*16 + (lane & 15)] = f2bf(o[dt][r] * invl);
  }
}

// ---------------- tf = mean over N of lnf(hid) (bf16 in, f32 out) ----------------
__global__ __launch_bounds__(256) void reduce_tf_kernel(const ushort* __restrict__ hid, float* __restrict__ tf){
  int bt = blockIdx.x, tid = threadIdx.x;
  for (int d = tid; d < 512; d += 256){
    float s = 0.f;
    for (int n = 0; n < 64; n++) s += bf2f(hid[((size_t)bt*64 + n)*512 + d]);
    tf[(size_t)bt*512 + d] = s * (1.f/64.f);
  }
}

// ---------------- heads ----------------
__global__ __launch_bounds__(256) void head_kernel(
    const float* __restrict__ tf,
    const float* __restrict__ th_w1, const float* __restrict__ th_b1,
    const float* __restrict__ th_w2, const float* __restrict__ th_b2,
    const float* __restrict__ sh_w1, const float* __restrict__ sh_b1,
    const float* __restrict__ sh_w2, const float* __restrict__ sh_b2,
    const float* __restrict__ pf_w1, const float* __restrict__ pf_b1,
    const float* __restrict__ pf_w2, const float* __restrict__ pf_b2,
    float* __restrict__ out)
{
  __shared__ float z[512];
  __shared__ float red[4];
  int bi = blockIdx.x, tid = threadIdx.x;
  const float *w1, *b1, *w2, *b2;
  float* dst;
  if (bi < 64){
    w1 = pf_w1; b1 = pf_b1; w2 = pf_w2; b2 = pf_b2; dst = out + 4 + bi;
    z[tid]       = tf[(size_t)bi*512 + tid];
    z[tid + 256] = tf[(size_t)bi*512 + tid + 256];
  } else if (bi < 66){
    int b = bi - 64;
    w1 = th_w1; b1 = th_b1; w2 = th_w2; b2 = th_b2; dst = out + b;
    z[tid]       = tf[(size_t)(b*32 + 31)*512 + tid];
    z[tid + 256] = tf[(size_t)(b*32 + 31)*512 + tid + 256];
  } else {
    int b = bi - 66;
    w1 = sh_w1; b1 = sh_b1; w2 = sh_w2; b2 = sh_b2; dst = out + 2 + b;
    float s0 = 0.f, s1 = 0.f;
    for (int t = 0; t < 32; t++){
      s0 += tf[(size_t)(b*32 + t)*512 + tid];
      s1 += tf[(size_t)(b*32 + t)*512 + tid + 256];
    }
    z[tid] = s0 * (1.f/32.f); z[tid + 256] = s1 * (1.f/32.f);
  }
  __syncthreads();
  float a = b1[tid];
  const float* wrow = w1 + (size_t)tid * 512;
  for (int k = 0; k < 512; k++) a = fmaf(wrow[k], z[k], a);
  a = (a > 0.f) ? a : 0.2f * a;
  float s = blockReduceSum(a * w2[tid], red);
  if (tid == 0) *dst = s + b2[0];
}

__global__ __launch_bounds__(64) void final_kernel(float* __restrict__ out){
  int b = threadIdx.x;
  if (b < 2){
    float s = 0.f;
    for (int t = 0; t < 32; t++) s += out[4 + b*32 + t];
    out[68 + b] = out[b] + out[2 + b] + s * (1.f/32.f);
  }
}

extern "C" void kernel_launch(void* const* d_in, const int* in_sizes, int n_in,
                              void* d_out, int out_size, void* d_ws, size_t ws_size,
                              hipStream_t stream)
{
  const float* x          = (const float*)d_in[0];
  const float* patch_w    = (const float*)d_in[1];
  const float* patch_b    = (const float*)d_in[2];
  const float* tok_ln_g   = (const float*)d_in[3];
  const float* tok_ln_b   = (const float*)d_in[4];
  const float* spatial_pos= (const float*)d_in[5];
  const float* temporal_pos=(const float*)d_in[6];
  const float* snorm_g    = (const float*)d_in[7];
  const float* snorm_b    = (const float*)d_in[8];
  const float* sa_in_w    = (const float*)d_in[9];
  const float* sa_in_b    = (const float*)d_in[10];
  const float* sa_out_w   = (const float*)d_in[11];
  const float* sa_out_b   = (const float*)d_in[12];
  const float* ln1_g      = (const float*)d_in[13];
  const float* ln1_b      = (const float*)d_in[14];
  const float* kqv_w      = (const float*)d_in[15];
  const float* kqv_b      = (const float*)d_in[16];
  const float* proj_w     = (const float*)d_in[17];
  const float* proj_b     = (const float*)d_in[18];
  const float* ln2_g      = (const float*)d_in[19];
  const float* ln2_b      = (const float*)d_in[20];
  const float* fc_w       = (const float*)d_in[21];
  const float* fc_b       = (const float*)d_in[22];
  const float* cproj_w    = (const float*)d_in[23];
  const float* cproj_b    = (const float*)d_in[24];
  const float* lnf_g      = (const float*)d_in[25];
  const float* lnf_b      = (const float*)d_in[26];
  const float* th_w1 = (const float*)d_in[27];
  const float* th_b1 = (const float*)d_in[28];
  const float* th_w2 = (const float*)d_in[29];
  const float* th_b2 = (const float*)d_in[30];
  const float* sh_w1 = (const float*)d_in[31];
  const float* sh_b1 = (const float*)d_in[32];
  const float* sh_w2 = (const float*)d_in[33];
  const float* sh_b2 = (const float*)d_in[34];
  const float* pf_w1 = (const float*)d_in[35];
  const float* pf_b1 = (const float*)d_in[36];
  const float* pf_w2 = (const float*)d_in[37];
  const float* pf_b2 = (const float*)d_in[38];

  float* out = (float*)d_out;
  // workspace layout
  float*  A  = (float*)d_ws;                         // 4096x512 f32 hidden
  float*  Cf = A + (size_t)MTOK*512;                 // 4096x1536 f32 qkv (spatial) / aliases below
  ushort* Bf = (ushort*)(Cf + (size_t)MTOK*1536);    // 4096x512 bf16 (ln out)
  ushort* Ef = Bf + (size_t)MTOK*512;                // 4096x512 bf16 (attn out)
  float*  tf = (float*)(Ef + (size_t)MTOK*512);      // 64x512 f32
  ushort* Gf = (ushort*)Cf;                          // gelu bf16 4096x2048 (alias)
  ushort* Cb = (ushort*)Cf;                          // temporal qkv bf16 4096x1536 (alias)

  patch_embed_kernel<<<MTOK, 256, 0, stream>>>(x, patch_w, patch_b, tok_ln_g, tok_ln_b,
                                               spatial_pos, temporal_pos, A);
  // spatial layers (fp32 attention path)
  for (int i = 0; i < 3; i++){
    ln_bf16_kernel<<<MTOK, 256, 0, stream>>>(A, Bf, snorm_g, snorm_b);
    gemm_bf16_kernel<false,false><<<dim3(1536/128, MTOK/128), 256, 0, stream>>>(
        Bf, sa_in_w + (size_t)i*1536*512, sa_in_b + (size_t)i*1536, nullptr, Cf, MTOK, 1536, 512);
    spatial_attn_kernel<<<dim3(64, 4), 256, 0, stream>>>(Cf, Ef);
    gemm_bf16_kernel<false,false><<<dim3(512/128, MTOK/128), 256, 0, stream>>>(
        Ef, sa_out_w + (size_t)i*512*512, sa_out_b + (size_t)i*512, A, A, MTOK, 512, 512);
  }
  // temporal layers (bf16 MFMA attention path)
  for (int i = 0; i < 6; i++){
    ln_bf16_kernel<<<MTOK, 256, 0, stream>>>(A, Bf, ln1_g + (size_t)i*512, ln1_b + (size_t)i*512);
    gemm_bf16_kernel<false,true><<<dim3(1536/128, MTOK/128), 256, 0, stream>>>(
        Bf, kqv_w + (size_t)i*1536*512, kqv_b + (size_t)i*1536, nullptr, Cb, MTOK, 1536, 512);
    temporal_attn_mfma_kernel<<<512, 256, 0, stream>>>(Cb, Ef);
    gemm_bf16_kernel<false,false><<<dim3(512/128, MTOK/128), 256, 0, stream>>>(
        Ef, proj_w + (size_t)i*512*512, proj_b + (size_t)i*512, A, A, MTOK, 512, 512);
    ln_bf16_kernel<<<MTOK, 256, 0, stream>>>(A, Bf, ln2_g + (size_t)i*512, ln2_b + (size_t)i*512);
    gemm_bf16_kernel<true,true><<<dim3(2048/128, MTOK/128), 256, 0, stream>>>(
        Bf, fc_w + (size_t)i*2048*512, fc_b + (size_t)i*2048, nullptr, Gf, MTOK, 2048, 512);
    gemm_bf16_kernel<false,false><<<dim3(512/128, MTOK/128), 256, 0, stream>>>(
        Gf, cproj_w + (size_t)i*512*2048, cproj_b + (size_t)i*512, A, A, MTOK, 512, 2048);
  }
  // final LN + heads
  ln_bf16_kernel<<<MTOK, 256, 0, stream>>>(A, Bf, lnf_g, lnf_b);
  reduce_tf_kernel<<<64, 256, 0, stream>>>(Bf, tf);
  head_kernel<<<68, 256, 0, stream>>>(tf, th_w1, th_b1, th_w2, th_b2,
                                      sh_w1, sh_b1, sh_w2, sh_b2,
                                      pf_w1, pf_b1, pf_w2, pf_b2, out);
  final_kernel<<<1, 64, 0, stream>>>(out);
}

// Round 5
// 1304.295 us; speedup vs baseline: 6.0166x; 1.2958x over previous
//
#include <hip/hip_runtime.h>
#include <hip/hip_bf16.h>
#include <math.h>

// Sizes: B=2 T=32 C=3 H=W=64 P=8 -> N=64, D=512, L=2048, M=B*T*N=4096
#define MTOK 4096

typedef __bf16 bf16x8 __attribute__((ext_vector_type(8)));
typedef float f32x4 __attribute__((ext_vector_type(4)));

__device__ __forceinline__ ushort f2bf(float f){
  __hip_bfloat16 h = __float2bfloat16(f);
  return *reinterpret_cast<ushort*>(&h);
}
__device__ __forceinline__ float bf2f(ushort u){
  return __uint_as_float(((uint)u) << 16);
}
__device__ __forceinline__ void gload_lds16(const void* g, void* l){
  __builtin_amdgcn_global_load_lds((__attribute__((address_space(1))) void*)(void*)g,
                                   (__attribute__((address_space(3))) void*)l, 16, 0, 0);
}

__device__ __forceinline__ float blockReduceSum(float v, float* red){
  #pragma unroll
  for (int off = 32; off; off >>= 1) v += __shfl_down(v, off, 64);
  int lane = threadIdx.x & 63, wid = threadIdx.x >> 6;
  __syncthreads();
  if (lane == 0) red[wid] = v;
  __syncthreads();
  float r = 0.f;
  int nw = blockDim.x >> 6;
  for (int i = 0; i < nw; i++) r += red[i];
  return r;
}
__device__ __forceinline__ float rowMax16(float v){
  #pragma unroll
  for (int m = 8; m; m >>= 1) v = fmaxf(v, __shfl_xor(v, m, 64));
  return v;
}
__device__ __forceinline__ float rowSum16(float v){
  #pragma unroll
  for (int m = 8; m; m >>= 1) v += __shfl_xor(v, m, 64);
  return v;
}

// ---------------- im2col: x -> patches [4096][192] bf16 ----------------
__global__ __launch_bounds__(192) void im2col_kernel(
    const float* __restrict__ x, ushort* __restrict__ Pm)
{
  int m = blockIdx.x, e = threadIdx.x;
  int b = m >> 11, t = (m >> 6) & 31, n = m & 63;
  int hn = n >> 3, wn = n & 7;
  int c = e / 64, rem = e & 63;
  int ph = rem >> 3, pwj = rem & 7;
  Pm[(size_t)m*192 + e] = f2bf(x[(((size_t)(b*32 + t)*3 + c)*64 + hn*8 + ph)*64 + wn*8 + pwj]);
}

// ---------------- tok LN + pos: f32 in (gemm out) -> f32 A ----------------
__global__ __launch_bounds__(256) void ln_pos_kernel(
    const float* __restrict__ in, float* __restrict__ out,
    const float* __restrict__ g, const float* __restrict__ b,
    const float* __restrict__ spos, const float* __restrict__ tpos)
{
  int r = blockIdx.x, tid = threadIdx.x;
  int n = r & 63, t = (r >> 6) & 31;
  const float* row = in + (size_t)r * 512;
  float2 v = *(const float2*)(row + tid*2);
  __shared__ float red[4];
  float s = blockReduceSum(v.x + v.y, red);
  float mu = s * (1.f/512.f);
  float dx = v.x - mu, dy = v.y - mu;
  float vv = blockReduceSum(dx*dx + dy*dy, red);
  float inv = rsqrtf(vv * (1.f/512.f) + 1e-5f);
  float2 gg = *(const float2*)(g + tid*2);
  float2 bb = *(const float2*)(b + tid*2);
  float2 sp = *(const float2*)(spos + n*512 + tid*2);
  float2 tp = *(const float2*)(tpos + t*512 + tid*2);
  float2 o; o.x = dx*inv*gg.x + bb.x + sp.x + tp.x; o.y = dy*inv*gg.y + bb.y + sp.y + tp.y;
  *(float2*)(out + (size_t)r*512 + tid*2) = o;
}

// ---------------- LayerNorm (D=512) fp32 in -> bf16 out ----------------
__global__ __launch_bounds__(256) void ln_bf16_kernel(
    const float* __restrict__ in, ushort* __restrict__ out,
    const float* __restrict__ g, const float* __restrict__ b)
{
  int r = blockIdx.x, tid = threadIdx.x;
  const float* row = in + (size_t)r * 512;
  float2 v = *(const float2*)(row + tid*2);
  __shared__ float red[4];
  float s = blockReduceSum(v.x + v.y, red);
  float mu = s * (1.f/512.f);
  float dx = v.x - mu, dy = v.y - mu;
  float vv = blockReduceSum(dx*dx + dy*dy, red);
  float inv = rsqrtf(vv * (1.f/512.f) + 1e-5f);
  float2 gg = *(const float2*)(g + tid*2);
  float2 bb = *(const float2*)(b + tid*2);
  ushort2 o2; o2.x = f2bf(dx*inv*gg.x + bb.x); o2.y = f2bf(dy*inv*gg.y + bb.y);
  *(ushort2*)(out + (size_t)r*512 + tid*2) = o2;
}

// ---------------- MFMA GEMM: Y[M,N] = X[M,K](bf16) @ W[N,K](f32->bf16)^T + bias (+res)(+gelu) ----------------
// BM x 128 tile, BK=64, 4 waves (2x2). BM=128: wave 64x64 (4x4 frags); BM=64: wave 32x64 (2x4).
// X staged via global_load_lds (linear dest, pre-swizzled src); W reg-staged with cvt + swizzled write.
// Swizzle: byte_in_row ^= (row&7)<<4  (128B rows)
template<int BM, bool GELU, bool BF16OUT>
__global__ __launch_bounds__(256) void gemm_bf16_kernel(
    const ushort* __restrict__ X, const float* __restrict__ W,
    const float* __restrict__ bias, const float* __restrict__ res,
    void* __restrict__ Yv, int M, int Nn, int K)
{
  constexpr int WM = BM / 2;    // wave m-tile
  constexpr int FM = WM / 16;   // m fragments per wave
  __shared__ char smem[BM*128 + 16384];
  char* Xs = smem;
  char* Ws = smem + BM*128;
  int tid = threadIdx.x, lane = tid & 63, wv = tid >> 6;
  int bm = blockIdx.y * BM, bn = blockIdx.x * 128;
  int wm = (wv >> 1) * WM, wn = (wv & 1) * 64;

  f32x4 zero4 = {0.f, 0.f, 0.f, 0.f};
  f32x4 acc[FM][4];
  #pragma unroll
  for (int i = 0; i < FM; i++)
    #pragma unroll
    for (int j = 0; j < 4; j++) acc[i][j] = zero4;

  int xrow_off = wv*8 + (lane >> 3);
  int xcolsrc  = (((lane & 7) ^ (lane >> 3)) * 16);
  int wrow0 = tid >> 2;
  int wkseg = (tid & 3) * 16;

  for (int k0 = 0; k0 < K; k0 += 64){
    __syncthreads();
    #pragma unroll
    for (int i = 0; i < BM/32; i++){
      int row = i*32 + xrow_off;
      const char* src = (const char*)(X + (size_t)(bm + row)*K + k0) + xcolsrc;
      char* dst = Xs + (i*32 + wv*8)*128;
      gload_lds16(src, dst);
    }
    #pragma unroll
    for (int i = 0; i < 2; i++){
      int row = wrow0 + i*64;
      const float* src = W + (size_t)(bn + row)*K + k0 + wkseg;
      float4 v0 = *(const float4*)(src);
      float4 v1 = *(const float4*)(src + 4);
      float4 v2 = *(const float4*)(src + 8);
      float4 v3 = *(const float4*)(src + 12);
      uint4 w0, w1;
      w0.x = (uint)f2bf(v0.x) | ((uint)f2bf(v0.y) << 16);
      w0.y = (uint)f2bf(v0.z) | ((uint)f2bf(v0.w) << 16);
      w0.z = (uint)f2bf(v1.x) | ((uint)f2bf(v1.y) << 16);
      w0.w = (uint)f2bf(v1.z) | ((uint)f2bf(v1.w) << 16);
      w1.x = (uint)f2bf(v2.x) | ((uint)f2bf(v2.y) << 16);
      w1.y = (uint)f2bf(v2.z) | ((uint)f2bf(v2.w) << 16);
      w1.z = (uint)f2bf(v3.x) | ((uint)f2bf(v3.y) << 16);
      w1.w = (uint)f2bf(v3.z) | ((uint)f2bf(v3.w) << 16);
      int swz = (row & 7) << 4;
      char* base = Ws + row*128;
      *(uint4*)(base + ((wkseg*2)      ^ swz)) = w0;
      *(uint4*)(base + ((wkseg*2 + 16) ^ swz)) = w1;
    }
    __syncthreads();
    #pragma unroll
    for (int kc = 0; kc < 2; kc++){
      bf16x8 a[FM], b[4];
      #pragma unroll
      for (int f = 0; f < FM; f++){
        int ra = wm + f*16 + (lane & 15);
        a[f] = *(const bf16x8*)(Xs + ra*128 + ((kc*64 + (lane>>4)*16) ^ ((ra & 7) << 4)));
      }
      #pragma unroll
      for (int f = 0; f < 4; f++){
        int rb = wn + f*16 + (lane & 15);
        b[f] = *(const bf16x8*)(Ws + rb*128 + ((kc*64 + (lane>>4)*16) ^ ((rb & 7) << 4)));
      }
      #pragma unroll
      for (int i = 0; i < FM; i++)
        #pragma unroll
        for (int j = 0; j < 4; j++)
          acc[i][j] = __builtin_amdgcn_mfma_f32_16x16x32_bf16(a[i], b[j], acc[i][j], 0, 0, 0);
    }
  }
  int col0 = lane & 15;
  float bv[4];
  #pragma unroll
  for (int fn = 0; fn < 4; fn++) bv[fn] = bias[bn + wn + fn*16 + col0];
  #pragma unroll
  for (int fm = 0; fm < FM; fm++){
    #pragma unroll
    for (int r = 0; r < 4; r++){
      int m = bm + wm + fm*16 + (lane >> 4)*4 + r;
      #pragma unroll
      for (int fn = 0; fn < 4; fn++){
        int n = bn + wn + fn*16 + col0;
        float v = acc[fm][fn][r] + bv[fn];
        if (res) v += res[(size_t)m*Nn + n];
        if (GELU) v = 0.5f * v * (1.f + erff(v * 0.70710678118654752440f));
        if (BF16OUT) ((ushort*)Yv)[(size_t)m*Nn + n] = f2bf(v);
        else         ((float*) Yv)[(size_t)m*Nn + n] = v;
      }
    }
  }
}

// ---------------- spatial attention, bf16 MFMA: per (frame, head), N=64, hd=128 ----------------
// qkv row (1536 bf16): [q 0:512 | k 512:1024 | v 1024:1536], head slice h*128.
// 4 waves x 16 q-rows. K LDS rows = 256B, swizzle (row&15)<<4; Vt/Ps rows = 128B, swizzle (row&7)<<4.
__global__ __launch_bounds__(256) void spatial_attn_mfma_kernel(
    const ushort* __restrict__ qkv, ushort* __restrict__ y)
{
  __shared__ char Ks[64*256];    // K [tok][d=128] bf16
  __shared__ char Vt[128*128];   // V^T [d][tok] bf16
  __shared__ char Ps[64*128];    // P [q][tok] bf16 (wave-private rows)
  int bt = blockIdx.x, h = blockIdx.y;
  int tid = threadIdx.x, lane = tid & 63, w = tid >> 6;
  const ushort* base = qkv + (size_t)bt*64*1536 + (size_t)h*128;
  const float scale = 0.08838834764831845f;   // 1/sqrt(128)

  // Q fragments (registers)
  int qrow = w*16 + (lane & 15);
  bf16x8 qa[4];
  #pragma unroll
  for (int kc = 0; kc < 4; kc++)
    qa[kc] = *(const bf16x8*)(base + (size_t)qrow*1536 + kc*32 + (lane>>4)*8);

  // stage K via global_load_lds: 4 rows per gload (256B rows)
  #pragma unroll
  for (int i = 0; i < 4; i++){
    int row = w*16 + i*4 + (lane >> 4);
    const char* src = (const char*)(base + (size_t)row*1536 + 512) + (((lane & 15) ^ (row & 15)) * 16);
    char* dst = Ks + (w*16 + i*4)*256;
    gload_lds16(src, dst);
  }
  // stage V^T: key pair (2 keys) x 16 d per thread, paired b32 writes
  {
    int vj = (tid & 31) * 2;
    int d0 = (tid >> 5) * 16;
    const ushort* v0p = base + (size_t)vj*1536 + 1024 + d0;
    const ushort* v1p = v0p + 1536;
    uint4 a0 = *(const uint4*)(v0p);
    uint4 a1 = *(const uint4*)(v0p + 8);
    uint4 b0 = *(const uint4*)(v1p);
    uint4 b1 = *(const uint4*)(v1p + 8);
    uint av[8] = {a0.x, a0.y, a0.z, a0.w, a1.x, a1.y, a1.z, a1.w};
    uint bv[8] = {b0.x, b0.y, b0.z, b0.w, b1.x, b1.y, b1.z, b1.w};
    int cb = 4 * (tid & 31);
    #pragma unroll
    for (int e = 0; e < 8; e++){
      int dl = d0 + e*2, dh = dl + 1;
      uint vlo = (av[e] & 0xffffu) | ((bv[e] & 0xffffu) << 16);
      uint vhi = (av[e] >> 16) | (bv[e] & 0xffff0000u);
      *(uint*)(Vt + dl*128 + (cb ^ ((dl & 7) << 4))) = vlo;
      *(uint*)(Vt + dh*128 + (cb ^ ((dh & 7) << 4))) = vhi;
    }
  }
  __syncthreads();

  // QK^T
  f32x4 zero4 = {0.f,0.f,0.f,0.f};
  f32x4 accS[4];
  #pragma unroll
  for (int jt = 0; jt < 4; jt++){
    accS[jt] = zero4;
    #pragma unroll
    for (int kc = 0; kc < 4; kc++){
      int krow = jt*16 + (lane & 15);
      bf16x8 kb = *(const bf16x8*)(Ks + krow*256 + ((kc*64 + (lane>>4)*16) ^ ((krow & 15) << 4)));
      accS[jt] = __builtin_amdgcn_mfma_f32_16x16x32_bf16(qa[kc], kb, accS[jt], 0, 0, 0);
    }
  }
  // softmax (single tile), P -> LDS bf16
  float l_sum[4];
  #pragma unroll
  for (int r = 0; r < 4; r++){
    float mx = fmaxf(fmaxf(accS[0][r], accS[1][r]), fmaxf(accS[2][r], accS[3][r]));
    mx = rowMax16(mx);
    int prow = w*16 + (lane>>4)*4 + r;
    int swz = (prow & 7) << 4;
    char* pbase = Ps + prow*128;
    float ps = 0.f;
    #pragma unroll
    for (int jt = 0; jt < 4; jt++){
      float p = __expf((accS[jt][r] - mx) * scale);
      ushort pb = f2bf(p);
      *(ushort*)(pbase + ((2*(jt*16 + (lane & 15))) ^ swz)) = pb;
      ps += bf2f(pb);
    }
    l_sum[r] = rowSum16(ps);
  }
  // PV
  bf16x8 pa[2];
  #pragma unroll
  for (int kc2 = 0; kc2 < 2; kc2++){
    int prow = w*16 + (lane & 15);
    pa[kc2] = *(const bf16x8*)(Ps + prow*128 + ((kc2*64 + (lane>>4)*16) ^ ((prow & 7) << 4)));
  }
  f32x4 o[8];
  #pragma unroll
  for (int dt = 0; dt < 8; dt++){
    o[dt] = zero4;
    #pragma unroll
    for (int kc2 = 0; kc2 < 2; kc2++){
      int vrow = dt*16 + (lane & 15);
      bf16x8 vb = *(const bf16x8*)(Vt + vrow*128 + ((kc2*64 + (lane>>4)*16) ^ ((vrow & 7) << 4)));
      o[dt] = __builtin_amdgcn_mfma_f32_16x16x32_bf16(pa[kc2], vb, o[dt], 0, 0, 0);
    }
  }
  // epilogue
  #pragma unroll
  for (int r = 0; r < 4; r++){
    float invl = 1.f / l_sum[r];
    int token = bt*64 + w*16 + (lane>>4)*4 + r;
    ushort* yrow = y + (size_t)token*512 + h*128;
    #pragma unroll
    for (int dt = 0; dt < 8; dt++)
      yrow[dt*16 + (lane & 15)] = f2bf(o[dt][r] * invl);
  }
}

// ---------------- temporal causal attention, bf16 MFMA flash ----------------
// qkv row (1536 bf16): [k 0:512 | q 512:1024 | v 1024:1536], head slice h*64.
__global__ __launch_bounds__(256) void temporal_attn_mfma_kernel(
    const ushort* __restrict__ qkv, ushort* __restrict__ y)
{
  __shared__ char Ks[64*128];
  __shared__ char Vt[64*128];
  __shared__ char Ps[64*128];
  int id = blockIdx.x;
  int bh = id & 15;
  int idx = id >> 4;
  int qt = (idx < 16) ? idx : 47 - idx;
  int b = bh >> 3, h = bh & 7;
  int tid = threadIdx.x, lane = tid & 63, w = tid >> 6;
  const ushort* base = qkv + (size_t)(b*2048)*1536 + h*64;

  int qrow = qt*64 + w*16 + (lane & 15);
  bf16x8 qa[2];
  #pragma unroll
  for (int kc = 0; kc < 2; kc++)
    qa[kc] = *(const bf16x8*)(base + (size_t)qrow*1536 + 512 + kc*32 + (lane>>4)*8);

  f32x4 zero4 = {0.f,0.f,0.f,0.f};
  f32x4 o[4];
  float m_old[4], l_sum[4];
  #pragma unroll
  for (int dt = 0; dt < 4; dt++) o[dt] = zero4;
  #pragma unroll
  for (int r = 0; r < 4; r++){ m_old[r] = -1e30f; l_sum[r] = 0.f; }

  int kcolsrc = ((lane & 7) ^ (lane >> 3)) * 16;
  int vj = tid & 63;
  int vd0 = (tid >> 6) * 16;

  for (int kt = 0; kt <= qt; kt++){
    __syncthreads();
    #pragma unroll
    for (int i = 0; i < 2; i++){
      int row = w*16 + i*8 + (lane >> 3);
      const char* src = (const char*)(base + (size_t)(kt*64 + row)*1536) + kcolsrc;
      char* dst = Ks + (w*16 + i*8)*128;
      gload_lds16(src, dst);
    }
    {
      const ushort* vrow = base + (size_t)(kt*64 + vj)*1536 + 1024 + vd0;
      uint4 p0 = *(const uint4*)(vrow);
      uint4 p1 = *(const uint4*)(vrow + 8);
      uint vals[8] = {p0.x, p0.y, p0.z, p0.w, p1.x, p1.y, p1.z, p1.w};
      #pragma unroll
      for (int e = 0; e < 8; e++){
        int d0 = vd0 + e*2;
        *(ushort*)(Vt + d0*128     + ((2*vj) ^ (( d0    & 7) << 4))) = (ushort)(vals[e] & 0xffff);
        *(ushort*)(Vt + (d0+1)*128 + ((2*vj) ^ (((d0+1) & 7) << 4))) = (ushort)(vals[e] >> 16);
      }
    }
    __syncthreads();

    f32x4 accS[4];
    #pragma unroll
    for (int jt = 0; jt < 4; jt++){
      accS[jt] = zero4;
      #pragma unroll
      for (int kc = 0; kc < 2; kc++){
        int krow = jt*16 + (lane & 15);
        bf16x8 kb = *(const bf16x8*)(Ks + krow*128 + ((kc*64 + (lane>>4)*16) ^ ((krow & 7) << 4)));
        accS[jt] = __builtin_amdgcn_mfma_f32_16x16x32_bf16(qa[kc], kb, accS[jt], 0, 0, 0);
      }
    }
    if (kt == qt){
      #pragma unroll
      for (int jt = 0; jt < 4; jt++){
        int gj = kt*64 + jt*16 + (lane & 15);
        #pragma unroll
        for (int r = 0; r < 4; r++){
          int gi = qt*64 + w*16 + (lane>>4)*4 + r;
          if (gj > gi) accS[jt][r] = -1e30f;
        }
      }
    }
    #pragma unroll
    for (int r = 0; r < 4; r++){
      float mloc = fmaxf(fmaxf(accS[0][r], accS[1][r]), fmaxf(accS[2][r], accS[3][r])) * 0.125f;
      mloc = rowMax16(mloc);
      float mnew = fmaxf(m_old[r], mloc);
      float corr = __expf(m_old[r] - mnew);
      int prow = w*16 + (lane>>4)*4 + r;
      int swz = (prow & 7) << 4;
      char* pbase = Ps + prow*128;
      float ps = 0.f;
      #pragma unroll
      for (int jt = 0; jt < 4; jt++){
        float p = __expf(accS[jt][r]*0.125f - mnew);
        ushort pb = f2bf(p);
        *(ushort*)(pbase + ((2*(jt*16 + (lane & 15))) ^ swz)) = pb;
        ps += bf2f(pb);
      }
      ps = rowSum16(ps);
      l_sum[r] = l_sum[r]*corr + ps;
      m_old[r] = mnew;
      #pragma unroll
      for (int dt = 0; dt < 4; dt++) o[dt][r] *= corr;
    }
    bf16x8 pa[2];
    #pragma unroll
    for (int kc2 = 0; kc2 < 2; kc2++){
      int prow = w*16 + (lane & 15);
      pa[kc2] = *(const bf16x8*)(Ps + prow*128 + ((kc2*64 + (lane>>4)*16) ^ ((prow & 7) << 4)));
    }
    #pragma unroll
    for (int dt = 0; dt < 4; dt++){
      #pragma unroll
      for (int kc2 = 0; kc2 < 2; kc2++){
        int vrow = dt*16 + (lane & 15);
        bf16x8 vb = *(const bf16x8*)(Vt + vrow*128 + ((kc2*64 + (lane>>4)*16) ^ ((vrow & 7) << 4)));
        o[dt] = __builtin_amdgcn_mfma_f32_16x16x32_bf16(pa[kc2], vb, o[dt], 0, 0, 0);
      }
    }
  }
  #pragma unroll
  for (int r = 0; r < 4; r++){
    float invl = 1.f / l_sum[r];
    int token = qt*64 + w*16 + (lane>>4)*4 + r;
    ushort* yrow = y + (size_t)(b*2048 + token)*512 + h*64;
    #pragma unroll
    for (int dt = 0; dt < 4; dt++)
      yrow[dt*16 + (lane & 15)] = f2bf(o[dt][r] * invl);
  }
}

// ---------------- tf = mean over N of lnf(hid) (bf16 in, f32 out) ----------------
__global__ __launch_bounds__(256) void reduce_tf_kernel(const ushort* __restrict__ hid, float* __restrict__ tf){
  int bt = blockIdx.x, tid = threadIdx.x;
  for (int d = tid; d < 512; d += 256){
    float s = 0.f;
    for (int n = 0; n < 64; n++) s += bf2f(hid[((size_t)bt*64 + n)*512 + d]);
    tf[(size_t)bt*512 + d] = s * (1.f/64.f);
  }
}

// ---------------- heads ----------------
__global__ __launch_bounds__(256) void head_kernel(
    const float* __restrict__ tf,
    const float* __restrict__ th_w1, const float* __restrict__ th_b1,
    const float* __restrict__ th_w2, const float* __restrict__ th_b2,
    const float* __restrict__ sh_w1, const float* __restrict__ sh_b1,
    const float* __restrict__ sh_w2, const float* __restrict__ sh_b2,
    const float* __restrict__ pf_w1, const float* __restrict__ pf_b1,
    const float* __restrict__ pf_w2, const float* __restrict__ pf_b2,
    float* __restrict__ out)
{
  __shared__ float z[512];
  __shared__ float red[4];
  int bi = blockIdx.x, tid = threadIdx.x;
  const float *w1, *b1, *w2, *b2;
  float* dst;
  if (bi < 64){
    w1 = pf_w1; b1 = pf_b1; w2 = pf_w2; b2 = pf_b2; dst = out + 4 + bi;
    z[tid]       = tf[(size_t)bi*512 + tid];
    z[tid + 256] = tf[(size_t)bi*512 + tid + 256];
  } else if (bi < 66){
    int b = bi - 64;
    w1 = th_w1; b1 = th_b1; w2 = th_w2; b2 = th_b2; dst = out + b;
    z[tid]       = tf[(size_t)(b*32 + 31)*512 + tid];
    z[tid + 256] = tf[(size_t)(b*32 + 31)*512 + tid + 256];
  } else {
    int b = bi - 66;
    w1 = sh_w1; b1 = sh_b1; w2 = sh_w2; b2 = sh_b2; dst = out + 2 + b;
    float s0 = 0.f, s1 = 0.f;
    for (int t = 0; t < 32; t++){
      s0 += tf[(size_t)(b*32 + t)*512 + tid];
      s1 += tf[(size_t)(b*32 + t)*512 + tid + 256];
    }
    z[tid] = s0 * (1.f/32.f); z[tid + 256] = s1 * (1.f/32.f);
  }
  __syncthreads();
  float a = b1[tid];
  const float* wrow = w1 + (size_t)tid * 512;
  for (int k = 0; k < 512; k++) a = fmaf(wrow[k], z[k], a);
  a = (a > 0.f) ? a : 0.2f * a;
  float s = blockReduceSum(a * w2[tid], red);
  if (tid == 0) *dst = s + b2[0];
}

__global__ __launch_bounds__(64) void final_kernel(float* __restrict__ out){
  int b = threadIdx.x;
  if (b < 2){
    float s = 0.f;
    for (int t = 0; t < 32; t++) s += out[4 + b*32 + t];
    out[68 + b] = out[b] + out[2 + b] + s * (1.f/32.f);
  }
}

extern "C" void kernel_launch(void* const* d_in, const int* in_sizes, int n_in,
                              void* d_out, int out_size, void* d_ws, size_t ws_size,
                              hipStream_t stream)
{
  const float* x          = (const float*)d_in[0];
  const float* patch_w    = (const float*)d_in[1];
  const float* patch_b    = (const float*)d_in[2];
  const float* tok_ln_g   = (const float*)d_in[3];
  const float* tok_ln_b   = (const float*)d_in[4];
  const float* spatial_pos= (const float*)d_in[5];
  const float* temporal_pos=(const float*)d_in[6];
  const float* snorm_g    = (const float*)d_in[7];
  const float* snorm_b    = (const float*)d_in[8];
  const float* sa_in_w    = (const float*)d_in[9];
  const float* sa_in_b    = (const float*)d_in[10];
  const float* sa_out_w   = (const float*)d_in[11];
  const float* sa_out_b   = (const float*)d_in[12];
  const float* ln1_g      = (const float*)d_in[13];
  const float* ln1_b      = (const float*)d_in[14];
  const float* kqv_w      = (const float*)d_in[15];
  const float* kqv_b      = (const float*)d_in[16];
  const float* proj_w     = (const float*)d_in[17];
  const float* proj_b     = (const float*)d_in[18];
  const float* ln2_g      = (const float*)d_in[19];
  const float* ln2_b      = (const float*)d_in[20];
  const float* fc_w       = (const float*)d_in[21];
  const float* fc_b       = (const float*)d_in[22];
  const float* cproj_w    = (const float*)d_in[23];
  const float* cproj_b    = (const float*)d_in[24];
  const float* lnf_g      = (const float*)d_in[25];
  const float* lnf_b      = (const float*)d_in[26];
  const float* th_w1 = (const float*)d_in[27];
  const float* th_b1 = (const float*)d_in[28];
  const float* th_w2 = (const float*)d_in[29];
  const float* th_b2 = (const float*)d_in[30];
  const float* sh_w1 = (const float*)d_in[31];
  const float* sh_b1 = (const float*)d_in[32];
  const float* sh_w2 = (const float*)d_in[33];
  const float* sh_b2 = (const float*)d_in[34];
  const float* pf_w1 = (const float*)d_in[35];
  const float* pf_b1 = (const float*)d_in[36];
  const float* pf_w2 = (const float*)d_in[37];
  const float* pf_b2 = (const float*)d_in[38];

  float* out = (float*)d_out;
  // workspace layout
  float*  A  = (float*)d_ws;                         // 4096x512 f32 hidden
  float*  Cf = A + (size_t)MTOK*512;                 // 4096x1536 f32 region (multi-alias)
  ushort* Bf = (ushort*)(Cf + (size_t)MTOK*1536);    // 4096x512 bf16 (ln out)
  ushort* Ef = Bf + (size_t)MTOK*512;                // 4096x512 bf16 (attn out)
  float*  tf = (float*)(Ef + (size_t)MTOK*512);      // 64x512 f32
  ushort* Gf = (ushort*)Cf;                          // gelu bf16 4096x2048 (alias)
  ushort* Cb = (ushort*)Cf;                          // qkv bf16 4096x1536 (alias)
  ushort* Pm = (ushort*)(Cf + (size_t)MTOK*512);     // patches bf16 4096x192 (alias, tail of Cf)

  // patch embed: im2col -> MFMA GEMM (f32 out into Cf head) -> LN+pos -> A
  im2col_kernel<<<MTOK, 192, 0, stream>>>(x, Pm);
  gemm_bf16_kernel<64,false,false><<<dim3(512/128, MTOK/64), 256, 0, stream>>>(
      Pm, patch_w, patch_b, nullptr, Cf, MTOK, 512, 192);
  ln_pos_kernel<<<MTOK, 256, 0, stream>>>(Cf, A, tok_ln_g, tok_ln_b, spatial_pos, temporal_pos);

  // spatial layers (bf16 MFMA attention)
  for (int i = 0; i < 3; i++){
    ln_bf16_kernel<<<MTOK, 256, 0, stream>>>(A, Bf, snorm_g, snorm_b);
    gemm_bf16_kernel<128,false,true><<<dim3(1536/128, MTOK/128), 256, 0, stream>>>(
        Bf, sa_in_w + (size_t)i*1536*512, sa_in_b + (size_t)i*1536, nullptr, Cb, MTOK, 1536, 512);
    spatial_attn_mfma_kernel<<<dim3(64, 4), 256, 0, stream>>>(Cb, Ef);
    gemm_bf16_kernel<64,false,false><<<dim3(512/128, MTOK/64), 256, 0, stream>>>(
        Ef, sa_out_w + (size_t)i*512*512, sa_out_b + (size_t)i*512, A, A, MTOK, 512, 512);
  }
  // temporal layers (bf16 MFMA attention)
  for (int i = 0; i < 6; i++){
    ln_bf16_kernel<<<MTOK, 256, 0, stream>>>(A, Bf, ln1_g + (size_t)i*512, ln1_b + (size_t)i*512);
    gemm_bf16_kernel<128,false,true><<<dim3(1536/128, MTOK/128), 256, 0, stream>>>(
        Bf, kqv_w + (size_t)i*1536*512, kqv_b + (size_t)i*1536, nullptr, Cb, MTOK, 1536, 512);
    temporal_attn_mfma_kernel<<<512, 256, 0, stream>>>(Cb, Ef);
    gemm_bf16_kernel<64,false,false><<<dim3(512/128, MTOK/64), 256, 0, stream>>>(
        Ef, proj_w + (size_t)i*512*512, proj_b + (size_t)i*512, A, A, MTOK, 512, 512);
    ln_bf16_kernel<<<MTOK, 256, 0, stream>>>(A, Bf, ln2_g + (size_t)i*512, ln2_b + (size_t)i*512);
    gemm_bf16_kernel<128,true,true><<<dim3(2048/128, MTOK/128), 256, 0, stream>>>(
        Bf, fc_w + (size_t)i*2048*512, fc_b + (size_t)i*2048, nullptr, Gf, MTOK, 2048, 512);
    gemm_bf16_kernel<64,false,false><<<dim3(512/128, MTOK/64), 256, 0, stream>>>(
        Gf, cproj_w + (size_t)i*512*2048, cproj_b + (size_t)i*512, A, A, MTOK, 512, 2048);
  }
  // final LN + heads
  ln_bf16_kernel<<<MTOK, 256, 0, stream>>>(A, Bf, lnf_g, lnf_b);
  reduce_tf_kernel<<<64, 256, 0, stream>>>(Bf, tf);
  head_kernel<<<68, 256, 0, stream>>>(tf, th_w1, th_b1, th_w2, th_b2,
                                      sh_w1, sh_b1, sh_w2, sh_b2,
                                      pf_w1, pf_b1, pf_w2, pf_b2, out);
  final_kernel<<<1, 64, 0, stream>>>(out);
}

// Round 6
// 1083.427 us; speedup vs baseline: 7.2431x; 1.2039x over previous
//
#include <hip/hip_runtime.h>
#include <hip/hip_bf16.h>
#include <math.h>

// Sizes: B=2 T=32 C=3 H=W=64 P=8 -> N=64, D=512, L=2048, M=B*T*N=4096
#define MTOK 4096

typedef __bf16 bf16x8 __attribute__((ext_vector_type(8)));
typedef float f32x4 __attribute__((ext_vector_type(4)));

__device__ __forceinline__ ushort f2bf(float f){
  __hip_bfloat16 h = __float2bfloat16(f);
  return *reinterpret_cast<ushort*>(&h);
}
__device__ __forceinline__ float bf2f(ushort u){
  return __uint_as_float(((uint)u) << 16);
}
__device__ __forceinline__ void gload_lds16(const void* g, void* l){
  __builtin_amdgcn_global_load_lds((__attribute__((address_space(1))) void*)(void*)g,
                                   (__attribute__((address_space(3))) void*)l, 16, 0, 0);
}

__device__ __forceinline__ float blockReduceSum(float v, float* red){
  #pragma unroll
  for (int off = 32; off; off >>= 1) v += __shfl_down(v, off, 64);
  int lane = threadIdx.x & 63, wid = threadIdx.x >> 6;
  __syncthreads();
  if (lane == 0) red[wid] = v;
  __syncthreads();
  float r = 0.f;
  int nw = blockDim.x >> 6;
  for (int i = 0; i < nw; i++) r += red[i];
  return r;
}
__device__ __forceinline__ float rowMax16(float v){
  #pragma unroll
  for (int m = 8; m; m >>= 1) v = fmaxf(v, __shfl_xor(v, m, 64));
  return v;
}
__device__ __forceinline__ float rowSum16(float v){
  #pragma unroll
  for (int m = 8; m; m >>= 1) v += __shfl_xor(v, m, 64);
  return v;
}

// ---------------- weight f32 -> bf16 (n multiple of 2048) ----------------
__global__ __launch_bounds__(256) void cvt_w_kernel(
    const float* __restrict__ src, ushort* __restrict__ dst, int n)
{
  int i = (blockIdx.x * 256 + threadIdx.x) * 8;
  float4 a = *(const float4*)(src + i);
  float4 b = *(const float4*)(src + i + 4);
  uint4 o;
  o.x = (uint)f2bf(a.x) | ((uint)f2bf(a.y) << 16);
  o.y = (uint)f2bf(a.z) | ((uint)f2bf(a.w) << 16);
  o.z = (uint)f2bf(b.x) | ((uint)f2bf(b.y) << 16);
  o.w = (uint)f2bf(b.z) | ((uint)f2bf(b.w) << 16);
  *(uint4*)(dst + i) = o;
}

// ---------------- im2col: x -> patches [4096][192] bf16 ----------------
__global__ __launch_bounds__(192) void im2col_kernel(
    const float* __restrict__ x, ushort* __restrict__ Pm)
{
  int m = blockIdx.x, e = threadIdx.x;
  int b = m >> 11, t = (m >> 6) & 31, n = m & 63;
  int hn = n >> 3, wn = n & 7;
  int c = e / 64, rem = e & 63;
  int ph = rem >> 3, pwj = rem & 7;
  Pm[(size_t)m*192 + e] = f2bf(x[(((size_t)(b*32 + t)*3 + c)*64 + hn*8 + ph)*64 + wn*8 + pwj]);
}

// ---------------- tok LN + pos: f32 in -> f32 A ----------------
__global__ __launch_bounds__(256) void ln_pos_kernel(
    const float* __restrict__ in, float* __restrict__ out,
    const float* __restrict__ g, const float* __restrict__ b,
    const float* __restrict__ spos, const float* __restrict__ tpos)
{
  int r = blockIdx.x, tid = threadIdx.x;
  int n = r & 63, t = (r >> 6) & 31;
  const float* row = in + (size_t)r * 512;
  float2 v = *(const float2*)(row + tid*2);
  __shared__ float red[4];
  float s = blockReduceSum(v.x + v.y, red);
  float mu = s * (1.f/512.f);
  float dx = v.x - mu, dy = v.y - mu;
  float vv = blockReduceSum(dx*dx + dy*dy, red);
  float inv = rsqrtf(vv * (1.f/512.f) + 1e-5f);
  float2 gg = *(const float2*)(g + tid*2);
  float2 bb = *(const float2*)(b + tid*2);
  float2 sp = *(const float2*)(spos + n*512 + tid*2);
  float2 tp = *(const float2*)(tpos + t*512 + tid*2);
  float2 o; o.x = dx*inv*gg.x + bb.x + sp.x + tp.x; o.y = dy*inv*gg.y + bb.y + sp.y + tp.y;
  *(float2*)(out + (size_t)r*512 + tid*2) = o;
}

// ---------------- LayerNorm (D=512) fp32 in -> bf16 out ----------------
__global__ __launch_bounds__(256) void ln_bf16_kernel(
    const float* __restrict__ in, ushort* __restrict__ out,
    const float* __restrict__ g, const float* __restrict__ b)
{
  int r = blockIdx.x, tid = threadIdx.x;
  const float* row = in + (size_t)r * 512;
  float2 v = *(const float2*)(row + tid*2);
  __shared__ float red[4];
  float s = blockReduceSum(v.x + v.y, red);
  float mu = s * (1.f/512.f);
  float dx = v.x - mu, dy = v.y - mu;
  float vv = blockReduceSum(dx*dx + dy*dy, red);
  float inv = rsqrtf(vv * (1.f/512.f) + 1e-5f);
  float2 gg = *(const float2*)(g + tid*2);
  float2 bb = *(const float2*)(b + tid*2);
  ushort2 o2; o2.x = f2bf(dx*inv*gg.x + bb.x); o2.y = f2bf(dy*inv*gg.y + bb.y);
  *(ushort2*)(out + (size_t)r*512 + tid*2) = o2;
}

// ---------------- MFMA GEMM v2: Y = X[M,K](bf16) @ Wb[N,K](bf16)^T + bias (+res)(+gelu) ----------------
// BM x BN tile, BK=64, 4 waves. BN=128: 2x2 wave layout; BN=64: 4x1 (wave 16-row slab).
// Both operands staged via global_load_lds (linear dest, pre-swizzled src), double-buffered,
// 2-phase pipeline: stage(t+1) issued before compute(t), one barrier per K-step.
// LDS rows 128B, swizzle: byte ^= (row&7)<<4.
template<int BM, int BN, bool GELU, bool BF16OUT>
__global__ __launch_bounds__(256) void gemm2_kernel(
    const ushort* __restrict__ X, const ushort* __restrict__ Wb,
    const float* __restrict__ bias, const float* __restrict__ res,
    void* __restrict__ Yv, int M, int Nn, int K)
{
  constexpr int WROWS = (BN == 128) ? 2 : 4;
  constexpr int WM = BM / WROWS;
  constexpr int FM = WM / 16;
  constexpr int FN = 4;
  __shared__ __attribute__((aligned(16))) char smem[2*(BM+BN)*128];
  char* Xs0 = smem;
  char* Ws0 = smem + BM*128;
  char* Xs1 = smem + (BM+BN)*128;
  char* Ws1 = Xs1 + BM*128;
  int tid = threadIdx.x, lane = tid & 63, wv = tid >> 6;
  int bm = blockIdx.y * BM, bn = blockIdx.x * BN;
  int wm, wn;
  if (BN == 128){ wm = (wv >> 1) * WM; wn = (wv & 1) * 64; }
  else          { wm = wv * WM;        wn = 0; }

  f32x4 acc[FM][FN];
  #pragma unroll
  for (int i = 0; i < FM; i++)
    #pragma unroll
    for (int j = 0; j < FN; j++){ f32x4 z = {0.f,0.f,0.f,0.f}; acc[i][j] = z; }

  int rowoff = wv*8 + (lane >> 3);
  int colsrc = ((lane & 7) ^ (lane >> 3)) * 16;

  auto stage = [&](char* Xd, char* Wd, int k0){
    #pragma unroll
    for (int i = 0; i < BM/32; i++){
      int row = i*32 + rowoff;
      gload_lds16((const char*)(X + (size_t)(bm + row)*K + k0) + colsrc,
                  Xd + (i*32 + wv*8)*128);
    }
    #pragma unroll
    for (int i = 0; i < BN/32; i++){
      int row = i*32 + rowoff;
      gload_lds16((const char*)(Wb + (size_t)(bn + row)*K + k0) + colsrc,
                  Wd + (i*32 + wv*8)*128);
    }
  };

  stage(Xs0, Ws0, 0);
  __syncthreads();                 // tile 0 ready (vmcnt drained by barrier)
  int nt = K >> 6;
  for (int t = 0; t < nt; t++){
    char* Xc = (t & 1) ? Xs1 : Xs0;
    char* Wc = (t & 1) ? Ws1 : Ws0;
    if (t + 1 < nt) stage((t & 1) ? Xs0 : Xs1, (t & 1) ? Ws0 : Ws1, (t+1)*64);
    #pragma unroll
    for (int kc = 0; kc < 2; kc++){
      bf16x8 a[FM], b[FN];
      #pragma unroll
      for (int f = 0; f < FM; f++){
        int ra = wm + f*16 + (lane & 15);
        a[f] = *(const bf16x8*)(Xc + ra*128 + ((kc*64 + (lane>>4)*16) ^ ((ra & 7) << 4)));
      }
      #pragma unroll
      for (int f = 0; f < FN; f++){
        int rb = wn + f*16 + (lane & 15);
        b[f] = *(const bf16x8*)(Wc + rb*128 + ((kc*64 + (lane>>4)*16) ^ ((rb & 7) << 4)));
      }
      #pragma unroll
      for (int i = 0; i < FM; i++)
        #pragma unroll
        for (int j = 0; j < FN; j++)
          acc[i][j] = __builtin_amdgcn_mfma_f32_16x16x32_bf16(a[i], b[j], acc[i][j], 0, 0, 0);
    }
    __syncthreads();               // prefetch landed; reads of current buffer done
  }
  int col0 = lane & 15;
  float bv[FN];
  #pragma unroll
  for (int fn = 0; fn < FN; fn++) bv[fn] = bias[bn + wn + fn*16 + col0];
  #pragma unroll
  for (int fm = 0; fm < FM; fm++){
    #pragma unroll
    for (int r = 0; r < 4; r++){
      int m = bm + wm + fm*16 + (lane >> 4)*4 + r;
      #pragma unroll
      for (int fn = 0; fn < FN; fn++){
        int n = bn + wn + fn*16 + col0;
        float v = acc[fm][fn][r] + bv[fn];
        if (res) v += res[(size_t)m*Nn + n];
        if (GELU) v = 0.5f * v * (1.f + erff(v * 0.70710678118654752440f));
        if (BF16OUT) ((ushort*)Yv)[(size_t)m*Nn + n] = f2bf(v);
        else         ((float*) Yv)[(size_t)m*Nn + n] = v;
      }
    }
  }
}

// ---------------- spatial attention, bf16 MFMA: per (frame, head), N=64, hd=128 ----------------
// qkv row (1536 bf16): [q 0:512 | k 512:1024 | v 1024:1536], head slice h*128.
__global__ __launch_bounds__(256) void spatial_attn_mfma_kernel(
    const ushort* __restrict__ qkv, ushort* __restrict__ y)
{
  __shared__ __attribute__((aligned(16))) char Ks[64*256];
  __shared__ __attribute__((aligned(16))) char Vt[128*128];
  __shared__ __attribute__((aligned(16))) char Ps[64*128];
  int bt = blockIdx.x, h = blockIdx.y;
  int tid = threadIdx.x, lane = tid & 63, w = tid >> 6;
  const ushort* base = qkv + (size_t)bt*64*1536 + (size_t)h*128;
  const float scale = 0.08838834764831845f;   // 1/sqrt(128)

  int qrow = w*16 + (lane & 15);
  bf16x8 qa[4];
  #pragma unroll
  for (int kc = 0; kc < 4; kc++)
    qa[kc] = *(const bf16x8*)(base + (size_t)qrow*1536 + kc*32 + (lane>>4)*8);

  #pragma unroll
  for (int i = 0; i < 4; i++){
    int row = w*16 + i*4 + (lane >> 4);
    const char* src = (const char*)(base + (size_t)row*1536 + 512) + (((lane & 15) ^ (row & 15)) * 16);
    char* dst = Ks + (w*16 + i*4)*256;
    gload_lds16(src, dst);
  }
  {
    int vj = (tid & 31) * 2;
    int d0 = (tid >> 5) * 16;
    const ushort* v0p = base + (size_t)vj*1536 + 1024 + d0;
    const ushort* v1p = v0p + 1536;
    uint4 a0 = *(const uint4*)(v0p);
    uint4 a1 = *(const uint4*)(v0p + 8);
    uint4 b0 = *(const uint4*)(v1p);
    uint4 b1 = *(const uint4*)(v1p + 8);
    uint av[8] = {a0.x, a0.y, a0.z, a0.w, a1.x, a1.y, a1.z, a1.w};
    uint bv[8] = {b0.x, b0.y, b0.z, b0.w, b1.x, b1.y, b1.z, b1.w};
    int cb = 4 * (tid & 31);
    #pragma unroll
    for (int e = 0; e < 8; e++){
      int dl = d0 + e*2, dh = dl + 1;
      uint vlo = (av[e] & 0xffffu) | ((bv[e] & 0xffffu) << 16);
      uint vhi = (av[e] >> 16) | (bv[e] & 0xffff0000u);
      *(uint*)(Vt + dl*128 + (cb ^ ((dl & 7) << 4))) = vlo;
      *(uint*)(Vt + dh*128 + (cb ^ ((dh & 7) << 4))) = vhi;
    }
  }
  __syncthreads();

  f32x4 zero4 = {0.f,0.f,0.f,0.f};
  f32x4 accS[4];
  #pragma unroll
  for (int jt = 0; jt < 4; jt++){
    accS[jt] = zero4;
    #pragma unroll
    for (int kc = 0; kc < 4; kc++){
      int krow = jt*16 + (lane & 15);
      bf16x8 kb = *(const bf16x8*)(Ks + krow*256 + ((kc*64 + (lane>>4)*16) ^ ((krow & 15) << 4)));
      accS[jt] = __builtin_amdgcn_mfma_f32_16x16x32_bf16(qa[kc], kb, accS[jt], 0, 0, 0);
    }
  }
  float l_sum[4];
  #pragma unroll
  for (int r = 0; r < 4; r++){
    float mx = fmaxf(fmaxf(accS[0][r], accS[1][r]), fmaxf(accS[2][r], accS[3][r]));
    mx = rowMax16(mx);
    int prow = w*16 + (lane>>4)*4 + r;
    int swz = (prow & 7) << 4;
    char* pbase = Ps + prow*128;
    float ps = 0.f;
    #pragma unroll
    for (int jt = 0; jt < 4; jt++){
      float p = __expf((accS[jt][r] - mx) * scale);
      ushort pb = f2bf(p);
      *(ushort*)(pbase + ((2*(jt*16 + (lane & 15))) ^ swz)) = pb;
      ps += bf2f(pb);
    }
    l_sum[r] = rowSum16(ps);
  }
  bf16x8 pa[2];
  #pragma unroll
  for (int kc2 = 0; kc2 < 2; kc2++){
    int prow = w*16 + (lane & 15);
    pa[kc2] = *(const bf16x8*)(Ps + prow*128 + ((kc2*64 + (lane>>4)*16) ^ ((prow & 7) << 4)));
  }
  f32x4 o[8];
  #pragma unroll
  for (int dt = 0; dt < 8; dt++){
    o[dt] = zero4;
    #pragma unroll
    for (int kc2 = 0; kc2 < 2; kc2++){
      int vrow = dt*16 + (lane & 15);
      bf16x8 vb = *(const bf16x8*)(Vt + vrow*128 + ((kc2*64 + (lane>>4)*16) ^ ((vrow & 7) << 4)));
      o[dt] = __builtin_amdgcn_mfma_f32_16x16x32_bf16(pa[kc2], vb, o[dt], 0, 0, 0);
    }
  }
  #pragma unroll
  for (int r = 0; r < 4; r++){
    float invl = 1.f / l_sum[r];
    int token = bt*64 + w*16 + (lane>>4)*4 + r;
    ushort* yrow = y + (size_t)token*512 + h*128;
    #pragma unroll
    for (int dt = 0; dt < 8; dt++)
      yrow[dt*16 + (lane & 15)] = f2bf(o[dt][r] * invl);
  }
}

// ---------------- temporal causal attention, bf16 MFMA flash, 2-phase pipelined ----------------
// qkv row (1536 bf16): [k 0:512 | q 512:1024 | v 1024:1536], head slice h*64.
// Per kt-step: prefetch K(kt+1) via gload_lds into buf^1 + V(kt+1) into regs,
// compute QK/softmax/PV on buf, ds_write V(kt+1), ONE barrier.
__global__ __launch_bounds__(256) void temporal_attn_mfma_kernel(
    const ushort* __restrict__ qkv, ushort* __restrict__ y)
{
  __shared__ __attribute__((aligned(16))) char Ks[2][64*128];
  __shared__ __attribute__((aligned(16))) char Vt[2][64*128];
  __shared__ __attribute__((aligned(16))) char Ps[64*128];
  int id = blockIdx.x;
  int bh = id & 15;
  int idx = id >> 4;
  int qt = (idx < 16) ? idx : 47 - idx;    // co-resident pair sums to 31
  int b = bh >> 3, h = bh & 7;
  int tid = threadIdx.x, lane = tid & 63, w = tid >> 6;
  const ushort* base = qkv + (size_t)(b*2048)*1536 + h*64;

  int qrow = qt*64 + w*16 + (lane & 15);
  bf16x8 qa[2];
  #pragma unroll
  for (int kc = 0; kc < 2; kc++)
    qa[kc] = *(const bf16x8*)(base + (size_t)qrow*1536 + 512 + kc*32 + (lane>>4)*8);

  f32x4 zero4 = {0.f,0.f,0.f,0.f};
  f32x4 o[4];
  float m_old[4], l_sum[4];
  #pragma unroll
  for (int dt = 0; dt < 4; dt++) o[dt] = zero4;
  #pragma unroll
  for (int r = 0; r < 4; r++){ m_old[r] = -1e30f; l_sum[r] = 0.f; }

  int kcolsrc = ((lane & 7) ^ (lane >> 3)) * 16;
  int vj = tid & 63;
  int vd0 = (tid >> 6) * 16;

  auto stageK = [&](char* dst, int kt){
    #pragma unroll
    for (int i = 0; i < 2; i++){
      int row = w*16 + i*8 + (lane >> 3);
      gload_lds16((const char*)(base + (size_t)(kt*64 + row)*1536) + kcolsrc,
                  dst + (w*16 + i*8)*128);
    }
  };
  auto loadV = [&](int kt, uint4& p0, uint4& p1){
    const ushort* vrow = base + (size_t)(kt*64 + vj)*1536 + 1024 + vd0;
    p0 = *(const uint4*)(vrow);
    p1 = *(const uint4*)(vrow + 8);
  };
  auto writeV = [&](char* dst, uint4 p0, uint4 p1){
    uint vals[8] = {p0.x, p0.y, p0.z, p0.w, p1.x, p1.y, p1.z, p1.w};
    #pragma unroll
    for (int e = 0; e < 8; e++){
      int d0 = vd0 + e*2;
      *(ushort*)(dst + d0*128     + ((2*vj) ^ (( d0    & 7) << 4))) = (ushort)(vals[e] & 0xffff);
      *(ushort*)(dst + (d0+1)*128 + ((2*vj) ^ (((d0+1) & 7) << 4))) = (ushort)(vals[e] >> 16);
    }
  };

  // prologue: tile 0
  stageK(Ks[0], 0);
  {
    uint4 p0, p1;
    loadV(0, p0, p1);
    writeV(Vt[0], p0, p1);   // compiler inserts vmcnt wait for p0/p1
  }
  __syncthreads();

  for (int kt = 0; kt <= qt; kt++){
    int cur = kt & 1;
    char* Kc = Ks[0] + cur*(64*128);   // static bases + offset select (no dyn array idx)
    char* Vc = Vt[0] + cur*(64*128);
    char* Kn = Ks[0] + (cur^1)*(64*128);
    char* Vn = Vt[0] + (cur^1)*(64*128);
    uint4 nv0, nv1;
    bool pf = (kt < qt);
    if (pf){
      stageK(Kn, kt+1);
      loadV(kt+1, nv0, nv1);
      __builtin_amdgcn_sched_barrier(0);   // pin prefetch issue before compute
    }

    f32x4 accS[4];
    #pragma unroll
    for (int jt = 0; jt < 4; jt++){
      accS[jt] = zero4;
      #pragma unroll
      for (int kc = 0; kc < 2; kc++){
        int krow = jt*16 + (lane & 15);
        bf16x8 kb = *(const bf16x8*)(Kc + krow*128 + ((kc*64 + (lane>>4)*16) ^ ((krow & 7) << 4)));
        accS[jt] = __builtin_amdgcn_mfma_f32_16x16x32_bf16(qa[kc], kb, accS[jt], 0, 0, 0);
      }
    }
    if (kt == qt){
      #pragma unroll
      for (int jt = 0; jt < 4; jt++){
        int gj = kt*64 + jt*16 + (lane & 15);
        #pragma unroll
        for (int r = 0; r < 4; r++){
          int gi = qt*64 + w*16 + (lane>>4)*4 + r;
          if (gj > gi) accS[jt][r] = -1e30f;
        }
      }
    }
    #pragma unroll
    for (int r = 0; r < 4; r++){
      float mloc = fmaxf(fmaxf(accS[0][r], accS[1][r]), fmaxf(accS[2][r], accS[3][r])) * 0.125f;
      mloc = rowMax16(mloc);
      float mnew = fmaxf(m_old[r], mloc);
      float corr = __expf(m_old[r] - mnew);
      int prow = w*16 + (lane>>4)*4 + r;
      int swz = (prow & 7) << 4;
      char* pbase = Ps + prow*128;
      float ps = 0.f;
      #pragma unroll
      for (int jt = 0; jt < 4; jt++){
        float p = __expf(accS[jt][r]*0.125f - mnew);
        ushort pb = f2bf(p);
        *(ushort*)(pbase + ((2*(jt*16 + (lane & 15))) ^ swz)) = pb;
        ps += bf2f(pb);
      }
      ps = rowSum16(ps);
      l_sum[r] = l_sum[r]*corr + ps;
      m_old[r] = mnew;
      #pragma unroll
      for (int dt = 0; dt < 4; dt++) o[dt][r] *= corr;
    }
    bf16x8 pa[2];
    #pragma unroll
    for (int kc2 = 0; kc2 < 2; kc2++){
      int prow = w*16 + (lane & 15);
      pa[kc2] = *(const bf16x8*)(Ps + prow*128 + ((kc2*64 + (lane>>4)*16) ^ ((prow & 7) << 4)));
    }
    #pragma unroll
    for (int dt = 0; dt < 4; dt++){
      #pragma unroll
      for (int kc2 = 0; kc2 < 2; kc2++){
        int vrow = dt*16 + (lane & 15);
        bf16x8 vb = *(const bf16x8*)(Vc + vrow*128 + ((kc2*64 + (lane>>4)*16) ^ ((vrow & 7) << 4)));
        o[dt] = __builtin_amdgcn_mfma_f32_16x16x32_bf16(pa[kc2], vb, o[dt], 0, 0, 0);
      }
    }
    if (pf) writeV(Vn, nv0, nv1);    // vmcnt wait auto-inserted for nv0/nv1
    __syncthreads();
  }
  #pragma unroll
  for (int r = 0; r < 4; r++){
    float invl = 1.f / l_sum[r];
    int token = qt*64 + w*16 + (lane>>4)*4 + r;
    ushort* yrow = y + (size_t)(b*2048 + token)*512 + h*64;
    #pragma unroll
    for (int dt = 0; dt < 4; dt++)
      yrow[dt*16 + (lane & 15)] = f2bf(o[dt][r] * invl);
  }
}

// ---------------- tf = mean over N of lnf(hid) (bf16 in, f32 out) ----------------
__global__ __launch_bounds__(256) void reduce_tf_kernel(const ushort* __restrict__ hid, float* __restrict__ tf){
  int bt = blockIdx.x, tid = threadIdx.x;
  for (int d = tid; d < 512; d += 256){
    float s = 0.f;
    for (int n = 0; n < 64; n++) s += bf2f(hid[((size_t)bt*64 + n)*512 + d]);
    tf[(size_t)bt*512 + d] = s * (1.f/64.f);
  }
}

// ---------------- heads ----------------
__global__ __launch_bounds__(256) void head_kernel(
    const float* __restrict__ tf,
    const float* __restrict__ th_w1, const float* __restrict__ th_b1,
    const float* __restrict__ th_w2, const float* __restrict__ th_b2,
    const float* __restrict__ sh_w1, const float* __restrict__ sh_b1,
    const float* __restrict__ sh_w2, const float* __restrict__ sh_b2,
    const float* __restrict__ pf_w1, const float* __restrict__ pf_b1,
    const float* __restrict__ pf_w2, const float* __restrict__ pf_b2,
    float* __restrict__ out)
{
  __shared__ float z[512];
  __shared__ float red[4];
  int bi = blockIdx.x, tid = threadIdx.x;
  const float *w1, *b1, *w2, *b2;
  float* dst;
  if (bi < 64){
    w1 = pf_w1; b1 = pf_b1; w2 = pf_w2; b2 = pf_b2; dst = out + 4 + bi;
    z[tid]       = tf[(size_t)bi*512 + tid];
    z[tid + 256] = tf[(size_t)bi*512 + tid + 256];
  } else if (bi < 66){
    int b = bi - 64;
    w1 = th_w1; b1 = th_b1; w2 = th_w2; b2 = th_b2; dst = out + b;
    z[tid]       = tf[(size_t)(b*32 + 31)*512 + tid];
    z[tid + 256] = tf[(size_t)(b*32 + 31)*512 + tid + 256];
  } else {
    int b = bi - 66;
    w1 = sh_w1; b1 = sh_b1; w2 = sh_w2; b2 = sh_b2; dst = out + 2 + b;
    float s0 = 0.f, s1 = 0.f;
    for (int t = 0; t < 32; t++){
      s0 += tf[(size_t)(b*32 + t)*512 + tid];
      s1 += tf[(size_t)(b*32 + t)*512 + tid + 256];
    }
    z[tid] = s0 * (1.f/32.f); z[tid + 256] = s1 * (1.f/32.f);
  }
  __syncthreads();
  float a = b1[tid];
  const float* wrow = w1 + (size_t)tid * 512;
  for (int k = 0; k < 512; k++) a = fmaf(wrow[k], z[k], a);
  a = (a > 0.f) ? a : 0.2f * a;
  float s = blockReduceSum(a * w2[tid], red);
  if (tid == 0) *dst = s + b2[0];
}

__global__ __launch_bounds__(64) void final_kernel(float* __restrict__ out){
  int b = threadIdx.x;
  if (b < 2){
    float s = 0.f;
    for (int t = 0; t < 32; t++) s += out[4 + b*32 + t];
    out[68 + b] = out[b] + out[2 + b] + s * (1.f/32.f);
  }
}

extern "C" void kernel_launch(void* const* d_in, const int* in_sizes, int n_in,
                              void* d_out, int out_size, void* d_ws, size_t ws_size,
                              hipStream_t stream)
{
  const float* x          = (const float*)d_in[0];
  const float* patch_w    = (const float*)d_in[1];
  const float* patch_b    = (const float*)d_in[2];
  const float* tok_ln_g   = (const float*)d_in[3];
  const float* tok_ln_b   = (const float*)d_in[4];
  const float* spatial_pos= (const float*)d_in[5];
  const float* temporal_pos=(const float*)d_in[6];
  const float* snorm_g    = (const float*)d_in[7];
  const float* snorm_b    = (const float*)d_in[8];
  const float* sa_in_w    = (const float*)d_in[9];
  const float* sa_in_b    = (const float*)d_in[10];
  const float* sa_out_w   = (const float*)d_in[11];
  const float* sa_out_b   = (const float*)d_in[12];
  const float* ln1_g      = (const float*)d_in[13];
  const float* ln1_b      = (const float*)d_in[14];
  const float* kqv_w      = (const float*)d_in[15];
  const float* kqv_b      = (const float*)d_in[16];
  const float* proj_w     = (const float*)d_in[17];
  const float* proj_b     = (const float*)d_in[18];
  const float* ln2_g      = (const float*)d_in[19];
  const float* ln2_b      = (const float*)d_in[20];
  const float* fc_w       = (const float*)d_in[21];
  const float* fc_b       = (const float*)d_in[22];
  const float* cproj_w    = (const float*)d_in[23];
  const float* cproj_b    = (const float*)d_in[24];
  const float* lnf_g      = (const float*)d_in[25];
  const float* lnf_b      = (const float*)d_in[26];
  const float* th_w1 = (const float*)d_in[27];
  const float* th_b1 = (const float*)d_in[28];
  const float* th_w2 = (const float*)d_in[29];
  const float* th_b2 = (const float*)d_in[30];
  const float* sh_w1 = (const float*)d_in[31];
  const float* sh_b1 = (const float*)d_in[32];
  const float* sh_w2 = (const float*)d_in[33];
  const float* sh_b2 = (const float*)d_in[34];
  const float* pf_w1 = (const float*)d_in[35];
  const float* pf_b1 = (const float*)d_in[36];
  const float* pf_w2 = (const float*)d_in[37];
  const float* pf_b2 = (const float*)d_in[38];

  float* out = (float*)d_out;
  // workspace layout (bytes)
  char* p = (char*)d_ws;
  float*  A  = (float*)p;      p += (size_t)MTOK*512*4;    // f32 hidden
  ushort* Ru = (ushort*)p;     p += (size_t)MTOK*2048*2;   // bf16 region: qkv / gelu; f32 patch-gemm out
  ushort* Bf = (ushort*)p;     p += (size_t)MTOK*512*2;    // ln out bf16
  ushort* Ef = (ushort*)p;     p += (size_t)MTOK*512*2;    // attn out bf16 (also im2col patches)
  float*  tfp = (float*)p;     p += (size_t)64*512*4;
  ushort* Wslot = (ushort*)p;  p += (size_t)1048576*2;     // bf16 weight slot (max 1M elems)
  float*  Pf = (float*)Ru;     // patch gemm f32 out 4096x512
  ushort* Pm = Ef;             // patches bf16 4096x192 (before Ef first written)

  // patch embed: im2col -> cvt W -> MFMA GEMM -> LN+pos
  im2col_kernel<<<MTOK, 192, 0, stream>>>(x, Pm);
  cvt_w_kernel<<<48, 256, 0, stream>>>(patch_w, Wslot, 512*192);
  gemm2_kernel<64,64,false,false><<<dim3(8, 64), 256, 0, stream>>>(
      Pm, Wslot, patch_b, nullptr, Pf, MTOK, 512, 192);
  ln_pos_kernel<<<MTOK, 256, 0, stream>>>(Pf, A, tok_ln_g, tok_ln_b, spatial_pos, temporal_pos);

  // spatial layers
  for (int i = 0; i < 3; i++){
    ln_bf16_kernel<<<MTOK, 256, 0, stream>>>(A, Bf, snorm_g, snorm_b);
    cvt_w_kernel<<<384, 256, 0, stream>>>(sa_in_w + (size_t)i*1536*512, Wslot, 1536*512);
    gemm2_kernel<64,128,false,true><<<dim3(12, 64), 256, 0, stream>>>(
        Bf, Wslot, sa_in_b + (size_t)i*1536, nullptr, Ru, MTOK, 1536, 512);
    spatial_attn_mfma_kernel<<<dim3(64, 4), 256, 0, stream>>>(Ru, Ef);
    cvt_w_kernel<<<128, 256, 0, stream>>>(sa_out_w + (size_t)i*512*512, Wslot, 512*512);
    gemm2_kernel<64,64,false,false><<<dim3(8, 64), 256, 0, stream>>>(
        Ef, Wslot, sa_out_b + (size_t)i*512, A, A, MTOK, 512, 512);
  }
  // temporal layers
  for (int i = 0; i < 6; i++){
    ln_bf16_kernel<<<MTOK, 256, 0, stream>>>(A, Bf, ln1_g + (size_t)i*512, ln1_b + (size_t)i*512);
    cvt_w_kernel<<<384, 256, 0, stream>>>(kqv_w + (size_t)i*1536*512, Wslot, 1536*512);
    gemm2_kernel<64,128,false,true><<<dim3(12, 64), 256, 0, stream>>>(
        Bf, Wslot, kqv_b + (size_t)i*1536, nullptr, Ru, MTOK, 1536, 512);
    temporal_attn_mfma_kernel<<<512, 256, 0, stream>>>(Ru, Ef);
    cvt_w_kernel<<<128, 256, 0, stream>>>(proj_w + (size_t)i*512*512, Wslot, 512*512);
    gemm2_kernel<64,64,false,false><<<dim3(8, 64), 256, 0, stream>>>(
        Ef, Wslot, proj_b + (size_t)i*512, A, A, MTOK, 512, 512);
    ln_bf16_kernel<<<MTOK, 256, 0, stream>>>(A, Bf, ln2_g + (size_t)i*512, ln2_b + (size_t)i*512);
    cvt_w_kernel<<<512, 256, 0, stream>>>(fc_w + (size_t)i*2048*512, Wslot, 2048*512);
    gemm2_kernel<128,128,true,true><<<dim3(16, 32), 256, 0, stream>>>(
        Bf, Wslot, fc_b + (size_t)i*2048, nullptr, Ru, MTOK, 2048, 512);
    cvt_w_kernel<<<512, 256, 0, stream>>>(cproj_w + (size_t)i*512*2048, Wslot, 512*2048);
    gemm2_kernel<64,64,false,false><<<dim3(8, 64), 256, 0, stream>>>(
        Ru, Wslot, cproj_b + (size_t)i*512, A, A, MTOK, 512, 2048);
  }
  // final LN + heads
  ln_bf16_kernel<<<MTOK, 256, 0, stream>>>(A, Bf, lnf_g, lnf_b);
  reduce_tf_kernel<<<64, 256, 0, stream>>>(Bf, tfp);
  head_kernel<<<68, 256, 0, stream>>>(tfp, th_w1, th_b1, th_w2, th_b2,
                                      sh_w1, sh_b1, sh_w2, sh_b2,
                                      pf_w1, pf_b1, pf_w2, pf_b2, out);
  final_kernel<<<1, 64, 0, stream>>>(out);
}

// Round 7
// 1025.491 us; speedup vs baseline: 7.6523x; 1.0565x over previous
//
#include <hip/hip_runtime.h>
#include <hip/hip_bf16.h>
#include <math.h>

// Sizes: B=2 T=32 C=3 H=W=64 P=8 -> N=64, D=512, L=2048, M=B*T*N=4096
#define MTOK 4096

typedef __bf16 bf16x8 __attribute__((ext_vector_type(8)));
typedef float f32x4 __attribute__((ext_vector_type(4)));

__device__ __forceinline__ ushort f2bf(float f){
  __hip_bfloat16 h = __float2bfloat16(f);
  return *reinterpret_cast<ushort*>(&h);
}
__device__ __forceinline__ float bf2f(ushort u){
  return __uint_as_float(((uint)u) << 16);
}
__device__ __forceinline__ void gload_lds16(const void* g, void* l){
  __builtin_amdgcn_global_load_lds((__attribute__((address_space(1))) void*)(void*)g,
                                   (__attribute__((address_space(3))) void*)l, 16, 0, 0);
}

__device__ __forceinline__ float blockReduceSum(float v, float* red){
  #pragma unroll
  for (int off = 32; off; off >>= 1) v += __shfl_down(v, off, 64);
  int lane = threadIdx.x & 63, wid = threadIdx.x >> 6;
  __syncthreads();
  if (lane == 0) red[wid] = v;
  __syncthreads();
  float r = 0.f;
  int nw = blockDim.x >> 6;
  for (int i = 0; i < nw; i++) r += red[i];
  return r;
}
__device__ __forceinline__ float rowMax16(float v){
  #pragma unroll
  for (int m = 8; m; m >>= 1) v = fmaxf(v, __shfl_xor(v, m, 64));
  return v;
}
__device__ __forceinline__ float rowSum16(float v){
  #pragma unroll
  for (int m = 8; m; m >>= 1) v += __shfl_xor(v, m, 64);
  return v;
}

// ---------------- weight f32 -> bf16 (per-matrix fallback; n multiple of 2048) ----------------
__global__ __launch_bounds__(256) void cvt_w_kernel(
    const float* __restrict__ src, ushort* __restrict__ dst, int n)
{
  int i = (blockIdx.x * 256 + threadIdx.x) * 8;
  float4 a = *(const float4*)(src + i);
  float4 b = *(const float4*)(src + i + 4);
  uint4 o;
  o.x = (uint)f2bf(a.x) | ((uint)f2bf(a.y) << 16);
  o.y = (uint)f2bf(a.z) | ((uint)f2bf(a.w) << 16);
  o.z = (uint)f2bf(b.x) | ((uint)f2bf(b.y) << 16);
  o.w = (uint)f2bf(b.z) | ((uint)f2bf(b.w) << 16);
  *(uint4*)(dst + i) = o;
}

// ---------------- all weights -> bf16 arena (one dispatch) ----------------
// arena element offsets
#define OFF_PATCH 0u
#define OFF_SAIN  98304u
#define OFF_SAOUT 2457600u
#define OFF_KQV   3244032u
#define OFF_PROJ  7962624u
#define OFF_FC    9535488u
#define OFF_CPROJ 15826944u
#define W_TOTAL   22118400u
__global__ __launch_bounds__(256) void cvt_all_kernel(
    const float* __restrict__ pw, const float* __restrict__ sain,
    const float* __restrict__ saout, const float* __restrict__ kqv,
    const float* __restrict__ proj, const float* __restrict__ fc,
    const float* __restrict__ cproj, ushort* __restrict__ dst)
{
  int blk = blockIdx.x;
  const float* src; size_t off;
  if      (blk <    48){ src = pw;    off = OFF_PATCH; }
  else if (blk <  1200){ src = sain;  off = OFF_SAIN;  blk -= 48;   }
  else if (blk <  1584){ src = saout; off = OFF_SAOUT; blk -= 1200; }
  else if (blk <  3888){ src = kqv;   off = OFF_KQV;   blk -= 1584; }
  else if (blk <  4656){ src = proj;  off = OFF_PROJ;  blk -= 3888; }
  else if (blk <  7728){ src = fc;    off = OFF_FC;    blk -= 4656; }
  else                 { src = cproj; off = OFF_CPROJ; blk -= 7728; }
  size_t si = (size_t)blk*2048 + threadIdx.x*8;
  float4 a = *(const float4*)(src + si);
  float4 b = *(const float4*)(src + si + 4);
  uint4 o;
  o.x = (uint)f2bf(a.x) | ((uint)f2bf(a.y) << 16);
  o.y = (uint)f2bf(a.z) | ((uint)f2bf(a.w) << 16);
  o.z = (uint)f2bf(b.x) | ((uint)f2bf(b.y) << 16);
  o.w = (uint)f2bf(b.z) | ((uint)f2bf(b.w) << 16);
  *(uint4*)(dst + off + si) = o;
}

// ---------------- im2col: x -> patches [4096][192] bf16 (8 elems/thread) ----------------
__global__ __launch_bounds__(256) void im2col_kernel(
    const float* __restrict__ x, ushort* __restrict__ Pm)
{
  int idx = blockIdx.x*256 + threadIdx.x;   // 0..98303
  int m = idx / 24, e8 = idx % 24;
  int b = m >> 11, t = (m >> 6) & 31, n = m & 63;
  int hn = n >> 3, wn = n & 7;
  int c = e8 >> 3, ph = e8 & 7;
  const float* src = x + (((size_t)(b*32 + t)*3 + c)*64 + hn*8 + ph)*64 + wn*8;
  float4 a = *(const float4*)src;
  float4 bq = *(const float4*)(src + 4);
  uint4 o;
  o.x = (uint)f2bf(a.x) | ((uint)f2bf(a.y) << 16);
  o.y = (uint)f2bf(a.z) | ((uint)f2bf(a.w) << 16);
  o.z = (uint)f2bf(bq.x) | ((uint)f2bf(bq.y) << 16);
  o.w = (uint)f2bf(bq.z) | ((uint)f2bf(bq.w) << 16);
  *(uint4*)(Pm + (size_t)m*192 + e8*8) = o;
}

// ---------------- tok LN + pos (wave per row, 4 rows/block) ----------------
__global__ __launch_bounds__(256) void ln_pos_kernel(
    const float* __restrict__ in, float* __restrict__ out,
    const float* __restrict__ g, const float* __restrict__ b,
    const float* __restrict__ spos, const float* __restrict__ tpos)
{
  int r = blockIdx.x*4 + (threadIdx.x >> 6);
  int lane = threadIdx.x & 63;
  int n = r & 63, t = (r >> 6) & 31;
  const float* row = in + (size_t)r*512 + lane*8;
  float4 v0 = *(const float4*)row;
  float4 v1 = *(const float4*)(row + 4);
  float s = v0.x+v0.y+v0.z+v0.w+v1.x+v1.y+v1.z+v1.w;
  float q = v0.x*v0.x+v0.y*v0.y+v0.z*v0.z+v0.w*v0.w+v1.x*v1.x+v1.y*v1.y+v1.z*v1.z+v1.w*v1.w;
  #pragma unroll
  for (int m = 1; m < 64; m <<= 1){ s += __shfl_xor(s, m, 64); q += __shfl_xor(q, m, 64); }
  float mu = s*(1.f/512.f);
  float inv = rsqrtf(q*(1.f/512.f) - mu*mu + 1e-5f);
  const float* gp = g + lane*8;
  const float* bp = b + lane*8;
  const float* sp = spos + n*512 + lane*8;
  const float* tp = tpos + t*512 + lane*8;
  float* op = out + (size_t)r*512 + lane*8;
  #pragma unroll
  for (int e = 0; e < 2; e++){
    float4 vv = e ? v1 : v0;
    float4 gg = *(const float4*)(gp + e*4);
    float4 bb = *(const float4*)(bp + e*4);
    float4 ss = *(const float4*)(sp + e*4);
    float4 tt = *(const float4*)(tp + e*4);
    float4 oo;
    oo.x = (vv.x-mu)*inv*gg.x + bb.x + ss.x + tt.x;
    oo.y = (vv.y-mu)*inv*gg.y + bb.y + ss.y + tt.y;
    oo.z = (vv.z-mu)*inv*gg.z + bb.z + ss.z + tt.z;
    oo.w = (vv.w-mu)*inv*gg.w + bb.w + ss.w + tt.w;
    *(float4*)(op + e*4) = oo;
  }
}

// ---------------- LayerNorm (D=512) fp32 in -> bf16 out (wave per row) ----------------
__global__ __launch_bounds__(256) void ln_bf16_kernel(
    const float* __restrict__ in, ushort* __restrict__ out,
    const float* __restrict__ g, const float* __restrict__ b)
{
  int r = blockIdx.x*4 + (threadIdx.x >> 6);
  int lane = threadIdx.x & 63;
  const float* row = in + (size_t)r*512 + lane*8;
  float4 v0 = *(const float4*)row;
  float4 v1 = *(const float4*)(row + 4);
  float s = v0.x+v0.y+v0.z+v0.w+v1.x+v1.y+v1.z+v1.w;
  float q = v0.x*v0.x+v0.y*v0.y+v0.z*v0.z+v0.w*v0.w+v1.x*v1.x+v1.y*v1.y+v1.z*v1.z+v1.w*v1.w;
  #pragma unroll
  for (int m = 1; m < 64; m <<= 1){ s += __shfl_xor(s, m, 64); q += __shfl_xor(q, m, 64); }
  float mu = s*(1.f/512.f);
  float inv = rsqrtf(q*(1.f/512.f) - mu*mu + 1e-5f);
  float4 g0 = *(const float4*)(g + lane*8);
  float4 g1 = *(const float4*)(g + lane*8 + 4);
  float4 b0 = *(const float4*)(b + lane*8);
  float4 b1 = *(const float4*)(b + lane*8 + 4);
  uint4 o;
  o.x = (uint)f2bf((v0.x-mu)*inv*g0.x + b0.x) | ((uint)f2bf((v0.y-mu)*inv*g0.y + b0.y) << 16);
  o.y = (uint)f2bf((v0.z-mu)*inv*g0.z + b0.z) | ((uint)f2bf((v0.w-mu)*inv*g0.w + b0.w) << 16);
  o.z = (uint)f2bf((v1.x-mu)*inv*g1.x + b1.x) | ((uint)f2bf((v1.y-mu)*inv*g1.y + b1.y) << 16);
  o.w = (uint)f2bf((v1.z-mu)*inv*g1.z + b1.z) | ((uint)f2bf((v1.w-mu)*inv*g1.w + b1.w) << 16);
  *(uint4*)(out + (size_t)r*512 + lane*8) = o;
}

// ---------------- MFMA GEMM v2 (unchanged from R6) ----------------
template<int BM, int BN, bool GELU, bool BF16OUT>
__global__ __launch_bounds__(256) void gemm2_kernel(
    const ushort* __restrict__ X, const ushort* __restrict__ Wb,
    const float* __restrict__ bias, const float* __restrict__ res,
    void* __restrict__ Yv, int M, int Nn, int K)
{
  constexpr int WROWS = (BN == 128) ? 2 : 4;
  constexpr int WM = BM / WROWS;
  constexpr int FM = WM / 16;
  constexpr int FN = 4;
  __shared__ __attribute__((aligned(16))) char smem[2*(BM+BN)*128];
  char* Xs0 = smem;
  char* Ws0 = smem + BM*128;
  char* Xs1 = smem + (BM+BN)*128;
  char* Ws1 = Xs1 + BM*128;
  int tid = threadIdx.x, lane = tid & 63, wv = tid >> 6;
  int bm = blockIdx.y * BM, bn = blockIdx.x * BN;
  int wm, wn;
  if (BN == 128){ wm = (wv >> 1) * WM; wn = (wv & 1) * 64; }
  else          { wm = wv * WM;        wn = 0; }

  f32x4 acc[FM][FN];
  #pragma unroll
  for (int i = 0; i < FM; i++)
    #pragma unroll
    for (int j = 0; j < FN; j++){ f32x4 z = {0.f,0.f,0.f,0.f}; acc[i][j] = z; }

  int rowoff = wv*8 + (lane >> 3);
  int colsrc = ((lane & 7) ^ (lane >> 3)) * 16;

  auto stage = [&](char* Xd, char* Wd, int k0){
    #pragma unroll
    for (int i = 0; i < BM/32; i++){
      int row = i*32 + rowoff;
      gload_lds16((const char*)(X + (size_t)(bm + row)*K + k0) + colsrc,
                  Xd + (i*32 + wv*8)*128);
    }
    #pragma unroll
    for (int i = 0; i < BN/32; i++){
      int row = i*32 + rowoff;
      gload_lds16((const char*)(Wb + (size_t)(bn + row)*K + k0) + colsrc,
                  Wd + (i*32 + wv*8)*128);
    }
  };

  stage(Xs0, Ws0, 0);
  __syncthreads();
  int nt = K >> 6;
  for (int t = 0; t < nt; t++){
    char* Xc = (t & 1) ? Xs1 : Xs0;
    char* Wc = (t & 1) ? Ws1 : Ws0;
    if (t + 1 < nt) stage((t & 1) ? Xs0 : Xs1, (t & 1) ? Ws0 : Ws1, (t+1)*64);
    #pragma unroll
    for (int kc = 0; kc < 2; kc++){
      bf16x8 a[FM], b[FN];
      #pragma unroll
      for (int f = 0; f < FM; f++){
        int ra = wm + f*16 + (lane & 15);
        a[f] = *(const bf16x8*)(Xc + ra*128 + ((kc*64 + (lane>>4)*16) ^ ((ra & 7) << 4)));
      }
      #pragma unroll
      for (int f = 0; f < FN; f++){
        int rb = wn + f*16 + (lane & 15);
        b[f] = *(const bf16x8*)(Wc + rb*128 + ((kc*64 + (lane>>4)*16) ^ ((rb & 7) << 4)));
      }
      #pragma unroll
      for (int i = 0; i < FM; i++)
        #pragma unroll
        for (int j = 0; j < FN; j++)
          acc[i][j] = __builtin_amdgcn_mfma_f32_16x16x32_bf16(a[i], b[j], acc[i][j], 0, 0, 0);
    }
    __syncthreads();
  }
  int col0 = lane & 15;
  float bv[FN];
  #pragma unroll
  for (int fn = 0; fn < FN; fn++) bv[fn] = bias[bn + wn + fn*16 + col0];
  #pragma unroll
  for (int fm = 0; fm < FM; fm++){
    #pragma unroll
    for (int r = 0; r < 4; r++){
      int m = bm + wm + fm*16 + (lane >> 4)*4 + r;
      #pragma unroll
      for (int fn = 0; fn < FN; fn++){
        int n = bn + wn + fn*16 + col0;
        float v = acc[fm][fn][r] + bv[fn];
        if (res) v += res[(size_t)m*Nn + n];
        if (GELU) v = 0.5f * v * (1.f + erff(v * 0.70710678118654752440f));
        if (BF16OUT) ((ushort*)Yv)[(size_t)m*Nn + n] = f2bf(v);
        else         ((float*) Yv)[(size_t)m*Nn + n] = v;
      }
    }
  }
}

// ---------------- spatial attention, bf16 MFMA (unchanged) ----------------
__global__ __launch_bounds__(256) void spatial_attn_mfma_kernel(
    const ushort* __restrict__ qkv, ushort* __restrict__ y)
{
  __shared__ __attribute__((aligned(16))) char Ks[64*256];
  __shared__ __attribute__((aligned(16))) char Vt[128*128];
  __shared__ __attribute__((aligned(16))) char Ps[64*128];
  int bt = blockIdx.x, h = blockIdx.y;
  int tid = threadIdx.x, lane = tid & 63, w = tid >> 6;
  const ushort* base = qkv + (size_t)bt*64*1536 + (size_t)h*128;
  const float scale = 0.08838834764831845f;

  int qrow = w*16 + (lane & 15);
  bf16x8 qa[4];
  #pragma unroll
  for (int kc = 0; kc < 4; kc++)
    qa[kc] = *(const bf16x8*)(base + (size_t)qrow*1536 + kc*32 + (lane>>4)*8);

  #pragma unroll
  for (int i = 0; i < 4; i++){
    int row = w*16 + i*4 + (lane >> 4);
    const char* src = (const char*)(base + (size_t)row*1536 + 512) + (((lane & 15) ^ (row & 15)) * 16);
    char* dst = Ks + (w*16 + i*4)*256;
    gload_lds16(src, dst);
  }
  {
    int vj = (tid & 31) * 2;
    int d0 = (tid >> 5) * 16;
    const ushort* v0p = base + (size_t)vj*1536 + 1024 + d0;
    const ushort* v1p = v0p + 1536;
    uint4 a0 = *(const uint4*)(v0p);
    uint4 a1 = *(const uint4*)(v0p + 8);
    uint4 b0 = *(const uint4*)(v1p);
    uint4 b1 = *(const uint4*)(v1p + 8);
    uint av[8] = {a0.x, a0.y, a0.z, a0.w, a1.x, a1.y, a1.z, a1.w};
    uint bv[8] = {b0.x, b0.y, b0.z, b0.w, b1.x, b1.y, b1.z, b1.w};
    int cb = 4 * (tid & 31);
    #pragma unroll
    for (int e = 0; e < 8; e++){
      int dl = d0 + e*2, dh = dl + 1;
      uint vlo = (av[e] & 0xffffu) | ((bv[e] & 0xffffu) << 16);
      uint vhi = (av[e] >> 16) | (bv[e] & 0xffff0000u);
      *(uint*)(Vt + dl*128 + (cb ^ ((dl & 7) << 4))) = vlo;
      *(uint*)(Vt + dh*128 + (cb ^ ((dh & 7) << 4))) = vhi;
    }
  }
  __syncthreads();

  f32x4 zero4 = {0.f,0.f,0.f,0.f};
  f32x4 accS[4];
  __builtin_amdgcn_s_setprio(1);
  #pragma unroll
  for (int jt = 0; jt < 4; jt++){
    accS[jt] = zero4;
    #pragma unroll
    for (int kc = 0; kc < 4; kc++){
      int krow = jt*16 + (lane & 15);
      bf16x8 kb = *(const bf16x8*)(Ks + krow*256 + ((kc*64 + (lane>>4)*16) ^ ((krow & 15) << 4)));
      accS[jt] = __builtin_amdgcn_mfma_f32_16x16x32_bf16(qa[kc], kb, accS[jt], 0, 0, 0);
    }
  }
  __builtin_amdgcn_s_setprio(0);
  float l_sum[4];
  #pragma unroll
  for (int r = 0; r < 4; r++){
    float mx = fmaxf(fmaxf(accS[0][r], accS[1][r]), fmaxf(accS[2][r], accS[3][r]));
    mx = rowMax16(mx);
    int prow = w*16 + (lane>>4)*4 + r;
    int swz = (prow & 7) << 4;
    char* pbase = Ps + prow*128;
    float ps = 0.f;
    #pragma unroll
    for (int jt = 0; jt < 4; jt++){
      float p = __expf((accS[jt][r] - mx) * scale);
      ushort pb = f2bf(p);
      *(ushort*)(pbase + ((2*(jt*16 + (lane & 15))) ^ swz)) = pb;
      ps += bf2f(pb);
    }
    l_sum[r] = rowSum16(ps);
  }
  bf16x8 pa[2];
  #pragma unroll
  for (int kc2 = 0; kc2 < 2; kc2++){
    int prow = w*16 + (lane & 15);
    pa[kc2] = *(const bf16x8*)(Ps + prow*128 + ((kc2*64 + (lane>>4)*16) ^ ((prow & 7) << 4)));
  }
  f32x4 o[8];
  __builtin_amdgcn_s_setprio(1);
  #pragma unroll
  for (int dt = 0; dt < 8; dt++){
    o[dt] = zero4;
    #pragma unroll
    for (int kc2 = 0; kc2 < 2; kc2++){
      int vrow = dt*16 + (lane & 15);
      bf16x8 vb = *(const bf16x8*)(Vt + vrow*128 + ((kc2*64 + (lane>>4)*16) ^ ((vrow & 7) << 4)));
      o[dt] = __builtin_amdgcn_mfma_f32_16x16x32_bf16(pa[kc2], vb, o[dt], 0, 0, 0);
    }
  }
  __builtin_amdgcn_s_setprio(0);
  #pragma unroll
  for (int r = 0; r < 4; r++){
    float invl = 1.f / l_sum[r];
    int token = bt*64 + w*16 + (lane>>4)*4 + r;
    ushort* yrow = y + (size_t)token*512 + h*128;
    #pragma unroll
    for (int dt = 0; dt < 8; dt++)
      yrow[dt*16 + (lane & 15)] = f2bf(o[dt][r] * invl);
  }
}

// ---------------- temporal causal attention v3: QBLK=32, 2 waves, all blocks resident ----------------
// qkv row (1536 bf16): [k 0:512 | q 512:1024 | v 1024:1536], head slice h*64.
// grid 1024 = 64 q-tiles x 16 (b,h). LDS 20KB -> 4+ blocks/CU (all co-resident).
__global__ __launch_bounds__(128) void temporal_attn_mfma_kernel(
    const ushort* __restrict__ qkv, ushort* __restrict__ y)
{
  __shared__ __attribute__((aligned(16))) char Ks[64*128];
  __shared__ __attribute__((aligned(16))) char Vt[64*128];
  __shared__ __attribute__((aligned(16))) char Ps[32*128];
  int id = blockIdx.x;
  int bh = id & 15;
  int idx = id >> 4;                       // 0..63
  int qt = (idx < 32) ? (63 - idx) : (idx - 32);  // heavy tiles dispatch first
  int b = bh >> 3, h = bh & 7;
  int tid = threadIdx.x, lane = tid & 63, w = tid >> 6;   // w in {0,1}
  const ushort* base = qkv + (size_t)(b*2048)*1536 + h*64;

  int qrow = qt*32 + w*16 + (lane & 15);
  bf16x8 qa[2];
  #pragma unroll
  for (int kc = 0; kc < 2; kc++)
    qa[kc] = *(const bf16x8*)(base + (size_t)qrow*1536 + 512 + kc*32 + (lane>>4)*8);

  f32x4 zero4 = {0.f,0.f,0.f,0.f};
  f32x4 o[4];
  float m_old[4], l_sum[4];
  #pragma unroll
  for (int dt = 0; dt < 4; dt++) o[dt] = zero4;
  #pragma unroll
  for (int r = 0; r < 4; r++){ m_old[r] = -1e30f; l_sum[r] = 0.f; }

  int kcolsrc = ((lane & 7) ^ (lane >> 3)) * 16;
  int vj = (tid & 31) * 2;       // key pair
  int vd0 = (tid >> 5) * 16;     // d segment 0/16/32/48

  int ktmax = qt >> 1;
  for (int kt = 0; kt <= ktmax; kt++){
    __syncthreads();   // prev tile's LDS reads complete
    // stage K: wave w covers keys w*32..w*32+31 (4 gloads)
    #pragma unroll
    for (int i = 0; i < 4; i++){
      int row = w*32 + i*8 + (lane >> 3);
      gload_lds16((const char*)(base + (size_t)(kt*64 + row)*1536) + kcolsrc,
                  Ks + (w*32 + i*8)*128);
    }
    // stage V^T: 2 keys x 16 d per thread, paired b32 writes
    {
      const ushort* v0p = base + (size_t)(kt*64 + vj)*1536 + 1024 + vd0;
      const ushort* v1p = v0p + 1536;
      uint4 a0 = *(const uint4*)(v0p);
      uint4 a1 = *(const uint4*)(v0p + 8);
      uint4 b0 = *(const uint4*)(v1p);
      uint4 b1 = *(const uint4*)(v1p + 8);
      uint av[8] = {a0.x, a0.y, a0.z, a0.w, a1.x, a1.y, a1.z, a1.w};
      uint bv[8] = {b0.x, b0.y, b0.z, b0.w, b1.x, b1.y, b1.z, b1.w};
      int cb = 4 * (tid & 31);
      #pragma unroll
      for (int e = 0; e < 8; e++){
        int dl = vd0 + e*2, dh = dl + 1;
        uint vlo = (av[e] & 0xffffu) | ((bv[e] & 0xffffu) << 16);
        uint vhi = (av[e] >> 16) | (bv[e] & 0xffff0000u);
        *(uint*)(Vt + dl*128 + (cb ^ ((dl & 7) << 4))) = vlo;
        *(uint*)(Vt + dh*128 + (cb ^ ((dh & 7) << 4))) = vhi;
      }
    }
    __syncthreads();   // K, V staged

    f32x4 accS[4];
    __builtin_amdgcn_s_setprio(1);
    #pragma unroll
    for (int jt = 0; jt < 4; jt++){
      accS[jt] = zero4;
      #pragma unroll
      for (int kc = 0; kc < 2; kc++){
        int krow = jt*16 + (lane & 15);
        bf16x8 kb = *(const bf16x8*)(Ks + krow*128 + ((kc*64 + (lane>>4)*16) ^ ((krow & 7) << 4)));
        accS[jt] = __builtin_amdgcn_mfma_f32_16x16x32_bf16(qa[kc], kb, accS[jt], 0, 0, 0);
      }
    }
    __builtin_amdgcn_s_setprio(0);
    if (kt == ktmax){
      #pragma unroll
      for (int jt = 0; jt < 4; jt++){
        int gj = kt*64 + jt*16 + (lane & 15);
        #pragma unroll
        for (int r = 0; r < 4; r++){
          int gi = qt*32 + w*16 + (lane>>4)*4 + r;
          if (gj > gi) accS[jt][r] = -1e30f;
        }
      }
    }
    #pragma unroll
    for (int r = 0; r < 4; r++){
      float mloc = fmaxf(fmaxf(accS[0][r], accS[1][r]), fmaxf(accS[2][r], accS[3][r])) * 0.125f;
      mloc = rowMax16(mloc);
      float mnew = fmaxf(m_old[r], mloc);
      float corr = __expf(m_old[r] - mnew);
      int prow = w*16 + (lane>>4)*4 + r;
      int swz = (prow & 7) << 4;
      char* pbase = Ps + prow*128;
      float ps = 0.f;
      #pragma unroll
      for (int jt = 0; jt < 4; jt++){
        float p = __expf(accS[jt][r]*0.125f - mnew);
        ushort pb = f2bf(p);
        *(ushort*)(pbase + ((2*(jt*16 + (lane & 15))) ^ swz)) = pb;
        ps += bf2f(pb);
      }
      ps = rowSum16(ps);
      l_sum[r] = l_sum[r]*corr + ps;
      m_old[r] = mnew;
      #pragma unroll
      for (int dt = 0; dt < 4; dt++) o[dt][r] *= corr;
    }
    bf16x8 pa[2];
    #pragma unroll
    for (int kc2 = 0; kc2 < 2; kc2++){
      int prow = w*16 + (lane & 15);
      pa[kc2] = *(const bf16x8*)(Ps + prow*128 + ((kc2*64 + (lane>>4)*16) ^ ((prow & 7) << 4)));
    }
    __builtin_amdgcn_s_setprio(1);
    #pragma unroll
    for (int dt = 0; dt < 4; dt++){
      #pragma unroll
      for (int kc2 = 0; kc2 < 2; kc2++){
        int vrow = dt*16 + (lane & 15);
        bf16x8 vb = *(const bf16x8*)(Vt + vrow*128 + ((kc2*64 + (lane>>4)*16) ^ ((vrow & 7) << 4)));
        o[dt] = __builtin_amdgcn_mfma_f32_16x16x32_bf16(pa[kc2], vb, o[dt], 0, 0, 0);
      }
    }
    __builtin_amdgcn_s_setprio(0);
  }
  #pragma unroll
  for (int r = 0; r < 4; r++){
    float invl = 1.f / l_sum[r];
    int token = qt*32 + w*16 + (lane>>4)*4 + r;
    ushort* yrow = y + (size_t)(b*2048 + token)*512 + h*64;
    #pragma unroll
    for (int dt = 0; dt < 4; dt++)
      yrow[dt*16 + (lane & 15)] = f2bf(o[dt][r] * invl);
  }
}

// ---------------- tf = mean over N of lnf(hid) (bf16 in, f32 out) ----------------
__global__ __launch_bounds__(256) void reduce_tf_kernel(const ushort* __restrict__ hid, float* __restrict__ tf){
  int bt = blockIdx.x, tid = threadIdx.x;
  for (int d = tid; d < 512; d += 256){
    float s = 0.f;
    for (int n = 0; n < 64; n++) s += bf2f(hid[((size_t)bt*64 + n)*512 + d]);
    tf[(size_t)bt*512 + d] = s * (1.f/64.f);
  }
}

// ---------------- heads ----------------
__global__ __launch_bounds__(256) void head_kernel(
    const float* __restrict__ tf,
    const float* __restrict__ th_w1, const float* __restrict__ th_b1,
    const float* __restrict__ th_w2, const float* __restrict__ th_b2,
    const float* __restrict__ sh_w1, const float* __restrict__ sh_b1,
    const float* __restrict__ sh_w2, const float* __restrict__ sh_b2,
    const float* __restrict__ pf_w1, const float* __restrict__ pf_b1,
    const float* __restrict__ pf_w2, const float* __restrict__ pf_b2,
    float* __restrict__ out)
{
  __shared__ float z[512];
  __shared__ float red[4];
  int bi = blockIdx.x, tid = threadIdx.x;
  const float *w1, *b1, *w2, *b2;
  float* dst;
  if (bi < 64){
    w1 = pf_w1; b1 = pf_b1; w2 = pf_w2; b2 = pf_b2; dst = out + 4 + bi;
    z[tid]       = tf[(size_t)bi*512 + tid];
    z[tid + 256] = tf[(size_t)bi*512 + tid + 256];
  } else if (bi < 66){
    int b = bi - 64;
    w1 = th_w1; b1 = th_b1; w2 = th_w2; b2 = th_b2; dst = out + b;
    z[tid]       = tf[(size_t)(b*32 + 31)*512 + tid];
    z[tid + 256] = tf[(size_t)(b*32 + 31)*512 + tid + 256];
  } else {
    int b = bi - 66;
    w1 = sh_w1; b1 = sh_b1; w2 = sh_w2; b2 = sh_b2; dst = out + 2 + b;
    float s0 = 0.f, s1 = 0.f;
    for (int t = 0; t < 32; t++){
      s0 += tf[(size_t)(b*32 + t)*512 + tid];
      s1 += tf[(size_t)(b*32 + t)*512 + tid + 256];
    }
    z[tid] = s0 * (1.f/32.f); z[tid + 256] = s1 * (1.f/32.f);
  }
  __syncthreads();
  float a = b1[tid];
  const float* wrow = w1 + (size_t)tid * 512;
  for (int k = 0; k < 512; k++) a = fmaf(wrow[k], z[k], a);
  a = (a > 0.f) ? a : 0.2f * a;
  float s = blockReduceSum(a * w2[tid], red);
  if (tid == 0) *dst = s + b2[0];
}

__global__ __launch_bounds__(64) void final_kernel(float* __restrict__ out){
  int b = threadIdx.x;
  if (b < 2){
    float s = 0.f;
    for (int t = 0; t < 32; t++) s += out[4 + b*32 + t];
    out[68 + b] = out[b] + out[2 + b] + s * (1.f/32.f);
  }
}

extern "C" void kernel_launch(void* const* d_in, const int* in_sizes, int n_in,
                              void* d_out, int out_size, void* d_ws, size_t ws_size,
                              hipStream_t stream)
{
  const float* x          = (const float*)d_in[0];
  const float* patch_w    = (const float*)d_in[1];
  const float* patch_b    = (const float*)d_in[2];
  const float* tok_ln_g   = (const float*)d_in[3];
  const float* tok_ln_b   = (const float*)d_in[4];
  const float* spatial_pos= (const float*)d_in[5];
  const float* temporal_pos=(const float*)d_in[6];
  const float* snorm_g    = (const float*)d_in[7];
  const float* snorm_b    = (const float*)d_in[8];
  const float* sa_in_w    = (const float*)d_in[9];
  const float* sa_in_b    = (const float*)d_in[10];
  const float* sa_out_w   = (const float*)d_in[11];
  const float* sa_out_b   = (const float*)d_in[12];
  const float* ln1_g      = (const float*)d_in[13];
  const float* ln1_b      = (const float*)d_in[14];
  const float* kqv_w      = (const float*)d_in[15];
  const float* kqv_b      = (const float*)d_in[16];
  const float* proj_w     = (const float*)d_in[17];
  const float* proj_b     = (const float*)d_in[18];
  const float* ln2_g      = (const float*)d_in[19];
  const float* ln2_b      = (const float*)d_in[20];
  const float* fc_w       = (const float*)d_in[21];
  const float* fc_b       = (const float*)d_in[22];
  const float* cproj_w    = (const float*)d_in[23];
  const float* cproj_b    = (const float*)d_in[24];
  const float* lnf_g      = (const float*)d_in[25];
  const float* lnf_b      = (const float*)d_in[26];
  const float* th_w1 = (const float*)d_in[27];
  const float* th_b1 = (const float*)d_in[28];
  const float* th_w2 = (const float*)d_in[29];
  const float* th_b2 = (const float*)d_in[30];
  const float* sh_w1 = (const float*)d_in[31];
  const float* sh_b1 = (const float*)d_in[32];
  const float* sh_w2 = (const float*)d_in[33];
  const float* sh_b2 = (const float*)d_in[34];
  const float* pf_w1 = (const float*)d_in[35];
  const float* pf_b1 = (const float*)d_in[36];
  const float* pf_w2 = (const float*)d_in[37];
  const float* pf_b2 = (const float*)d_in[38];

  float* out = (float*)d_out;
  // workspace layout (bytes)
  char* p = (char*)d_ws;
  float*  A  = (float*)p;      p += (size_t)MTOK*512*4;    // f32 hidden
  ushort* Ru = (ushort*)p;     p += (size_t)MTOK*2048*2;   // bf16 qkv/gelu; f32 patch-gemm out
  ushort* Bf = (ushort*)p;     p += (size_t)MTOK*512*2;    // ln out bf16
  ushort* Ef = (ushort*)p;     p += (size_t)MTOK*512*2;    // attn out bf16 (also im2col patches)
  float*  tfp = (float*)p;     p += (size_t)64*512*4;
  ushort* Wslot = (ushort*)p;  p += (size_t)1048576*2;     // fallback weight slot
  ushort* Wall = (ushort*)p;   p += (size_t)W_TOTAL*2;     // upfront bf16 arena
  float*  Pf = (float*)Ru;     // patch gemm f32 out 4096x512
  ushort* Pm = Ef;             // patches bf16 4096x192 (before Ef first written)

  const size_t NEED_BIG = (size_t)((char*)p - (char*)d_ws);
  const bool big = (ws_size >= NEED_BIG);

  if (big){
    cvt_all_kernel<<<10800, 256, 0, stream>>>(patch_w, sa_in_w, sa_out_w, kqv_w,
                                              proj_w, fc_w, cproj_w, Wall);
  }
  auto W = [&](const float* src, size_t arena_off, size_t nelem) -> const ushort* {
    if (big) return Wall + arena_off;
    cvt_w_kernel<<<(int)(nelem/2048), 256, 0, stream>>>(src, Wslot, (int)nelem);
    return Wslot;
  };

  // patch embed: im2col -> MFMA GEMM -> LN+pos
  im2col_kernel<<<384, 256, 0, stream>>>(x, Pm);
  gemm2_kernel<64,64,false,false><<<dim3(8, 64), 256, 0, stream>>>(
      Pm, W(patch_w, OFF_PATCH, 512*192), patch_b, nullptr, Pf, MTOK, 512, 192);
  ln_pos_kernel<<<1024, 256, 0, stream>>>(Pf, A, tok_ln_g, tok_ln_b, spatial_pos, temporal_pos);

  // spatial layers
  for (int i = 0; i < 3; i++){
    ln_bf16_kernel<<<1024, 256, 0, stream>>>(A, Bf, snorm_g, snorm_b);
    gemm2_kernel<64,128,false,true><<<dim3(12, 64), 256, 0, stream>>>(
        Bf, W(sa_in_w + (size_t)i*1536*512, OFF_SAIN + (size_t)i*786432, 1536*512),
        sa_in_b + (size_t)i*1536, nullptr, Ru, MTOK, 1536, 512);
    spatial_attn_mfma_kernel<<<dim3(64, 4), 256, 0, stream>>>(Ru, Ef);
    gemm2_kernel<64,64,false,false><<<dim3(8, 64), 256, 0, stream>>>(
        Ef, W(sa_out_w + (size_t)i*512*512, OFF_SAOUT + (size_t)i*262144, 512*512),
        sa_out_b + (size_t)i*512, A, A, MTOK, 512, 512);
  }
  // temporal layers
  for (int i = 0; i < 6; i++){
    ln_bf16_kernel<<<1024, 256, 0, stream>>>(A, Bf, ln1_g + (size_t)i*512, ln1_b + (size_t)i*512);
    gemm2_kernel<64,128,false,true><<<dim3(12, 64), 256, 0, stream>>>(
        Bf, W(kqv_w + (size_t)i*1536*512, OFF_KQV + (size_t)i*786432, 1536*512),
        kqv_b + (size_t)i*1536, nullptr, Ru, MTOK, 1536, 512);
    temporal_attn_mfma_kernel<<<1024, 128, 0, stream>>>(Ru, Ef);
    gemm2_kernel<64,64,false,false><<<dim3(8, 64), 256, 0, stream>>>(
        Ef, W(proj_w + (size_t)i*512*512, OFF_PROJ + (size_t)i*262144, 512*512),
        proj_b + (size_t)i*512, A, A, MTOK, 512, 512);
    ln_bf16_kernel<<<1024, 256, 0, stream>>>(A, Bf, ln2_g + (size_t)i*512, ln2_b + (size_t)i*512);
    gemm2_kernel<128,128,true,true><<<dim3(16, 32), 256, 0, stream>>>(
        Bf, W(fc_w + (size_t)i*2048*512, OFF_FC + (size_t)i*1048576, 2048*512),
        fc_b + (size_t)i*2048, nullptr, Ru, MTOK, 2048, 512);
    gemm2_kernel<64,64,false,false><<<dim3(8, 64), 256, 0, stream>>>(
        Ru, W(cproj_w + (size_t)i*512*2048, OFF_CPROJ + (size_t)i*1048576, 512*2048),
        cproj_b + (size_t)i*512, A, A, MTOK, 512, 2048);
  }
  // final LN + heads
  ln_bf16_kernel<<<1024, 256, 0, stream>>>(A, Bf, lnf_g, lnf_b);
  reduce_tf_kernel<<<64, 256, 0, stream>>>(Bf, tfp);
  head_kernel<<<68, 256, 0, stream>>>(tfp, th_w1, th_b1, th_w2, th_b2,
                                      sh_w1, sh_b1, sh_w2, sh_b2,
                                      pf_w1, pf_b1, pf_w2, pf_b2, out);
  final_kernel<<<1, 64, 0, stream>>>(out);
}